// Round 1
// baseline (4028.056 us; speedup 1.0000x reference)
//
#include <hip/hip_runtime.h>
#include <cstdint>
#include <cstddef>

// Problem constants (match reference setup_inputs)
#define NN   50000      // nodes
#define NE   1200000    // edges
#define NR   45         // relations
#define INC  64
#define HIDC 32
#define OUTC 16
// Padded edge capacity: each relation bucket padded to multiple of 64 so every
// wave's 64 edges share one relation. NE + NR*64, itself a multiple of 64.
#define MAXE 1202880
#define NCHUNK (MAXE/64)

// ---------------------------------------------------------------------------
// Transpose W1 -> W1t[r][c][in], W2 -> W2t[r][c][in] so each output channel's
// weight column is contiguous (enables s_load_dwordx16 streaming in msg kernels)
__global__ __launch_bounds__(256) void prep_w(const float* __restrict__ W1,
                                              const float* __restrict__ W2,
                                              float* __restrict__ W1t,
                                              float* __restrict__ W2t) {
    int t = blockIdx.x * 256 + threadIdx.x;
    if (t < NR * HIDC * INC) {
        int r = t / (HIDC * INC), rem = t % (HIDC * INC);
        int c = rem / INC, in = rem % INC;
        W1t[t] = W1[(r * INC + in) * HIDC + c];
    }
    if (t < NR * OUTC * HIDC) {
        int r = t / (OUTC * HIDC), rem = t % (OUTC * HIDC);
        int c = rem / HIDC, in = rem % HIDC;
        W2t[t] = W2[(r * HIDC + in) * OUTC + c];
    }
}

// ---------------------------------------------------------------------------
// Per-(rel,dst) edge counts (shared by both layers) + per-relation histogram.
__global__ __launch_bounds__(256) void count_k(const int* __restrict__ ei,
                                               const int* __restrict__ et,
                                               unsigned* __restrict__ cnt,
                                               unsigned* __restrict__ hist) {
    __shared__ unsigned lh[NR];
    int t = threadIdx.x;
    if (t < NR) lh[t] = 0;
    __syncthreads();
    int e = blockIdx.x * 256 + t;
    if (e < NE) {
        int r = et[e];
        int dst = ei[NE + e];
        if ((unsigned)r < NR && (unsigned)dst < NN) {
            atomicAdd(&cnt[(size_t)r * NN + dst], 1u);
            atomicAdd(&lh[r], 1u);
        }
    }
    __syncthreads();
    if (t < NR && lh[t]) atomicAdd(&hist[t], lh[t]);
}

// 64-aligned exclusive prefix over 45 bins -> cursor (scatter write heads)
__global__ void prefix_k(const unsigned* __restrict__ hist,
                         unsigned* __restrict__ cursor) {
    if (threadIdx.x == 0 && blockIdx.x == 0) {
        unsigned acc = 0;
        for (int r = 0; r < NR; ++r) {
            cursor[r] = acc;
            acc += ((hist[r] + 63u) >> 6) << 6;   // pad bucket to x64
        }
    }
}

// Counting-sort scatter: edges grouped by relation; precompute 1/cnt per edge.
// Pad slots keep memset values (src=dst=0, scale=0 -> contribute exactly 0).
__global__ __launch_bounds__(256) void scatter_k(const int* __restrict__ ei,
                                                 const int* __restrict__ et,
                                                 const unsigned* __restrict__ cnt,
                                                 unsigned* __restrict__ cursor,
                                                 int* __restrict__ psrc,
                                                 int* __restrict__ pdst,
                                                 int* __restrict__ pet,
                                                 float* __restrict__ pscale) {
    __shared__ unsigned lh[NR], lbase[NR], lcur[NR];
    int t = threadIdx.x;
    if (t < NR) { lh[t] = 0; lcur[t] = 0; }
    __syncthreads();
    int e = blockIdx.x * 256 + t;
    int r = -1, src = 0, dst = 0;
    if (e < NE) {
        r = et[e]; src = ei[e]; dst = ei[NE + e];
        if ((unsigned)r >= NR || (unsigned)src >= NN || (unsigned)dst >= NN) r = -1;
        if (r >= 0) atomicAdd(&lh[r], 1u);
    }
    __syncthreads();
    if (t < NR && lh[t]) lbase[t] = atomicAdd(&cursor[t], lh[t]);
    __syncthreads();
    if (r >= 0) {
        unsigned pos = lbase[r] + atomicAdd(&lcur[r], 1u);
        psrc[pos] = src;
        pdst[pos] = dst;
        pet[pos]  = r;
        pscale[pos] = 1.0f / (float)cnt[(size_t)r * NN + dst];
    }
}

// ---------------------------------------------------------------------------
// Layer-1 messages. One lane per edge; one wave = 64 edges of ONE relation
// (guaranteed by bucket padding), so W is wave-uniform -> scalar (SGPR) loads.
// Each lane: x-row (64 f32) in VGPRs, 32 output channels, 2048 unrolled FMAs.
__global__ __launch_bounds__(256) void msg1_k(const float* __restrict__ x,
                                              const float* __restrict__ W1t,
                                              const int* __restrict__ psrc,
                                              const int* __restrict__ pdst,
                                              const int* __restrict__ pet,
                                              const float* __restrict__ pscale,
                                              float* __restrict__ agg1) {
    int wave = (blockIdx.x * 256 + threadIdx.x) >> 6;
    int lane = threadIdx.x & 63;
    if (wave >= NCHUNK) return;
    int base = wave << 6;
    int et = __builtin_amdgcn_readfirstlane(pet[base]);   // wave-uniform relation
    const float* __restrict__ wr = W1t + (size_t)et * (HIDC * INC);
    int e = base + lane;
    int src = psrc[e], dst = pdst[e];
    float sc = pscale[e];
    const float4* __restrict__ xp = (const float4*)(x + (size_t)src * INC);
    float xv[INC];
    #pragma unroll
    for (int i = 0; i < INC / 4; ++i) {
        float4 q = xp[i];
        xv[4*i] = q.x; xv[4*i+1] = q.y; xv[4*i+2] = q.z; xv[4*i+3] = q.w;
    }
    float* aout = agg1 + (size_t)dst * HIDC;
    #pragma unroll 4
    for (int c = 0; c < HIDC; ++c) {
        const float* __restrict__ wc = wr + c * INC;   // uniform -> s_load stream
        float a = 0.f;
        #pragma unroll
        for (int i = 0; i < INC; ++i) a = fmaf(xv[i], wc[i], a);
        atomicAdd(&aout[c], a * sc);
    }
}

// Layer-2 messages (32 -> 16)
__global__ __launch_bounds__(256) void msg2_k(const float* __restrict__ h,
                                              const float* __restrict__ W2t,
                                              const int* __restrict__ psrc,
                                              const int* __restrict__ pdst,
                                              const int* __restrict__ pet,
                                              const float* __restrict__ pscale,
                                              float* __restrict__ agg2) {
    int wave = (blockIdx.x * 256 + threadIdx.x) >> 6;
    int lane = threadIdx.x & 63;
    if (wave >= NCHUNK) return;
    int base = wave << 6;
    int et = __builtin_amdgcn_readfirstlane(pet[base]);
    const float* __restrict__ wr = W2t + (size_t)et * (OUTC * HIDC);
    int e = base + lane;
    int src = psrc[e], dst = pdst[e];
    float sc = pscale[e];
    const float4* __restrict__ hp = (const float4*)(h + (size_t)src * HIDC);
    float hv[HIDC];
    #pragma unroll
    for (int i = 0; i < HIDC / 4; ++i) {
        float4 q = hp[i];
        hv[4*i] = q.x; hv[4*i+1] = q.y; hv[4*i+2] = q.z; hv[4*i+3] = q.w;
    }
    float* aout = agg2 + (size_t)dst * OUTC;
    #pragma unroll 4
    for (int c = 0; c < OUTC; ++c) {
        const float* __restrict__ wc = wr + c * HIDC;
        float a = 0.f;
        #pragma unroll
        for (int i = 0; i < HIDC; ++i) a = fmaf(hv[i], wc[i], a);
        atomicAdd(&aout[c], a * sc);
    }
}

// ---------------------------------------------------------------------------
// Node update 1: h = relu(agg1 + x @ root1 + b1). Thread = (node, channel).
__global__ __launch_bounds__(256) void node1_k(const float* __restrict__ x,
                                               const float* __restrict__ root1,
                                               const float* __restrict__ b1,
                                               const float* __restrict__ agg1,
                                               float* __restrict__ h) {
    __shared__ float sr[INC * HIDC];
    int t = threadIdx.x;
    for (int k = t; k < INC * HIDC; k += 256) sr[k] = root1[k];
    __syncthreads();
    int idx = blockIdx.x * 256 + t;          // NN*HIDC is an exact multiple of 256
    int i = idx >> 5, c = idx & 31;
    const float* __restrict__ xr = x + (size_t)i * INC;
    float a = agg1[idx] + b1[c];
    #pragma unroll
    for (int in = 0; in < INC; ++in) a = fmaf(xr[in], sr[in * HIDC + c], a);
    h[idx] = a > 0.f ? a : 0.f;
}

// Node update 2: out = agg2 + h @ root2 + b2
__global__ __launch_bounds__(256) void node2_k(const float* __restrict__ h,
                                               const float* __restrict__ root2,
                                               const float* __restrict__ b2,
                                               const float* __restrict__ agg2,
                                               float* __restrict__ out) {
    __shared__ float sr[HIDC * OUTC];
    int t = threadIdx.x;
    for (int k = t; k < HIDC * OUTC; k += 256) sr[k] = root2[k];
    __syncthreads();
    int idx = blockIdx.x * 256 + t;          // NN*OUTC is an exact multiple of 256
    int i = idx >> 4, c = idx & 15;
    const float* __restrict__ hr = h + (size_t)i * HIDC;
    float a = agg2[idx] + b2[c];
    #pragma unroll
    for (int in = 0; in < HIDC; ++in) a = fmaf(hr[in], sr[in * OUTC + c], a);
    out[idx] = a;
}

// ---------------------------------------------------------------------------
extern "C" void kernel_launch(void* const* d_in, const int* in_sizes, int n_in,
                              void* d_out, int out_size, void* d_ws, size_t ws_size,
                              hipStream_t stream) {
    const float* x     = (const float*)d_in[0];
    const int*   ei    = (const int*)d_in[1];   // [2, NE]
    const int*   et    = (const int*)d_in[2];   // [NE]
    const float* W1    = (const float*)d_in[3];
    const float* root1 = (const float*)d_in[4];
    const float* b1    = (const float*)d_in[5];
    const float* W2    = (const float*)d_in[6];
    const float* root2 = (const float*)d_in[7];
    const float* b2    = (const float*)d_in[8];
    float* out = (float*)d_out;

    char* ws = (char*)d_ws;
    size_t o = 0;
    auto alloc = [&](size_t bytes) -> char* {
        char* p = ws + o;
        o = (o + bytes + 255) & ~(size_t)255;
        return p;
    };
    // --- region that must start zeroed (one contiguous memset) ---
    unsigned* cnt    = (unsigned*)alloc((size_t)NR * NN * 4);     // 9.0 MB
    float*    agg1   = (float*)   alloc((size_t)NN * HIDC * 4);   // 6.4 MB
    float*    agg2   = (float*)   alloc((size_t)NN * OUTC * 4);   // 3.2 MB
    unsigned* hist   = (unsigned*)alloc(NR * 4);
    int*      psrc   = (int*)     alloc((size_t)MAXE * 4);        // 4.8 MB
    int*      pdst   = (int*)     alloc((size_t)MAXE * 4);
    int*      pet    = (int*)     alloc((size_t)MAXE * 4);
    float*    pscale = (float*)   alloc((size_t)MAXE * 4);
    size_t zero_bytes = o;
    // --- regions fully written before read ---
    unsigned* cursor = (unsigned*)alloc(NR * 4);
    float*    W1t    = (float*)   alloc((size_t)NR * HIDC * INC * 4);
    float*    W2t    = (float*)   alloc((size_t)NR * OUTC * HIDC * 4);
    float*    h      = (float*)   alloc((size_t)NN * HIDC * 4);

    hipMemsetAsync(d_ws, 0, zero_bytes, stream);
    prep_w  <<<(NR * HIDC * INC + 255) / 256, 256, 0, stream>>>(W1, W2, W1t, W2t);
    count_k <<<(NE + 255) / 256, 256, 0, stream>>>(ei, et, cnt, hist);
    prefix_k<<<1, 64, 0, stream>>>(hist, cursor);
    scatter_k<<<(NE + 255) / 256, 256, 0, stream>>>(ei, et, cnt, cursor,
                                                    psrc, pdst, pet, pscale);
    msg1_k  <<<(MAXE + 255) / 256, 256, 0, stream>>>(x, W1t, psrc, pdst, pet, pscale, agg1);
    node1_k <<<NN * HIDC / 256, 256, 0, stream>>>(x, root1, b1, agg1, h);
    msg2_k  <<<(MAXE + 255) / 256, 256, 0, stream>>>(h, W2t, psrc, pdst, pet, pscale, agg2);
    node2_k <<<NN * OUTC / 256, 256, 0, stream>>>(h, root2, b2, agg2, out);
}

// Round 2
// 809.588 us; speedup vs baseline: 4.9754x; 4.9754x over previous
//
#include <hip/hip_runtime.h>
#include <cstdint>
#include <cstddef>

// Problem constants (match reference setup_inputs)
#define NN   50000      // nodes
#define NE   1200000    // edges
#define NR   45         // relations
#define INC  64
#define HIDC 32
#define OUTC 16
// Padded edge capacity: each relation bucket padded to multiple of 64 so every
// wave's 64 edges share one relation. NE + NR*64, itself a multiple of 64.
#define MAXE 1202880
#define NCHUNK (MAXE/64)

// ---------------------------------------------------------------------------
// Transpose W1 -> W1t[r][c][in], W2 -> W2t[r][c][in] so each output channel's
// weight column is contiguous (enables scalar-load streaming in msg kernels)
__global__ __launch_bounds__(256) void prep_w(const float* __restrict__ W1,
                                              const float* __restrict__ W2,
                                              float* __restrict__ W1t,
                                              float* __restrict__ W2t) {
    int t = blockIdx.x * 256 + threadIdx.x;
    if (t < NR * HIDC * INC) {
        int r = t / (HIDC * INC), rem = t % (HIDC * INC);
        int c = rem / INC, in = rem % INC;
        W1t[t] = W1[(r * INC + in) * HIDC + c];
    }
    if (t < NR * OUTC * HIDC) {
        int r = t / (OUTC * HIDC), rem = t % (OUTC * HIDC);
        int c = rem / HIDC, in = rem % HIDC;
        W2t[t] = W2[(r * HIDC + in) * OUTC + c];
    }
}

// ---------------------------------------------------------------------------
// Per-(rel,dst) edge counts (for the mean), per-relation histogram (for the
// relation counting sort), per-dst histogram (for the dst CSR).
__global__ __launch_bounds__(256) void count_k(const int* __restrict__ ei,
                                               const int* __restrict__ et,
                                               unsigned* __restrict__ cnt,
                                               unsigned* __restrict__ hist,
                                               unsigned* __restrict__ dhist) {
    __shared__ unsigned lh[NR];
    int t = threadIdx.x;
    if (t < NR) lh[t] = 0;
    __syncthreads();
    int e = blockIdx.x * 256 + t;
    if (e < NE) {
        int r = et[e];
        int dst = ei[NE + e];
        if ((unsigned)r < NR && (unsigned)dst < NN) {
            atomicAdd(&cnt[(size_t)r * NN + dst], 1u);
            atomicAdd(&lh[r], 1u);
            atomicAdd(&dhist[dst], 1u);
        }
    }
    __syncthreads();
    if (t < NR && lh[t]) atomicAdd(&hist[t], lh[t]);
}

// 64-aligned exclusive prefix over 45 relation bins -> cursor (scatter heads)
__global__ void prefix_k(const unsigned* __restrict__ hist,
                         unsigned* __restrict__ cursor) {
    if (threadIdx.x == 0 && blockIdx.x == 0) {
        unsigned acc = 0;
        for (int r = 0; r < NR; ++r) {
            cursor[r] = acc;
            acc += ((hist[r] + 63u) >> 6) << 6;   // pad bucket to x64
        }
    }
}

// Exclusive prefix over NN dst bins -> rowptr[NN+1] and dcursor (scatter heads)
__global__ __launch_bounds__(256) void dprefix_k(const unsigned* __restrict__ dhist,
                                                 unsigned* __restrict__ rowptr,
                                                 unsigned* __restrict__ dcursor) {
    __shared__ unsigned ps[257];
    int t = threadIdx.x;
    const int CH = (NN + 255) / 256;
    int lo = t * CH, hi = lo + CH; if (hi > NN) hi = NN; if (lo > NN) lo = NN;
    unsigned s = 0;
    for (int i = lo; i < hi; ++i) s += dhist[i];
    ps[t + 1] = s;
    if (t == 0) ps[0] = 0;
    __syncthreads();
    if (t == 0) for (int i = 1; i <= 256; ++i) ps[i] += ps[i - 1];
    __syncthreads();
    unsigned run = ps[t];
    for (int i = lo; i < hi; ++i) {
        rowptr[i] = run; dcursor[i] = run;
        run += dhist[i];
    }
    if (t == 255) rowptr[NN] = run;
}

// Counting-sort scatter by relation (for W-uniform msg compute) AND build the
// dst-sorted index list didx (holding relation-sorted positions) for gather.
// Pad slots keep memset values (src=0, scale=0 -> harmless rows, never gathered).
__global__ __launch_bounds__(256) void scatter_k(const int* __restrict__ ei,
                                                 const int* __restrict__ et,
                                                 const unsigned* __restrict__ cnt,
                                                 unsigned* __restrict__ cursor,
                                                 unsigned* __restrict__ dcursor,
                                                 int* __restrict__ psrc,
                                                 int* __restrict__ pet,
                                                 float* __restrict__ pscale,
                                                 unsigned* __restrict__ didx) {
    __shared__ unsigned lh[NR], lbase[NR], lcur[NR];
    int t = threadIdx.x;
    if (t < NR) { lh[t] = 0; lcur[t] = 0; }
    __syncthreads();
    int e = blockIdx.x * 256 + t;
    int r = -1, src = 0, dst = 0;
    if (e < NE) {
        r = et[e]; src = ei[e]; dst = ei[NE + e];
        if ((unsigned)r >= NR || (unsigned)src >= NN || (unsigned)dst >= NN) r = -1;
        if (r >= 0) atomicAdd(&lh[r], 1u);
    }
    __syncthreads();
    if (t < NR && lh[t]) lbase[t] = atomicAdd(&cursor[t], lh[t]);
    __syncthreads();
    if (r >= 0) {
        unsigned pos = lbase[r] + atomicAdd(&lcur[r], 1u);
        psrc[pos] = src;
        pet[pos]  = r;
        pscale[pos] = 1.0f / (float)cnt[(size_t)r * NN + dst];
        unsigned dpos = atomicAdd(&dcursor[dst], 1u);
        didx[dpos] = pos;
    }
}

// ---------------------------------------------------------------------------
// Layer-1 messages. One lane per edge; one wave = 64 edges of ONE relation
// (bucket padding), so W is wave-uniform -> scalar (SGPR) loads. Plain
// float4 stores of the scaled message row — NO atomics.
__global__ __launch_bounds__(256) void msg1_k(const float* __restrict__ x,
                                              const float* __restrict__ W1t,
                                              const int* __restrict__ psrc,
                                              const int* __restrict__ pet,
                                              const float* __restrict__ pscale,
                                              float* __restrict__ msg) {
    int wave = (blockIdx.x * 256 + threadIdx.x) >> 6;
    int lane = threadIdx.x & 63;
    if (wave >= NCHUNK) return;
    int base = wave << 6;
    int et = __builtin_amdgcn_readfirstlane(pet[base]);   // wave-uniform relation
    const float* __restrict__ wr = W1t + (size_t)et * (HIDC * INC);
    int e = base + lane;
    int src = psrc[e];
    float sc = pscale[e];
    const float4* __restrict__ xp = (const float4*)(x + (size_t)src * INC);
    float xv[INC];
    #pragma unroll
    for (int i = 0; i < INC / 4; ++i) {
        float4 q = xp[i];
        xv[4*i] = q.x; xv[4*i+1] = q.y; xv[4*i+2] = q.z; xv[4*i+3] = q.w;
    }
    float4* __restrict__ mrow = (float4*)(msg + (size_t)e * HIDC);
    #pragma unroll
    for (int c4 = 0; c4 < HIDC / 4; ++c4) {
        float4 o;
        float* op = (float*)&o;
        #pragma unroll
        for (int j = 0; j < 4; ++j) {
            const float* __restrict__ wc = wr + (c4 * 4 + j) * INC;
            float a = 0.f;
            #pragma unroll
            for (int i = 0; i < INC; ++i) a = fmaf(xv[i], wc[i], a);
            op[j] = a * sc;
        }
        mrow[c4] = o;
    }
}

// Layer-2 messages (32 -> 16)
__global__ __launch_bounds__(256) void msg2_k(const float* __restrict__ h,
                                              const float* __restrict__ W2t,
                                              const int* __restrict__ psrc,
                                              const int* __restrict__ pet,
                                              const float* __restrict__ pscale,
                                              float* __restrict__ msg) {
    int wave = (blockIdx.x * 256 + threadIdx.x) >> 6;
    int lane = threadIdx.x & 63;
    if (wave >= NCHUNK) return;
    int base = wave << 6;
    int et = __builtin_amdgcn_readfirstlane(pet[base]);
    const float* __restrict__ wr = W2t + (size_t)et * (OUTC * HIDC);
    int e = base + lane;
    int src = psrc[e];
    float sc = pscale[e];
    const float4* __restrict__ hp = (const float4*)(h + (size_t)src * HIDC);
    float hv[HIDC];
    #pragma unroll
    for (int i = 0; i < HIDC / 4; ++i) {
        float4 q = hp[i];
        hv[4*i] = q.x; hv[4*i+1] = q.y; hv[4*i+2] = q.z; hv[4*i+3] = q.w;
    }
    float4* __restrict__ mrow = (float4*)(msg + (size_t)e * OUTC);
    #pragma unroll
    for (int c4 = 0; c4 < OUTC / 4; ++c4) {
        float4 o;
        float* op = (float*)&o;
        #pragma unroll
        for (int j = 0; j < 4; ++j) {
            const float* __restrict__ wc = wr + (c4 * 4 + j) * HIDC;
            float a = 0.f;
            #pragma unroll
            for (int i = 0; i < HIDC; ++i) a = fmaf(hv[i], wc[i], a);
            op[j] = a * sc;
        }
        mrow[c4] = o;
    }
}

// ---------------------------------------------------------------------------
// Fused gather + node update 1: h = relu(sum(msg rows) + x @ root1 + b1).
// One wave per node; half-wave = one edge stream (c = lane&31, sub = lane>>5).
__global__ __launch_bounds__(256) void gather1_k(const float* __restrict__ x,
                                                 const float* __restrict__ root1,
                                                 const float* __restrict__ b1,
                                                 const float* __restrict__ msg,
                                                 const unsigned* __restrict__ rowptr,
                                                 const unsigned* __restrict__ didx,
                                                 float* __restrict__ h) {
    __shared__ float sr[INC * HIDC];   // 8 KB
    for (int k = threadIdx.x; k < INC * HIDC; k += 256) sr[k] = root1[k];
    __syncthreads();
    int wid = (blockIdx.x * 256 + threadIdx.x) >> 6;   // node id; grid exact
    int lane = threadIdx.x & 63;
    int c = lane & 31, sub = lane >> 5;
    unsigned k0 = rowptr[wid], k1 = rowptr[wid + 1];
    float acc = 0.f;
    for (unsigned k = k0 + sub; k < k1; k += 2)
        acc += msg[(size_t)didx[k] * HIDC + c];
    // root contribution: sub-half handles input range [sub*32, sub*32+32)
    const float* __restrict__ xr = x + (size_t)wid * INC + sub * 32;
    #pragma unroll
    for (int in = 0; in < 32; ++in)
        acc = fmaf(xr[in], sr[(sub * 32 + in) * HIDC + c], acc);
    acc += __shfl_xor(acc, 32);
    if (sub == 0) {
        float v = acc + b1[c];
        h[(size_t)wid * HIDC + c] = v > 0.f ? v : 0.f;
    }
}

// Fused gather + node update 2: out = sum(msg rows) + h @ root2 + b2.
// One wave per node; quarter-wave streams (c = lane&15, sub = lane>>4).
__global__ __launch_bounds__(256) void gather2_k(const float* __restrict__ h,
                                                 const float* __restrict__ root2,
                                                 const float* __restrict__ b2,
                                                 const float* __restrict__ msg,
                                                 const unsigned* __restrict__ rowptr,
                                                 const unsigned* __restrict__ didx,
                                                 float* __restrict__ out) {
    __shared__ float sr[HIDC * OUTC];  // 2 KB
    for (int k = threadIdx.x; k < HIDC * OUTC; k += 256) sr[k] = root2[k];
    __syncthreads();
    int wid = (blockIdx.x * 256 + threadIdx.x) >> 6;
    int lane = threadIdx.x & 63;
    int c = lane & 15, sub = lane >> 4;   // 4 streams
    unsigned k0 = rowptr[wid], k1 = rowptr[wid + 1];
    float acc = 0.f;
    for (unsigned k = k0 + sub; k < k1; k += 4)
        acc += msg[(size_t)didx[k] * OUTC + c];
    // root contribution: sub-quarter handles input range [sub*8, sub*8+8)
    const float* __restrict__ hr = h + (size_t)wid * HIDC + sub * 8;
    #pragma unroll
    for (int in = 0; in < 8; ++in)
        acc = fmaf(hr[in], sr[(sub * 8 + in) * OUTC + c], acc);
    acc += __shfl_xor(acc, 16);
    acc += __shfl_xor(acc, 32);
    if (sub == 0) out[(size_t)wid * OUTC + c] = acc + b2[c];
}

// ---------------------------------------------------------------------------
extern "C" void kernel_launch(void* const* d_in, const int* in_sizes, int n_in,
                              void* d_out, int out_size, void* d_ws, size_t ws_size,
                              hipStream_t stream) {
    const float* x     = (const float*)d_in[0];
    const int*   ei    = (const int*)d_in[1];   // [2, NE]
    const int*   et    = (const int*)d_in[2];   // [NE]
    const float* W1    = (const float*)d_in[3];
    const float* root1 = (const float*)d_in[4];
    const float* b1    = (const float*)d_in[5];
    const float* W2    = (const float*)d_in[6];
    const float* root2 = (const float*)d_in[7];
    const float* b2    = (const float*)d_in[8];
    float* out = (float*)d_out;

    char* ws = (char*)d_ws;
    size_t o = 0;
    auto alloc = [&](size_t bytes) -> char* {
        char* p = ws + o;
        o = (o + bytes + 255) & ~(size_t)255;
        return p;
    };
    // --- region that must start zeroed (one contiguous memset, ~23.7 MB) ---
    unsigned* cnt    = (unsigned*)alloc((size_t)NR * NN * 4);     // 9.0 MB
    unsigned* hist   = (unsigned*)alloc(NR * 4);
    unsigned* dhist  = (unsigned*)alloc((size_t)NN * 4);          // 0.2 MB
    int*      psrc   = (int*)     alloc((size_t)MAXE * 4);        // 4.8 MB
    int*      pet    = (int*)     alloc((size_t)MAXE * 4);
    float*    pscale = (float*)   alloc((size_t)MAXE * 4);
    size_t zero_bytes = o;
    // --- regions fully written before read ---
    unsigned* cursor = (unsigned*)alloc(NR * 4);
    unsigned* rowptr = (unsigned*)alloc(((size_t)NN + 1) * 4);
    unsigned* dcursor= (unsigned*)alloc((size_t)NN * 4);
    unsigned* didx   = (unsigned*)alloc((size_t)MAXE * 4);        // 4.8 MB
    float*    W1t    = (float*)   alloc((size_t)NR * HIDC * INC * 4);
    float*    W2t    = (float*)   alloc((size_t)NR * OUTC * HIDC * 4);
    float*    h      = (float*)   alloc((size_t)NN * HIDC * 4);   // 6.4 MB
    float*    msg1   = (float*)   alloc((size_t)MAXE * HIDC * 4); // 154 MB
    float*    msg2   = msg1;  // alias: msg1 fully consumed by gather1 before msg2

    hipMemsetAsync(d_ws, 0, zero_bytes, stream);
    prep_w   <<<(NR * HIDC * INC + 255) / 256, 256, 0, stream>>>(W1, W2, W1t, W2t);
    count_k  <<<(NE + 255) / 256, 256, 0, stream>>>(ei, et, cnt, hist, dhist);
    prefix_k <<<1, 64, 0, stream>>>(hist, cursor);
    dprefix_k<<<1, 256, 0, stream>>>(dhist, rowptr, dcursor);
    scatter_k<<<(NE + 255) / 256, 256, 0, stream>>>(ei, et, cnt, cursor, dcursor,
                                                    psrc, pet, pscale, didx);
    msg1_k   <<<(MAXE + 255) / 256, 256, 0, stream>>>(x, W1t, psrc, pet, pscale, msg1);
    gather1_k<<<NN * 64 / 256, 256, 0, stream>>>(x, root1, b1, msg1, rowptr, didx, h);
    msg2_k   <<<(MAXE + 255) / 256, 256, 0, stream>>>(h, W2t, psrc, pet, pscale, msg2);
    gather2_k<<<NN * 64 / 256, 256, 0, stream>>>(h, root2, b2, msg2, rowptr, didx, out);
}

// Round 3
// 739.702 us; speedup vs baseline: 5.4455x; 1.0945x over previous
//
#include <hip/hip_runtime.h>
#include <hip/hip_fp16.h>
#include <cstdint>
#include <cstddef>

// Problem constants (match reference setup_inputs)
#define NN   50000      // nodes
#define NE   1200000    // edges
#define NR   45         // relations
#define INC  64
#define HIDC 32
#define OUTC 16
// Padded edge capacity: each relation bucket padded to multiple of 64 so every
// wave's 64 edges share one relation. NE + NR*64, itself a multiple of 64.
#define MAXE 1202880
#define NCHUNK (MAXE/64)

// ---------------------------------------------------------------------------
// Transpose W1 -> W1t[r][c][in], W2 -> W2t[r][c][in] so each output channel's
// weight column is contiguous (scalar-load streaming in msg kernels)
__global__ __launch_bounds__(256) void prep_w(const float* __restrict__ W1,
                                              const float* __restrict__ W2,
                                              float* __restrict__ W1t,
                                              float* __restrict__ W2t) {
    int t = blockIdx.x * 256 + threadIdx.x;
    if (t < NR * HIDC * INC) {
        int r = t / (HIDC * INC), rem = t % (HIDC * INC);
        int c = rem / INC, in = rem % INC;
        W1t[t] = W1[(r * INC + in) * HIDC + c];
    }
    if (t < NR * OUTC * HIDC) {
        int r = t / (OUTC * HIDC), rem = t % (OUTC * HIDC);
        int c = rem / HIDC, in = rem % HIDC;
        W2t[t] = W2[(r * HIDC + in) * OUTC + c];
    }
}

// ---------------------------------------------------------------------------
// Per-(rel,dst) counts (for the mean), per-relation histogram (relation sort),
// per-dst histogram (dst CSR).
__global__ __launch_bounds__(256) void count_k(const int* __restrict__ ei,
                                               const int* __restrict__ et,
                                               unsigned* __restrict__ cnt,
                                               unsigned* __restrict__ hist,
                                               unsigned* __restrict__ dhist) {
    __shared__ unsigned lh[NR];
    int t = threadIdx.x;
    if (t < NR) lh[t] = 0;
    __syncthreads();
    int e = blockIdx.x * 256 + t;
    if (e < NE) {
        int r = et[e];
        int dst = ei[NE + e];
        if ((unsigned)r < NR && (unsigned)dst < NN) {
            atomicAdd(&cnt[(size_t)r * NN + dst], 1u);
            atomicAdd(&lh[r], 1u);
            atomicAdd(&dhist[dst], 1u);
        }
    }
    __syncthreads();
    if (t < NR && lh[t]) atomicAdd(&hist[t], lh[t]);
}

// 64-aligned exclusive prefix over 45 relation bins -> cursor (scatter heads)
__global__ void prefix_k(const unsigned* __restrict__ hist,
                         unsigned* __restrict__ cursor) {
    if (threadIdx.x == 0 && blockIdx.x == 0) {
        unsigned acc = 0;
        for (int r = 0; r < NR; ++r) {
            cursor[r] = acc;
            acc += ((hist[r] + 63u) >> 6) << 6;   // pad bucket to x64
        }
    }
}

// Exclusive prefix over NN dst bins -> rowptr[NN+1] and dcursor (scatter heads)
__global__ __launch_bounds__(256) void dprefix_k(const unsigned* __restrict__ dhist,
                                                 unsigned* __restrict__ rowptr,
                                                 unsigned* __restrict__ dcursor) {
    __shared__ unsigned ps[257];
    int t = threadIdx.x;
    const int CH = (NN + 255) / 256;
    int lo = t * CH, hi = lo + CH; if (hi > NN) hi = NN; if (lo > NN) lo = NN;
    unsigned s = 0;
    for (int i = lo; i < hi; ++i) s += dhist[i];
    ps[t + 1] = s;
    if (t == 0) ps[0] = 0;
    __syncthreads();
    if (t == 0) for (int i = 1; i <= 256; ++i) ps[i] += ps[i - 1];
    __syncthreads();
    unsigned run = ps[t];
    for (int i = lo; i < hi; ++i) {
        rowptr[i] = run; dcursor[i] = run;
        run += dhist[i];
    }
    if (t == 255) rowptr[NN] = run;
}

// Counting-sort scatter by relation. Packed record per relation-sorted slot:
//   pedges[pos] = {src, rel, bitcast(1/cnt), dpos}   (dpos = dst-sorted slot)
// Pad/tail slots keep memset zeros (scale==0 -> msg kernels redirect to dump).
__global__ __launch_bounds__(256) void scatter_k(const int* __restrict__ ei,
                                                 const int* __restrict__ et,
                                                 const unsigned* __restrict__ cnt,
                                                 unsigned* __restrict__ cursor,
                                                 unsigned* __restrict__ dcursor,
                                                 int4* __restrict__ pedges) {
    __shared__ unsigned lh[NR], lbase[NR], lcur[NR];
    int t = threadIdx.x;
    if (t < NR) { lh[t] = 0; lcur[t] = 0; }
    __syncthreads();
    int e = blockIdx.x * 256 + t;
    int r = -1, src = 0, dst = 0;
    if (e < NE) {
        r = et[e]; src = ei[e]; dst = ei[NE + e];
        if ((unsigned)r >= NR || (unsigned)src >= NN || (unsigned)dst >= NN) r = -1;
        if (r >= 0) atomicAdd(&lh[r], 1u);
    }
    __syncthreads();
    if (t < NR && lh[t]) lbase[t] = atomicAdd(&cursor[t], lh[t]);
    __syncthreads();
    if (r >= 0) {
        unsigned pos = lbase[r] + atomicAdd(&lcur[r], 1u);
        float sc = 1.0f / (float)cnt[(size_t)r * NN + dst];
        unsigned dpos = atomicAdd(&dcursor[dst], 1u);
        pedges[pos] = make_int4(src, r, __float_as_int(sc), (int)dpos);
    }
}

// ---------------------------------------------------------------------------
// Layer-1 messages. One lane per edge; one wave = 64 edges of ONE relation
// (bucket padding) -> W wave-uniform -> scalar loads. Row written in f16 at
// its DST-SORTED slot (64 B, sector-aligned) so gathers read sequentially.
__global__ __launch_bounds__(256) void msg1_k(const float* __restrict__ x,
                                              const float* __restrict__ W1t,
                                              const int4* __restrict__ pedges,
                                              __half* __restrict__ msg) {
    int wave = (blockIdx.x * 256 + threadIdx.x) >> 6;
    int lane = threadIdx.x & 63;
    if (wave >= NCHUNK) return;
    int e = (wave << 6) + lane;
    int4 er = pedges[e];
    int rel = __builtin_amdgcn_readfirstlane(er.y);       // wave-uniform
    const float* __restrict__ wr = W1t + (size_t)rel * (HIDC * INC);
    float sc = __int_as_float(er.z);
    int drow = (sc == 0.f) ? NE : er.w;                   // pads -> dump row
    const float4* __restrict__ xp = (const float4*)(x + (size_t)er.x * INC);
    float xv[INC];
    #pragma unroll
    for (int i = 0; i < INC / 4; ++i) {
        float4 q = xp[i];
        xv[4*i] = q.x; xv[4*i+1] = q.y; xv[4*i+2] = q.z; xv[4*i+3] = q.w;
    }
    unsigned um[HIDC / 2];
    #pragma unroll
    for (int c2 = 0; c2 < HIDC / 2; ++c2) {
        const float* __restrict__ w0 = wr + (2 * c2) * INC;
        const float* __restrict__ w1 = wr + (2 * c2 + 1) * INC;
        float a0 = 0.f, a1 = 0.f;
        #pragma unroll
        for (int i = 0; i < INC; ++i) {
            a0 = fmaf(xv[i], w0[i], a0);
            a1 = fmaf(xv[i], w1[i], a1);
        }
        union { __half2 h; unsigned u; } cv;
        cv.h = __floats2half2_rn(a0 * sc, a1 * sc);
        um[c2] = cv.u;
    }
    uint4* __restrict__ mrow = (uint4*)(msg + (size_t)drow * HIDC);
    #pragma unroll
    for (int q = 0; q < 4; ++q)
        mrow[q] = make_uint4(um[4*q], um[4*q+1], um[4*q+2], um[4*q+3]);
}

// Layer-2 messages (32 -> 16), f32 rows (64 B) at dst-sorted slots.
__global__ __launch_bounds__(256) void msg2_k(const float* __restrict__ h,
                                              const float* __restrict__ W2t,
                                              const int4* __restrict__ pedges,
                                              float* __restrict__ msg) {
    int wave = (blockIdx.x * 256 + threadIdx.x) >> 6;
    int lane = threadIdx.x & 63;
    if (wave >= NCHUNK) return;
    int e = (wave << 6) + lane;
    int4 er = pedges[e];
    int rel = __builtin_amdgcn_readfirstlane(er.y);
    const float* __restrict__ wr = W2t + (size_t)rel * (OUTC * HIDC);
    float sc = __int_as_float(er.z);
    int drow = (sc == 0.f) ? NE : er.w;
    const float4* __restrict__ hp = (const float4*)(h + (size_t)er.x * HIDC);
    float hv[HIDC];
    #pragma unroll
    for (int i = 0; i < HIDC / 4; ++i) {
        float4 q = hp[i];
        hv[4*i] = q.x; hv[4*i+1] = q.y; hv[4*i+2] = q.z; hv[4*i+3] = q.w;
    }
    float4* __restrict__ mrow = (float4*)(msg + (size_t)drow * OUTC);
    #pragma unroll
    for (int c4 = 0; c4 < OUTC / 4; ++c4) {
        float4 o;
        float* op = (float*)&o;
        #pragma unroll
        for (int j = 0; j < 4; ++j) {
            const float* __restrict__ wc = wr + (c4 * 4 + j) * HIDC;
            float a = 0.f;
            #pragma unroll
            for (int i = 0; i < HIDC; ++i) a = fmaf(hv[i], wc[i], a);
            op[j] = a * sc;
        }
        mrow[c4] = o;
    }
}

// ---------------------------------------------------------------------------
// Fused gather + node update 1: h = relu(sum(msg rows) + x @ root1 + b1).
// One wave per node. msg rows for this node are CONTIGUOUS (dst-sorted):
// lane = (sub, c2): sub in [0,4) streams k; c2 in [0,16) covers 32 ch as half2.
// Each load instruction reads 4 consecutive 64-B rows = 256 B coalesced.
__global__ __launch_bounds__(256) void gather1_k(const float* __restrict__ x,
                                                 const float* __restrict__ root1,
                                                 const float* __restrict__ b1,
                                                 const __half* __restrict__ msg,
                                                 const unsigned* __restrict__ rowptr,
                                                 float* __restrict__ h) {
    __shared__ float sr[INC * HIDC];   // 8 KB, [in][c]
    for (int k = threadIdx.x; k < INC * HIDC; k += 256) sr[k] = root1[k];
    __syncthreads();
    int wid = (blockIdx.x * 256 + threadIdx.x) >> 6;   // node id; grid exact
    int lane = threadIdx.x & 63;
    int c2 = lane & 15, sub = lane >> 4;
    unsigned k0 = rowptr[wid], k1 = rowptr[wid + 1];
    float accx = 0.f, accy = 0.f;
    for (unsigned k = k0 + sub; k < k1; k += 4) {
        union { __half2 hh; unsigned u; } cv;
        cv.u = ((const unsigned*)(msg + (size_t)k * HIDC))[c2];
        float2 f = __half22float2(cv.hh);
        accx += f.x; accy += f.y;
    }
    // root contribution: sub handles input range [sub*16, sub*16+16)
    const float4* __restrict__ xp = (const float4*)(x + (size_t)wid * INC + sub * 16);
    #pragma unroll
    for (int q = 0; q < 4; ++q) {
        float4 xr = xp[q];
        const float* xs = (const float*)&xr;
        #pragma unroll
        for (int j = 0; j < 4; ++j) {
            int in = sub * 16 + q * 4 + j;
            float2 rt = *(const float2*)&sr[in * HIDC + 2 * c2];
            accx = fmaf(xs[j], rt.x, accx);
            accy = fmaf(xs[j], rt.y, accy);
        }
    }
    accx += __shfl_xor(accx, 16); accy += __shfl_xor(accy, 16);
    accx += __shfl_xor(accx, 32); accy += __shfl_xor(accy, 32);
    if (sub == 0) {
        float2 bb = *(const float2*)&b1[2 * c2];
        float vx = accx + bb.x, vy = accy + bb.y;
        float2 o = make_float2(vx > 0.f ? vx : 0.f, vy > 0.f ? vy : 0.f);
        *(float2*)&h[(size_t)wid * HIDC + 2 * c2] = o;
    }
}

// Fused gather + node update 2: out = sum(msg rows) + h @ root2 + b2.
// One wave per node; c2 in [0,8) covers 16 ch as float2; sub in [0,8) streams k.
__global__ __launch_bounds__(256) void gather2_k(const float* __restrict__ h,
                                                 const float* __restrict__ root2,
                                                 const float* __restrict__ b2,
                                                 const float* __restrict__ msg,
                                                 const unsigned* __restrict__ rowptr,
                                                 float* __restrict__ out) {
    __shared__ float sr[HIDC * OUTC];  // 2 KB, [in][c]
    for (int k = threadIdx.x; k < HIDC * OUTC; k += 256) sr[k] = root2[k];
    __syncthreads();
    int wid = (blockIdx.x * 256 + threadIdx.x) >> 6;
    int lane = threadIdx.x & 63;
    int c2 = lane & 7, sub = lane >> 3;   // 8 streams
    unsigned k0 = rowptr[wid], k1 = rowptr[wid + 1];
    float accx = 0.f, accy = 0.f;
    for (unsigned k = k0 + sub; k < k1; k += 8) {
        float2 f = ((const float2*)(msg + (size_t)k * OUTC))[c2];
        accx += f.x; accy += f.y;
    }
    // root contribution: sub handles input range [sub*4, sub*4+4)
    const float4* __restrict__ hp = (const float4*)(h + (size_t)wid * HIDC + sub * 4);
    float4 hr = hp[0];
    const float* hs = (const float*)&hr;
    #pragma unroll
    for (int j = 0; j < 4; ++j) {
        int in = sub * 4 + j;
        float2 rt = *(const float2*)&sr[in * OUTC + 2 * c2];
        accx = fmaf(hs[j], rt.x, accx);
        accy = fmaf(hs[j], rt.y, accy);
    }
    accx += __shfl_xor(accx, 8);  accy += __shfl_xor(accy, 8);
    accx += __shfl_xor(accx, 16); accy += __shfl_xor(accy, 16);
    accx += __shfl_xor(accx, 32); accy += __shfl_xor(accy, 32);
    if (sub == 0) {
        float2 bb = *(const float2*)&b2[2 * c2];
        *(float2*)&out[(size_t)wid * OUTC + 2 * c2] =
            make_float2(accx + bb.x, accy + bb.y);
    }
}

// ---------------------------------------------------------------------------
extern "C" void kernel_launch(void* const* d_in, const int* in_sizes, int n_in,
                              void* d_out, int out_size, void* d_ws, size_t ws_size,
                              hipStream_t stream) {
    const float* x     = (const float*)d_in[0];
    const int*   ei    = (const int*)d_in[1];   // [2, NE]
    const int*   et    = (const int*)d_in[2];   // [NE]
    const float* W1    = (const float*)d_in[3];
    const float* root1 = (const float*)d_in[4];
    const float* b1    = (const float*)d_in[5];
    const float* W2    = (const float*)d_in[6];
    const float* root2 = (const float*)d_in[7];
    const float* b2    = (const float*)d_in[8];
    float* out = (float*)d_out;

    char* ws = (char*)d_ws;
    size_t o = 0;
    auto alloc = [&](size_t bytes) -> char* {
        char* p = ws + o;
        o = (o + bytes + 255) & ~(size_t)255;
        return p;
    };
    // --- region that must start zeroed (one contiguous memset, ~28.5 MB) ---
    unsigned* cnt    = (unsigned*)alloc((size_t)NR * NN * 4);      // 9.0 MB
    unsigned* hist   = (unsigned*)alloc(NR * 4);
    unsigned* dhist  = (unsigned*)alloc((size_t)NN * 4);           // 0.2 MB
    int4*     pedges = (int4*)    alloc((size_t)MAXE * 16);        // 19.2 MB
    size_t zero_bytes = o;
    // --- regions fully written before read ---
    unsigned* cursor = (unsigned*)alloc(NR * 4);
    unsigned* rowptr = (unsigned*)alloc(((size_t)NN + 1) * 4);
    unsigned* dcursor= (unsigned*)alloc((size_t)NN * 4);
    float*    W1t    = (float*)   alloc((size_t)NR * HIDC * INC * 4);
    float*    W2t    = (float*)   alloc((size_t)NR * OUTC * HIDC * 4);
    float*    h      = (float*)   alloc((size_t)NN * HIDC * 4);    // 6.4 MB
    // msg buffers alias: msg1 (f16, NE+1 rows x 64 B) fully consumed by
    // gather1 before msg2 (f32, NE+1 rows x 64 B) is produced.
    char*     msgraw = alloc(((size_t)NE + 1) * 64);               // 76.9 MB
    __half*   msg1   = (__half*)msgraw;
    float*    msg2   = (float*)msgraw;

    hipMemsetAsync(d_ws, 0, zero_bytes, stream);
    prep_w   <<<(NR * HIDC * INC + 255) / 256, 256, 0, stream>>>(W1, W2, W1t, W2t);
    count_k  <<<(NE + 255) / 256, 256, 0, stream>>>(ei, et, cnt, hist, dhist);
    prefix_k <<<1, 64, 0, stream>>>(hist, cursor);
    dprefix_k<<<1, 256, 0, stream>>>(dhist, rowptr, dcursor);
    scatter_k<<<(NE + 255) / 256, 256, 0, stream>>>(ei, et, cnt, cursor, dcursor, pedges);
    msg1_k   <<<(MAXE + 255) / 256, 256, 0, stream>>>(x, W1t, pedges, msg1);
    gather1_k<<<NN * 64 / 256, 256, 0, stream>>>(x, root1, b1, msg1, rowptr, h);
    msg2_k   <<<(MAXE + 255) / 256, 256, 0, stream>>>(h, W2t, pedges, msg2);
    gather2_k<<<NN * 64 / 256, 256, 0, stream>>>(h, root2, b2, msg2, rowptr, out);
}

// Round 4
// 621.965 us; speedup vs baseline: 6.4763x; 1.1893x over previous
//
#include <hip/hip_runtime.h>
#include <hip/hip_fp16.h>
#include <cstdint>
#include <cstddef>

// Problem constants (match reference setup_inputs)
#define NN   50000      // nodes
#define NE   1200000    // edges
#define NR   45         // relations
#define INC  64
#define HIDC 32
#define OUTC 16
// Padded edge capacity: each relation bucket padded to multiple of 64 so every
// wave's 64 edges share one relation. NE + NR*64, itself a multiple of 64.
#define MAXE 1202880
#define NCHUNK (MAXE/64)

// f16 pair type + dot2 accumulate (v_dot2_f32_f16 when available)
typedef _Float16 half2v __attribute__((ext_vector_type(2)));

#if defined(__has_builtin)
#  if __has_builtin(__builtin_amdgcn_fdot2)
#    define HAS_FDOT2 1
#  endif
#endif
#ifndef HAS_FDOT2
#  define HAS_FDOT2 0
#endif

__device__ __forceinline__ float dot2acc(half2v a, half2v b, float c) {
#if HAS_FDOT2
    return __builtin_amdgcn_fdot2(a, b, c, false);
#else
    return fmaf((float)a.x, (float)b.x, fmaf((float)a.y, (float)b.y, c));
#endif
}

// ---------------------------------------------------------------------------
// W1 -> W1th[r][c][in] (f16), W2 -> W2th[r][c][in] (f16): channel-major so the
// msg kernels stream weight columns via wave-uniform scalar loads.
__global__ __launch_bounds__(256) void prep_w(const float* __restrict__ W1,
                                              const float* __restrict__ W2,
                                              __half* __restrict__ W1th,
                                              __half* __restrict__ W2th) {
    int t = blockIdx.x * 256 + threadIdx.x;
    if (t < NR * HIDC * INC) {
        int r = t / (HIDC * INC), rem = t % (HIDC * INC);
        int c = rem / INC, in = rem % INC;
        W1th[t] = __float2half(W1[(r * INC + in) * HIDC + c]);
    }
    if (t < NR * OUTC * HIDC) {
        int r = t / (OUTC * HIDC), rem = t % (OUTC * HIDC);
        int c = rem / HIDC, in = rem % HIDC;
        W2th[t] = __float2half(W2[(r * HIDC + in) * OUTC + c]);
    }
}

// Cast x (f32) -> xh (f16), pairwise.
__global__ __launch_bounds__(256) void cast_x(const float* __restrict__ x,
                                              __half* __restrict__ xh) {
    int t = blockIdx.x * 256 + threadIdx.x;   // NN*INC/2 exact multiple of 256
    float2 f = ((const float2*)x)[t];
    union { __half2 h; unsigned u; } cv;
    cv.h = __floats2half2_rn(f.x, f.y);
    ((unsigned*)xh)[t] = cv.u;
}

// ---------------------------------------------------------------------------
// Per-(rel,dst) counts (for the mean), per-relation histogram (relation sort),
// per-dst histogram (dst CSR).
__global__ __launch_bounds__(256) void count_k(const int* __restrict__ ei,
                                               const int* __restrict__ et,
                                               unsigned* __restrict__ cnt,
                                               unsigned* __restrict__ hist,
                                               unsigned* __restrict__ dhist) {
    __shared__ unsigned lh[NR];
    int t = threadIdx.x;
    if (t < NR) lh[t] = 0;
    __syncthreads();
    int e = blockIdx.x * 256 + t;
    if (e < NE) {
        int r = et[e];
        int dst = ei[NE + e];
        if ((unsigned)r < NR && (unsigned)dst < NN) {
            atomicAdd(&cnt[(size_t)r * NN + dst], 1u);
            atomicAdd(&lh[r], 1u);
            atomicAdd(&dhist[dst], 1u);
        }
    }
    __syncthreads();
    if (t < NR && lh[t]) atomicAdd(&hist[t], lh[t]);
}

// 64-aligned exclusive prefix over 45 relation bins -> cursor (scatter heads)
__global__ void prefix_k(const unsigned* __restrict__ hist,
                         unsigned* __restrict__ cursor) {
    if (threadIdx.x == 0 && blockIdx.x == 0) {
        unsigned acc = 0;
        for (int r = 0; r < NR; ++r) {
            cursor[r] = acc;
            acc += ((hist[r] + 63u) >> 6) << 6;   // pad bucket to x64
        }
    }
}

// Exclusive prefix over NN dst bins -> rowptr[NN+1] and dcursor (scatter heads)
__global__ __launch_bounds__(256) void dprefix_k(const unsigned* __restrict__ dhist,
                                                 unsigned* __restrict__ rowptr,
                                                 unsigned* __restrict__ dcursor) {
    __shared__ unsigned ps[257];
    int t = threadIdx.x;
    const int CH = (NN + 255) / 256;
    int lo = t * CH, hi = lo + CH; if (hi > NN) hi = NN; if (lo > NN) lo = NN;
    unsigned s = 0;
    for (int i = lo; i < hi; ++i) s += dhist[i];
    ps[t + 1] = s;
    if (t == 0) ps[0] = 0;
    __syncthreads();
    if (t == 0) for (int i = 1; i <= 256; ++i) ps[i] += ps[i - 1];
    __syncthreads();
    unsigned run = ps[t];
    for (int i = lo; i < hi; ++i) {
        rowptr[i] = run; dcursor[i] = run;
        run += dhist[i];
    }
    if (t == 255) rowptr[NN] = run;
}

// Counting-sort scatter by relation. Packed record per relation-sorted slot:
//   pedges[pos] = {src, rel, bitcast(1/cnt), dpos}   (dpos = dst-sorted slot)
// Pad/tail slots keep memset zeros (scale==0 -> msg kernels redirect to dump).
__global__ __launch_bounds__(256) void scatter_k(const int* __restrict__ ei,
                                                 const int* __restrict__ et,
                                                 const unsigned* __restrict__ cnt,
                                                 unsigned* __restrict__ cursor,
                                                 unsigned* __restrict__ dcursor,
                                                 int4* __restrict__ pedges) {
    __shared__ unsigned lh[NR], lbase[NR], lcur[NR];
    int t = threadIdx.x;
    if (t < NR) { lh[t] = 0; lcur[t] = 0; }
    __syncthreads();
    int e = blockIdx.x * 256 + t;
    int r = -1, src = 0, dst = 0;
    if (e < NE) {
        r = et[e]; src = ei[e]; dst = ei[NE + e];
        if ((unsigned)r >= NR || (unsigned)src >= NN || (unsigned)dst >= NN) r = -1;
        if (r >= 0) atomicAdd(&lh[r], 1u);
    }
    __syncthreads();
    if (t < NR && lh[t]) lbase[t] = atomicAdd(&cursor[t], lh[t]);
    __syncthreads();
    if (r >= 0) {
        unsigned pos = lbase[r] + atomicAdd(&lcur[r], 1u);
        float sc = 1.0f / (float)cnt[(size_t)r * NN + dst];
        unsigned dpos = atomicAdd(&dcursor[dst], 1u);
        pedges[pos] = make_int4(src, r, __float_as_int(sc), (int)dpos);
    }
}

// ---------------------------------------------------------------------------
// Layer-1 messages. One lane per edge; one wave = 64 edges of ONE relation
// (bucket padding) -> W wave-uniform -> scalar loads. x in f16 (128-B row,
// 8 loads), inner loop = 1024 v_dot2_f32_f16. Row written in f16 at its
// DST-SORTED slot (64 B) so gathers read sequentially.
__global__ __launch_bounds__(256) void msg1_k(const __half* __restrict__ xh,
                                              const __half* __restrict__ W1th,
                                              const int4* __restrict__ pedges,
                                              __half* __restrict__ msg) {
    int wave = (blockIdx.x * 256 + threadIdx.x) >> 6;
    int lane = threadIdx.x & 63;
    if (wave >= NCHUNK) return;
    int e = (wave << 6) + lane;
    int4 er = pedges[e];
    int rel = __builtin_amdgcn_readfirstlane(er.y);       // wave-uniform
    const _Float16* __restrict__ wr =
        (const _Float16*)W1th + (size_t)rel * (HIDC * INC);
    float sc = __int_as_float(er.z);
    int drow = (sc == 0.f) ? NE : er.w;                   // pads -> dump row
    half2v xv[INC / 2];
    const uint4* __restrict__ xp = (const uint4*)(xh + (size_t)er.x * INC);
    #pragma unroll
    for (int i = 0; i < INC / 8; ++i) ((uint4*)xv)[i] = xp[i];
    unsigned um[HIDC / 2];
    #pragma unroll
    for (int c2 = 0; c2 < HIDC / 2; ++c2) {
        const half2v* __restrict__ w0 = (const half2v*)(wr + (2 * c2) * INC);
        const half2v* __restrict__ w1 = (const half2v*)(wr + (2 * c2 + 1) * INC);
        float a0 = 0.f, a1 = 0.f;
        #pragma unroll
        for (int i = 0; i < INC / 2; ++i) {
            a0 = dot2acc(xv[i], w0[i], a0);
            a1 = dot2acc(xv[i], w1[i], a1);
        }
        union { __half2 h; unsigned u; } cv;
        cv.h = __floats2half2_rn(a0 * sc, a1 * sc);
        um[c2] = cv.u;
    }
    uint4* __restrict__ mrow = (uint4*)(msg + (size_t)drow * HIDC);
    #pragma unroll
    for (int q = 0; q < 4; ++q)
        mrow[q] = make_uint4(um[4*q], um[4*q+1], um[4*q+2], um[4*q+3]);
}

// Layer-2 messages (32 -> 16). h f16 (3.2 MB: L2-resident), 256 dot2/edge,
// f16 rows (32 B) at dst-sorted slots.
__global__ __launch_bounds__(256) void msg2_k(const __half* __restrict__ hh,
                                              const __half* __restrict__ W2th,
                                              const int4* __restrict__ pedges,
                                              __half* __restrict__ msg) {
    int wave = (blockIdx.x * 256 + threadIdx.x) >> 6;
    int lane = threadIdx.x & 63;
    if (wave >= NCHUNK) return;
    int e = (wave << 6) + lane;
    int4 er = pedges[e];
    int rel = __builtin_amdgcn_readfirstlane(er.y);
    const _Float16* __restrict__ wr =
        (const _Float16*)W2th + (size_t)rel * (OUTC * HIDC);
    float sc = __int_as_float(er.z);
    int drow = (sc == 0.f) ? NE : er.w;
    half2v hv[HIDC / 2];
    const uint4* __restrict__ hp = (const uint4*)(hh + (size_t)er.x * HIDC);
    #pragma unroll
    for (int i = 0; i < HIDC / 8; ++i) ((uint4*)hv)[i] = hp[i];
    unsigned um[OUTC / 2];
    #pragma unroll
    for (int c2 = 0; c2 < OUTC / 2; ++c2) {
        const half2v* __restrict__ w0 = (const half2v*)(wr + (2 * c2) * HIDC);
        const half2v* __restrict__ w1 = (const half2v*)(wr + (2 * c2 + 1) * HIDC);
        float a0 = 0.f, a1 = 0.f;
        #pragma unroll
        for (int i = 0; i < HIDC / 2; ++i) {
            a0 = dot2acc(hv[i], w0[i], a0);
            a1 = dot2acc(hv[i], w1[i], a1);
        }
        union { __half2 h; unsigned u; } cv;
        cv.h = __floats2half2_rn(a0 * sc, a1 * sc);
        um[c2] = cv.u;
    }
    uint4* __restrict__ mrow = (uint4*)(msg + (size_t)drow * OUTC);
    mrow[0] = make_uint4(um[0], um[1], um[2], um[3]);
    mrow[1] = make_uint4(um[4], um[5], um[6], um[7]);
}

// ---------------------------------------------------------------------------
// Fused gather + node update 1: h = relu(sum(msg rows) + x @ root1 + b1), f16 out.
// One wave per node; msg rows contiguous (dst-sorted). lane = (sub,c2):
// sub in [0,4) streams k, c2 in [0,16) covers 32 ch as half2.
__global__ __launch_bounds__(256) void gather1_k(const float* __restrict__ x,
                                                 const float* __restrict__ root1,
                                                 const float* __restrict__ b1,
                                                 const __half* __restrict__ msg,
                                                 const unsigned* __restrict__ rowptr,
                                                 __half* __restrict__ hh) {
    __shared__ float sr[INC * HIDC];   // 8 KB, [in][c]
    for (int k = threadIdx.x; k < INC * HIDC; k += 256) sr[k] = root1[k];
    __syncthreads();
    int wid = (blockIdx.x * 256 + threadIdx.x) >> 6;   // node id; grid exact
    int lane = threadIdx.x & 63;
    int c2 = lane & 15, sub = lane >> 4;
    unsigned k0 = rowptr[wid], k1 = rowptr[wid + 1];
    float accx = 0.f, accy = 0.f;
    for (unsigned k = k0 + sub; k < k1; k += 4) {
        union { __half2 hh2; unsigned u; } cv;
        cv.u = ((const unsigned*)(msg + (size_t)k * HIDC))[c2];
        float2 f = __half22float2(cv.hh2);
        accx += f.x; accy += f.y;
    }
    // root contribution: sub handles input range [sub*16, sub*16+16)
    const float4* __restrict__ xp = (const float4*)(x + (size_t)wid * INC + sub * 16);
    #pragma unroll
    for (int q = 0; q < 4; ++q) {
        float4 xr = xp[q];
        const float* xs = (const float*)&xr;
        #pragma unroll
        for (int j = 0; j < 4; ++j) {
            int in = sub * 16 + q * 4 + j;
            float2 rt = *(const float2*)&sr[in * HIDC + 2 * c2];
            accx = fmaf(xs[j], rt.x, accx);
            accy = fmaf(xs[j], rt.y, accy);
        }
    }
    accx += __shfl_xor(accx, 16); accy += __shfl_xor(accy, 16);
    accx += __shfl_xor(accx, 32); accy += __shfl_xor(accy, 32);
    if (sub == 0) {
        float2 bb = *(const float2*)&b1[2 * c2];
        float vx = accx + bb.x, vy = accy + bb.y;
        union { __half2 h2; unsigned u; } cv;
        cv.h2 = __floats2half2_rn(vx > 0.f ? vx : 0.f, vy > 0.f ? vy : 0.f);
        ((unsigned*)hh)[(size_t)wid * (HIDC / 2) + c2] = cv.u;
    }
}

// Fused gather + node update 2: out = sum(msg rows) + h @ root2 + b2 (f32 out).
// One wave per node; c2 in [0,8) covers 16 ch as half2; sub in [0,8) streams k.
__global__ __launch_bounds__(256) void gather2_k(const __half* __restrict__ hh,
                                                 const float* __restrict__ root2,
                                                 const float* __restrict__ b2,
                                                 const __half* __restrict__ msg,
                                                 const unsigned* __restrict__ rowptr,
                                                 float* __restrict__ out) {
    __shared__ float sr[HIDC * OUTC];  // 2 KB, [in][c]
    for (int k = threadIdx.x; k < HIDC * OUTC; k += 256) sr[k] = root2[k];
    __syncthreads();
    int wid = (blockIdx.x * 256 + threadIdx.x) >> 6;
    int lane = threadIdx.x & 63;
    int c2 = lane & 7, sub = lane >> 3;   // 8 streams
    unsigned k0 = rowptr[wid], k1 = rowptr[wid + 1];
    float accx = 0.f, accy = 0.f;
    for (unsigned k = k0 + sub; k < k1; k += 8) {
        union { __half2 hh2; unsigned u; } cv;
        cv.u = ((const unsigned*)(msg + (size_t)k * OUTC))[c2];
        float2 f = __half22float2(cv.hh2);
        accx += f.x; accy += f.y;
    }
    // root contribution: sub handles input range [sub*4, sub*4+4)
    uint2 hw = *(const uint2*)(hh + (size_t)wid * HIDC + sub * 4);
    union { __half2 h2; unsigned u; } ca, cb;
    ca.u = hw.x; cb.u = hw.y;
    float2 ha = __half22float2(ca.h2), hb = __half22float2(cb.h2);
    float hs[4] = { ha.x, ha.y, hb.x, hb.y };
    #pragma unroll
    for (int j = 0; j < 4; ++j) {
        int in = sub * 4 + j;
        float2 rt = *(const float2*)&sr[in * OUTC + 2 * c2];
        accx = fmaf(hs[j], rt.x, accx);
        accy = fmaf(hs[j], rt.y, accy);
    }
    accx += __shfl_xor(accx, 8);  accy += __shfl_xor(accy, 8);
    accx += __shfl_xor(accx, 16); accy += __shfl_xor(accy, 16);
    accx += __shfl_xor(accx, 32); accy += __shfl_xor(accy, 32);
    if (sub == 0) {
        float2 bb = *(const float2*)&b2[2 * c2];
        *(float2*)&out[(size_t)wid * OUTC + 2 * c2] =
            make_float2(accx + bb.x, accy + bb.y);
    }
}

// ---------------------------------------------------------------------------
extern "C" void kernel_launch(void* const* d_in, const int* in_sizes, int n_in,
                              void* d_out, int out_size, void* d_ws, size_t ws_size,
                              hipStream_t stream) {
    const float* x     = (const float*)d_in[0];
    const int*   ei    = (const int*)d_in[1];   // [2, NE]
    const int*   et    = (const int*)d_in[2];   // [NE]
    const float* W1    = (const float*)d_in[3];
    const float* root1 = (const float*)d_in[4];
    const float* b1    = (const float*)d_in[5];
    const float* W2    = (const float*)d_in[6];
    const float* root2 = (const float*)d_in[7];
    const float* b2    = (const float*)d_in[8];
    float* out = (float*)d_out;

    char* ws = (char*)d_ws;
    size_t o = 0;
    auto alloc = [&](size_t bytes) -> char* {
        char* p = ws + o;
        o = (o + bytes + 255) & ~(size_t)255;
        return p;
    };
    // --- region that must start zeroed (one contiguous memset, ~28.5 MB) ---
    unsigned* cnt    = (unsigned*)alloc((size_t)NR * NN * 4);      // 9.0 MB
    unsigned* hist   = (unsigned*)alloc(NR * 4);
    unsigned* dhist  = (unsigned*)alloc((size_t)NN * 4);           // 0.2 MB
    int4*     pedges = (int4*)    alloc((size_t)MAXE * 16);        // 19.2 MB
    size_t zero_bytes = o;
    // --- regions fully written before read ---
    unsigned* cursor = (unsigned*)alloc(NR * 4);
    unsigned* rowptr = (unsigned*)alloc(((size_t)NN + 1) * 4);
    unsigned* dcursor= (unsigned*)alloc((size_t)NN * 4);
    __half*   W1th   = (__half*)  alloc((size_t)NR * HIDC * INC * 2);  // 184 KB
    __half*   W2th   = (__half*)  alloc((size_t)NR * OUTC * HIDC * 2); //  46 KB
    __half*   xh     = (__half*)  alloc((size_t)NN * INC * 2);     // 6.4 MB
    __half*   hh     = (__half*)  alloc((size_t)NN * HIDC * 2);    // 3.2 MB
    // msg buffers alias: msg1 (f16, 64-B rows) fully consumed by gather1
    // before msg2 (f16, 32-B rows) is produced.
    char*     msgraw = alloc(((size_t)NE + 1) * 64);               // 76.9 MB
    __half*   msg1   = (__half*)msgraw;
    __half*   msg2   = (__half*)msgraw;

    hipMemsetAsync(d_ws, 0, zero_bytes, stream);
    prep_w   <<<(NR * HIDC * INC + 255) / 256, 256, 0, stream>>>(W1, W2, W1th, W2th);
    cast_x   <<<NN * INC / 2 / 256, 256, 0, stream>>>(x, xh);
    count_k  <<<(NE + 255) / 256, 256, 0, stream>>>(ei, et, cnt, hist, dhist);
    prefix_k <<<1, 64, 0, stream>>>(hist, cursor);
    dprefix_k<<<1, 256, 0, stream>>>(dhist, rowptr, dcursor);
    scatter_k<<<(NE + 255) / 256, 256, 0, stream>>>(ei, et, cnt, cursor, dcursor, pedges);
    msg1_k   <<<(MAXE + 255) / 256, 256, 0, stream>>>(xh, W1th, pedges, msg1);
    gather1_k<<<NN * 64 / 256, 256, 0, stream>>>(x, root1, b1, msg1, rowptr, hh);
    msg2_k   <<<(MAXE + 255) / 256, 256, 0, stream>>>(hh, W2th, pedges, msg2);
    gather2_k<<<NN * 64 / 256, 256, 0, stream>>>(hh, root2, b2, msg2, rowptr, out);
}

// Round 5
// 530.239 us; speedup vs baseline: 7.5967x; 1.1730x over previous
//
#include <hip/hip_runtime.h>
#include <hip/hip_fp16.h>
#include <cstdint>
#include <cstddef>

// Problem constants (match reference setup_inputs)
#define NN   50000      // nodes  (< 65536: src fits 16 bits)
#define NE   1200000    // edges  (< 2^21: dpos fits 21 bits)
#define NR   45         // relations (< 64: rel fits 6 bits)
#define INC  64
#define HIDC 32
#define OUTC 16
// Padded edge capacity: each relation bucket padded to multiple of 64 so every
// wave's 64 edges share one relation. NE + NR*64, itself a multiple of 64.
#define MAXE 1202880
#define NCHUNK (MAXE/64)

// f16 pair type + dot2 accumulate (v_dot2_f32_f16 when available)
typedef _Float16 half2v __attribute__((ext_vector_type(2)));

#if defined(__has_builtin)
#  if __has_builtin(__builtin_amdgcn_fdot2)
#    define HAS_FDOT2 1
#  endif
#endif
#ifndef HAS_FDOT2
#  define HAS_FDOT2 0
#endif

__device__ __forceinline__ float dot2acc(half2v a, half2v b, float c) {
#if HAS_FDOT2
    return __builtin_amdgcn_fdot2(a, b, c, false);
#else
    return fmaf((float)a.x, (float)b.x, fmaf((float)a.y, (float)b.y, c));
#endif
}

union F16Bits { unsigned short u; _Float16 f; };

// ---------------------------------------------------------------------------
// W1 -> W1th[r][c][in] (f16), W2 -> W2th[r][c][in] (f16): channel-major so the
// msg kernels stream weight columns via wave-uniform scalar loads.
__global__ __launch_bounds__(256) void prep_w(const float* __restrict__ W1,
                                              const float* __restrict__ W2,
                                              __half* __restrict__ W1th,
                                              __half* __restrict__ W2th) {
    int t = blockIdx.x * 256 + threadIdx.x;
    if (t < NR * HIDC * INC) {
        int r = t / (HIDC * INC), rem = t % (HIDC * INC);
        int c = rem / INC, in = rem % INC;
        W1th[t] = __float2half(W1[(r * INC + in) * HIDC + c]);
    }
    if (t < NR * OUTC * HIDC) {
        int r = t / (OUTC * HIDC), rem = t % (OUTC * HIDC);
        int c = rem / HIDC, in = rem % HIDC;
        W2th[t] = __float2half(W2[(r * HIDC + in) * OUTC + c]);
    }
}

// Cast x (f32) -> xh (f16), pairwise.
__global__ __launch_bounds__(256) void cast_x(const float* __restrict__ x,
                                              __half* __restrict__ xh) {
    int t = blockIdx.x * 256 + threadIdx.x;   // NN*INC/2 exact multiple of 256
    float2 f = ((const float2*)x)[t];
    union { __half2 h; unsigned u; } cv;
    cv.h = __floats2half2_rn(f.x, f.y);
    ((unsigned*)xh)[t] = cv.u;
}

// ---------------------------------------------------------------------------
// Per-(rel,dst) counts via device atomics; the atomic RETURN VALUE is the
// edge's rank within its (rel,dst) group (stored coalesced by edge id).
// Per-relation histogram aggregated in LDS (tiny device-atomic count).
__global__ __launch_bounds__(256) void count_k(const int* __restrict__ ei,
                                               const int* __restrict__ et,
                                               unsigned* __restrict__ cnt,
                                               unsigned* __restrict__ hist,
                                               unsigned* __restrict__ rank) {
    __shared__ unsigned lh[NR];
    int t = threadIdx.x;
    if (t < NR) lh[t] = 0;
    __syncthreads();
    int e = blockIdx.x * 256 + t;
    if (e < NE) {
        int r = et[e];
        int dst = ei[NE + e];
        if ((unsigned)r < NR && (unsigned)dst < NN) {
            rank[e] = atomicAdd(&cnt[(size_t)r * NN + dst], 1u);
            atomicAdd(&lh[r], 1u);
        }
    }
    __syncthreads();
    if (t < NR && lh[t]) atomicAdd(&hist[t], lh[t]);
}

// 64-aligned exclusive prefix over 45 relation bins -> cursor (scatter heads)
__global__ void prefix_k(const unsigned* __restrict__ hist,
                         unsigned* __restrict__ cursor) {
    if (threadIdx.x == 0 && blockIdx.x == 0) {
        unsigned acc = 0;
        for (int r = 0; r < NR; ++r) {
            cursor[r] = acc;
            acc += ((hist[r] + 63u) >> 6) << 6;   // pad bucket to x64
        }
    }
}

// Per-dst: relation-prefix offsets + f16 inverse counts, packed one word per
// (r,dst): {reloff:16 | f16(1/cnt):16}. Also derives dhist[dst] = degree.
// NOTE: reloff is the intra-dst prefix, bounded by deg(dst) — assumed < 65536
// (this graph: ~24 avg, <100 max).
__global__ __launch_bounds__(256) void drel_k(const unsigned* __restrict__ cnt,
                                              unsigned* __restrict__ packed,
                                              unsigned* __restrict__ dhist) {
    int dst = blockIdx.x * 256 + threadIdx.x;
    if (dst >= NN) return;
    unsigned run = 0;
    #pragma unroll 5
    for (int r = 0; r < NR; ++r) {
        unsigned c = cnt[(size_t)r * NN + dst];
        F16Bits fb; fb.f = (_Float16)(c ? 1.0f / (float)c : 0.0f);
        packed[(size_t)r * NN + dst] = (run & 0xFFFFu) | ((unsigned)fb.u << 16);
        run += c;
    }
    dhist[dst] = run;
}

// Exclusive prefix over NN dst bins -> rowptr[NN+1]
__global__ __launch_bounds__(256) void dprefix_k(const unsigned* __restrict__ dhist,
                                                 unsigned* __restrict__ rowptr) {
    __shared__ unsigned ps[257];
    int t = threadIdx.x;
    const int CH = (NN + 255) / 256;
    int lo = t * CH, hi = lo + CH; if (hi > NN) hi = NN; if (lo > NN) lo = NN;
    unsigned s = 0;
    for (int i = lo; i < hi; ++i) s += dhist[i];
    ps[t + 1] = s;
    if (t == 0) ps[0] = 0;
    __syncthreads();
    if (t == 0) for (int i = 1; i <= 256; ++i) ps[i] += ps[i - 1];
    __syncthreads();
    unsigned run = ps[t];
    for (int i = lo; i < hi; ++i) {
        rowptr[i] = run;
        run += dhist[i];
    }
    if (t == 255) rowptr[NN] = run;
}

// Stream-init all edge records to PAD (bit31 of word1 set). Real slots are
// overwritten by scatter_k; remaining pads route msg output to the dump row.
__global__ __launch_bounds__(256) void initp_k(uint4* __restrict__ pedges2) {
    int t = blockIdx.x * 256 + threadIdx.x;   // covers 2 records per thread
    if (t < MAXE / 2)
        pedges2[t] = make_uint4(0u, 0x80000000u, 0u, 0x80000000u);
}

// Counting-sort scatter by relation — ZERO device atomics for dpos:
//   dpos = rowptr[dst] + reloff(r,dst) + rank[e]   (deterministic)
// Record: word0 = src | scale_f16<<16 ; word1 = dpos | rel<<25  (bit31 clear)
__global__ __launch_bounds__(256) void scatter_k(const int* __restrict__ ei,
                                                 const int* __restrict__ et,
                                                 const unsigned* __restrict__ packed,
                                                 const unsigned* __restrict__ rowptr,
                                                 const unsigned* __restrict__ rank,
                                                 unsigned* __restrict__ cursor,
                                                 uint2* __restrict__ pedges) {
    __shared__ unsigned lh[NR], lbase[NR], lcur[NR];
    int t = threadIdx.x;
    if (t < NR) { lh[t] = 0; lcur[t] = 0; }
    __syncthreads();
    int e = blockIdx.x * 256 + t;
    int r = -1, src = 0, dst = 0;
    if (e < NE) {
        r = et[e]; src = ei[e]; dst = ei[NE + e];
        if ((unsigned)r >= NR || (unsigned)src >= NN || (unsigned)dst >= NN) r = -1;
        if (r >= 0) atomicAdd(&lh[r], 1u);
    }
    __syncthreads();
    if (t < NR && lh[t]) lbase[t] = atomicAdd(&cursor[t], lh[t]);
    __syncthreads();
    if (r >= 0) {
        unsigned pos = lbase[r] + atomicAdd(&lcur[r], 1u);   // LDS atomic
        unsigned pk = packed[(size_t)r * NN + dst];
        unsigned dpos = rowptr[dst] + (pk & 0xFFFFu) + rank[e];
        pedges[pos] = make_uint2((unsigned)src | (pk & 0xFFFF0000u),
                                 dpos | ((unsigned)r << 25));
    }
}

// ---------------------------------------------------------------------------
// Layer-1 messages. One lane per edge; one wave = 64 edges of ONE relation
// (bucket padding) -> W wave-uniform -> scalar loads. x in f16 (128-B row),
// inner loop = 1024 v_dot2_f32_f16. Row written in f16 at its DST-SORTED slot
// (64 B) so gathers read sequentially.
__global__ __launch_bounds__(256) void msg1_k(const __half* __restrict__ xh,
                                              const __half* __restrict__ W1th,
                                              const uint2* __restrict__ pedges,
                                              __half* __restrict__ msg) {
    int wave = (blockIdx.x * 256 + threadIdx.x) >> 6;
    int lane = threadIdx.x & 63;
    if (wave >= NCHUNK) return;
    int e = (wave << 6) + lane;
    uint2 er = pedges[e];
    int w1 = (int)er.y;
    int rel = __builtin_amdgcn_readfirstlane((w1 >> 25) & 63);  // wave-uniform
    const _Float16* __restrict__ wr =
        (const _Float16*)W1th + (size_t)rel * (HIDC * INC);
    F16Bits fb; fb.u = (unsigned short)(er.x >> 16);
    float sc = (float)fb.f;
    int src = er.x & 0xFFFF;
    int drow = (w1 < 0) ? NE : (w1 & 0x1FFFFFF);                // pads -> dump
    half2v xv[INC / 2];
    const uint4* __restrict__ xp = (const uint4*)(xh + (size_t)src * INC);
    #pragma unroll
    for (int i = 0; i < INC / 8; ++i) ((uint4*)xv)[i] = xp[i];
    unsigned um[HIDC / 2];
    #pragma unroll
    for (int c2 = 0; c2 < HIDC / 2; ++c2) {
        const half2v* __restrict__ w0 = (const half2v*)(wr + (2 * c2) * INC);
        const half2v* __restrict__ w1p = (const half2v*)(wr + (2 * c2 + 1) * INC);
        float a0 = 0.f, a1 = 0.f;
        #pragma unroll
        for (int i = 0; i < INC / 2; ++i) {
            a0 = dot2acc(xv[i], w0[i], a0);
            a1 = dot2acc(xv[i], w1p[i], a1);
        }
        union { __half2 h; unsigned u; } cv;
        cv.h = __floats2half2_rn(a0 * sc, a1 * sc);
        um[c2] = cv.u;
    }
    uint4* __restrict__ mrow = (uint4*)(msg + (size_t)drow * HIDC);
    #pragma unroll
    for (int q = 0; q < 4; ++q)
        mrow[q] = make_uint4(um[4*q], um[4*q+1], um[4*q+2], um[4*q+3]);
}

// Layer-2 messages (32 -> 16). h f16 (3.2 MB: L2-resident), 256 dot2/edge,
// f16 rows (32 B) at dst-sorted slots.
__global__ __launch_bounds__(256) void msg2_k(const __half* __restrict__ hh,
                                              const __half* __restrict__ W2th,
                                              const uint2* __restrict__ pedges,
                                              __half* __restrict__ msg) {
    int wave = (blockIdx.x * 256 + threadIdx.x) >> 6;
    int lane = threadIdx.x & 63;
    if (wave >= NCHUNK) return;
    int e = (wave << 6) + lane;
    uint2 er = pedges[e];
    int w1 = (int)er.y;
    int rel = __builtin_amdgcn_readfirstlane((w1 >> 25) & 63);
    const _Float16* __restrict__ wr =
        (const _Float16*)W2th + (size_t)rel * (OUTC * HIDC);
    F16Bits fb; fb.u = (unsigned short)(er.x >> 16);
    float sc = (float)fb.f;
    int src = er.x & 0xFFFF;
    int drow = (w1 < 0) ? NE : (w1 & 0x1FFFFFF);
    half2v hv[HIDC / 2];
    const uint4* __restrict__ hp = (const uint4*)(hh + (size_t)src * HIDC);
    #pragma unroll
    for (int i = 0; i < HIDC / 8; ++i) ((uint4*)hv)[i] = hp[i];
    unsigned um[OUTC / 2];
    #pragma unroll
    for (int c2 = 0; c2 < OUTC / 2; ++c2) {
        const half2v* __restrict__ w0 = (const half2v*)(wr + (2 * c2) * HIDC);
        const half2v* __restrict__ w1p = (const half2v*)(wr + (2 * c2 + 1) * HIDC);
        float a0 = 0.f, a1 = 0.f;
        #pragma unroll
        for (int i = 0; i < HIDC / 2; ++i) {
            a0 = dot2acc(hv[i], w0[i], a0);
            a1 = dot2acc(hv[i], w1p[i], a1);
        }
        union { __half2 h; unsigned u; } cv;
        cv.h = __floats2half2_rn(a0 * sc, a1 * sc);
        um[c2] = cv.u;
    }
    uint4* __restrict__ mrow = (uint4*)(msg + (size_t)drow * OUTC);
    mrow[0] = make_uint4(um[0], um[1], um[2], um[3]);
    mrow[1] = make_uint4(um[4], um[5], um[6], um[7]);
}

// ---------------------------------------------------------------------------
// Fused gather + node update 1: h = relu(sum(msg rows) + x @ root1 + b1), f16 out.
// One wave per node; msg rows contiguous (dst-sorted). lane = (sub,c2):
// sub in [0,4) streams k, c2 in [0,16) covers 32 ch as half2.
__global__ __launch_bounds__(256) void gather1_k(const float* __restrict__ x,
                                                 const float* __restrict__ root1,
                                                 const float* __restrict__ b1,
                                                 const __half* __restrict__ msg,
                                                 const unsigned* __restrict__ rowptr,
                                                 __half* __restrict__ hh) {
    __shared__ float sr[INC * HIDC];   // 8 KB, [in][c]
    for (int k = threadIdx.x; k < INC * HIDC; k += 256) sr[k] = root1[k];
    __syncthreads();
    int wid = (blockIdx.x * 256 + threadIdx.x) >> 6;   // node id; grid exact
    int lane = threadIdx.x & 63;
    int c2 = lane & 15, sub = lane >> 4;
    unsigned k0 = rowptr[wid], k1 = rowptr[wid + 1];
    float accx = 0.f, accy = 0.f;
    for (unsigned k = k0 + sub; k < k1; k += 4) {
        union { __half2 hh2; unsigned u; } cv;
        cv.u = ((const unsigned*)(msg + (size_t)k * HIDC))[c2];
        float2 f = __half22float2(cv.hh2);
        accx += f.x; accy += f.y;
    }
    // root contribution: sub handles input range [sub*16, sub*16+16)
    const float4* __restrict__ xp = (const float4*)(x + (size_t)wid * INC + sub * 16);
    #pragma unroll
    for (int q = 0; q < 4; ++q) {
        float4 xr = xp[q];
        const float* xs = (const float*)&xr;
        #pragma unroll
        for (int j = 0; j < 4; ++j) {
            int in = sub * 16 + q * 4 + j;
            float2 rt = *(const float2*)&sr[in * HIDC + 2 * c2];
            accx = fmaf(xs[j], rt.x, accx);
            accy = fmaf(xs[j], rt.y, accy);
        }
    }
    accx += __shfl_xor(accx, 16); accy += __shfl_xor(accy, 16);
    accx += __shfl_xor(accx, 32); accy += __shfl_xor(accy, 32);
    if (sub == 0) {
        float2 bb = *(const float2*)&b1[2 * c2];
        float vx = accx + bb.x, vy = accy + bb.y;
        union { __half2 h2; unsigned u; } cv;
        cv.h2 = __floats2half2_rn(vx > 0.f ? vx : 0.f, vy > 0.f ? vy : 0.f);
        ((unsigned*)hh)[(size_t)wid * (HIDC / 2) + c2] = cv.u;
    }
}

// Fused gather + node update 2: out = sum(msg rows) + h @ root2 + b2 (f32 out).
// One wave per node; c2 in [0,8) covers 16 ch as half2; sub in [0,8) streams k.
__global__ __launch_bounds__(256) void gather2_k(const __half* __restrict__ hh,
                                                 const float* __restrict__ root2,
                                                 const float* __restrict__ b2,
                                                 const __half* __restrict__ msg,
                                                 const unsigned* __restrict__ rowptr,
                                                 float* __restrict__ out) {
    __shared__ float sr[HIDC * OUTC];  // 2 KB, [in][c]
    for (int k = threadIdx.x; k < HIDC * OUTC; k += 256) sr[k] = root2[k];
    __syncthreads();
    int wid = (blockIdx.x * 256 + threadIdx.x) >> 6;
    int lane = threadIdx.x & 63;
    int c2 = lane & 7, sub = lane >> 3;   // 8 streams
    unsigned k0 = rowptr[wid], k1 = rowptr[wid + 1];
    float accx = 0.f, accy = 0.f;
    for (unsigned k = k0 + sub; k < k1; k += 8) {
        union { __half2 hh2; unsigned u; } cv;
        cv.u = ((const unsigned*)(msg + (size_t)k * OUTC))[c2];
        float2 f = __half22float2(cv.hh2);
        accx += f.x; accy += f.y;
    }
    // root contribution: sub handles input range [sub*4, sub*4+4)
    uint2 hw = *(const uint2*)(hh + (size_t)wid * HIDC + sub * 4);
    union { __half2 h2; unsigned u; } ca, cb;
    ca.u = hw.x; cb.u = hw.y;
    float2 ha = __half22float2(ca.h2), hb = __half22float2(cb.h2);
    float hs[4] = { ha.x, ha.y, hb.x, hb.y };
    #pragma unroll
    for (int j = 0; j < 4; ++j) {
        int in = sub * 4 + j;
        float2 rt = *(const float2*)&sr[in * OUTC + 2 * c2];
        accx = fmaf(hs[j], rt.x, accx);
        accy = fmaf(hs[j], rt.y, accy);
    }
    accx += __shfl_xor(accx, 8);  accy += __shfl_xor(accy, 8);
    accx += __shfl_xor(accx, 16); accy += __shfl_xor(accy, 16);
    accx += __shfl_xor(accx, 32); accy += __shfl_xor(accy, 32);
    if (sub == 0) {
        float2 bb = *(const float2*)&b2[2 * c2];
        *(float2*)&out[(size_t)wid * OUTC + 2 * c2] =
            make_float2(accx + bb.x, accy + bb.y);
    }
}

// ---------------------------------------------------------------------------
extern "C" void kernel_launch(void* const* d_in, const int* in_sizes, int n_in,
                              void* d_out, int out_size, void* d_ws, size_t ws_size,
                              hipStream_t stream) {
    const float* x     = (const float*)d_in[0];
    const int*   ei    = (const int*)d_in[1];   // [2, NE]
    const int*   et    = (const int*)d_in[2];   // [NE]
    const float* W1    = (const float*)d_in[3];
    const float* root1 = (const float*)d_in[4];
    const float* b1    = (const float*)d_in[5];
    const float* W2    = (const float*)d_in[6];
    const float* root2 = (const float*)d_in[7];
    const float* b2    = (const float*)d_in[8];
    float* out = (float*)d_out;

    char* ws = (char*)d_ws;
    size_t o = 0;
    auto alloc = [&](size_t bytes) -> char* {
        char* p = ws + o;
        o = (o + bytes + 255) & ~(size_t)255;
        return p;
    };
    // --- region that must start zeroed (one contiguous memset, ~9.0 MB) ---
    unsigned* cnt    = (unsigned*)alloc((size_t)NR * NN * 4);      // 9.0 MB
    unsigned* hist   = (unsigned*)alloc(NR * 4);
    size_t zero_bytes = o;
    // --- regions fully written before read ---
    unsigned* rank   = (unsigned*)alloc((size_t)NE * 4);           // 4.8 MB
    unsigned* packed = (unsigned*)alloc((size_t)NR * NN * 4);      // 9.0 MB
    unsigned* cursor = (unsigned*)alloc(NR * 4);
    unsigned* dhist  = (unsigned*)alloc((size_t)NN * 4);
    unsigned* rowptr = (unsigned*)alloc(((size_t)NN + 1) * 4);
    uint2*    pedges = (uint2*)   alloc((size_t)MAXE * 8);         // 9.6 MB
    __half*   W1th   = (__half*)  alloc((size_t)NR * HIDC * INC * 2);
    __half*   W2th   = (__half*)  alloc((size_t)NR * OUTC * HIDC * 2);
    __half*   xh     = (__half*)  alloc((size_t)NN * INC * 2);     // 6.4 MB
    __half*   hh     = (__half*)  alloc((size_t)NN * HIDC * 2);    // 3.2 MB
    // msg buffers alias: msg1 (f16, 64-B rows) fully consumed by gather1
    // before msg2 (f16, 32-B rows) is produced.
    char*     msgraw = alloc(((size_t)NE + 1) * 64);               // 76.9 MB
    __half*   msg1   = (__half*)msgraw;
    __half*   msg2   = (__half*)msgraw;

    hipMemsetAsync(d_ws, 0, zero_bytes, stream);
    prep_w   <<<(NR * HIDC * INC + 255) / 256, 256, 0, stream>>>(W1, W2, W1th, W2th);
    cast_x   <<<NN * INC / 2 / 256, 256, 0, stream>>>(x, xh);
    count_k  <<<(NE + 255) / 256, 256, 0, stream>>>(ei, et, cnt, hist, rank);
    prefix_k <<<1, 64, 0, stream>>>(hist, cursor);
    drel_k   <<<(NN + 255) / 256, 256, 0, stream>>>(cnt, packed, dhist);
    dprefix_k<<<1, 256, 0, stream>>>(dhist, rowptr);
    initp_k  <<<(MAXE / 2 + 255) / 256, 256, 0, stream>>>((uint4*)pedges);
    scatter_k<<<(NE + 255) / 256, 256, 0, stream>>>(ei, et, packed, rowptr, rank,
                                                    cursor, pedges);
    msg1_k   <<<(MAXE + 255) / 256, 256, 0, stream>>>(xh, W1th, pedges, msg1);
    gather1_k<<<NN * 64 / 256, 256, 0, stream>>>(x, root1, b1, msg1, rowptr, hh);
    msg2_k   <<<(MAXE + 255) / 256, 256, 0, stream>>>(hh, W2th, pedges, msg2);
    gather2_k<<<NN * 64 / 256, 256, 0, stream>>>(hh, root2, b2, msg2, rowptr, out);
}

// Round 6
// 448.965 us; speedup vs baseline: 8.9719x; 1.1810x over previous
//
#include <hip/hip_runtime.h>
#include <hip/hip_fp16.h>
#include <cstdint>
#include <cstddef>

// Problem constants (match reference setup_inputs)
#define NN   50000      // nodes  (< 65536: src/dst fit 16 bits)
#define NE   1200000    // edges
#define NR   45         // relations (< 64: rel fits 6 bits)
#define INC  64
#define HIDC 32
#define OUTC 16
// Padded edge capacity: each relation bucket padded to multiple of 64 so every
// wave's 64 edges share one relation. NE + NR*64, itself a multiple of 64.
#define MAXE 1202880
#define NCHUNK (MAXE/64)
// relation counting-sort blocking
#define EPB 4096
#define NB  ((NE + EPB - 1) / EPB)      // 293 blocks
// relcnt LDS: 16000 words x two 16-bit counters = 32000 dsts per half
#define HALFW 16000
#define HALFD (2 * HALFW)

// f16 pair type + dot2 accumulate (v_dot2_f32_f16 when available)
typedef _Float16 half2v __attribute__((ext_vector_type(2)));

#if defined(__has_builtin)
#  if __has_builtin(__builtin_amdgcn_fdot2)
#    define HAS_FDOT2 1
#  endif
#endif
#ifndef HAS_FDOT2
#  define HAS_FDOT2 0
#endif

__device__ __forceinline__ float dot2acc(half2v a, half2v b, float c) {
#if HAS_FDOT2
    return __builtin_amdgcn_fdot2(a, b, c, false);
#else
    return fmaf((float)a.x, (float)b.x, fmaf((float)a.y, (float)b.y, c));
#endif
}

union F16Bits { unsigned short u; _Float16 f; };

// ---------------------------------------------------------------------------
// W1 -> W1th[r][c][in] (f16), W2 -> W2th[r][c][in] (f16): channel-major so the
// msg kernels stream weight columns via wave-uniform scalar loads.
__global__ __launch_bounds__(256) void prep_w(const float* __restrict__ W1,
                                              const float* __restrict__ W2,
                                              __half* __restrict__ W1th,
                                              __half* __restrict__ W2th) {
    int t = blockIdx.x * 256 + threadIdx.x;
    if (t < NR * HIDC * INC) {
        int r = t / (HIDC * INC), rem = t % (HIDC * INC);
        int c = rem / INC, in = rem % INC;
        W1th[t] = __float2half(W1[(r * INC + in) * HIDC + c]);
    }
    if (t < NR * OUTC * HIDC) {
        int r = t / (OUTC * HIDC), rem = t % (OUTC * HIDC);
        int c = rem / HIDC, in = rem % HIDC;
        W2th[t] = __float2half(W2[(r * HIDC + in) * OUTC + c]);
    }
}

// Cast x (f32) -> xh (f16), pairwise.
__global__ __launch_bounds__(256) void cast_x(const float* __restrict__ x,
                                              __half* __restrict__ xh) {
    int t = blockIdx.x * 256 + threadIdx.x;   // NN*INC/2 exact multiple of 256
    float2 f = ((const float2*)x)[t];
    union { __half2 h; unsigned u; } cv;
    cv.h = __floats2half2_rn(f.x, f.y);
    ((unsigned*)xh)[t] = cv.u;
}

// ---------------------------------------------------------------------------
// ATOMIC-FREE relation counting sort, step 1: per-block 45-bin histograms
// (LDS atomics only). ghist[r*NB + b] = #edges of relation r in block b.
__global__ __launch_bounds__(256) void rhist_k(const int* __restrict__ ei,
                                               const int* __restrict__ et,
                                               unsigned* __restrict__ ghist) {
    __shared__ unsigned lh[NR];
    int t = threadIdx.x, b = blockIdx.x;
    if (t < NR) lh[t] = 0;
    __syncthreads();
    #pragma unroll
    for (int it = 0; it < EPB / 256; ++it) {
        int e = b * EPB + it * 256 + t;
        if (e < NE) {
            int r = et[e], src = ei[e], dst = ei[NE + e];
            if ((unsigned)r < NR && (unsigned)src < NN && (unsigned)dst < NN)
                atomicAdd(&lh[r], 1u);
        }
    }
    __syncthreads();
    if (t < NR) ghist[t * NB + b] = lh[t];
}

// Step 2 (single block): exclusive prefix within each relation row (in place),
// 64-padded relation bases, per-(r,block) scatter bases, relation ranges, and
// the chunk->relation map used by finalize_k.
__global__ __launch_bounds__(1024) void rscan_k(unsigned* __restrict__ ghist,
                                                unsigned* __restrict__ rbase,
                                                unsigned* __restrict__ rngs,
                                                int* __restrict__ chunkrel) {
    __shared__ unsigned relbase[NR + 1];
    __shared__ unsigned reltot[NR];
    int t = threadIdx.x;
    if (t < NR) {                       // row prefix (45 lanes, wave 0)
        unsigned run = 0;
        for (int b = 0; b < NB; ++b) {
            unsigned v = ghist[t * NB + b];
            ghist[t * NB + b] = run;
            run += v;
        }
        reltot[t] = run;
    }
    __syncthreads();
    if (t == 0) {                       // padded relation bases
        unsigned acc = 0;
        for (int r = 0; r < NR; ++r) {
            relbase[r] = acc;
            acc += ((reltot[r] + 63u) >> 6) << 6;
        }
        relbase[NR] = acc;
    }
    __syncthreads();
    for (int i = t; i < NR * NB; i += 1024)
        rbase[i] = ghist[i] + relbase[i / NB];
    if (t < NR) {
        rngs[2 * t]     = relbase[t];
        rngs[2 * t + 1] = relbase[t] + reltot[t];
    }
    for (int c = t; c < NCHUNK; c += 1024) chunkrel[c] = 0;
    __syncthreads();
    if (t < NR) {
        unsigned c0 = relbase[t] >> 6, c1 = relbase[t + 1] >> 6;
        for (unsigned c = c0; c < c1; ++c) chunkrel[c] = t;
    }
}

// Step 3: deterministic scatter into relation buckets (LDS atomics only).
// rsorted[pos] = {dst:16 | src:16}. Pad slots keep 0xFFFFFFFF (dst sentinel).
__global__ __launch_bounds__(256) void rscatter_k(const int* __restrict__ ei,
                                                  const int* __restrict__ et,
                                                  const unsigned* __restrict__ rbase,
                                                  unsigned* __restrict__ rsorted) {
    __shared__ unsigned lbase[NR], lcur[NR];
    int t = threadIdx.x, b = blockIdx.x;
    if (t < NR) { lbase[t] = rbase[t * NB + b]; lcur[t] = 0; }
    __syncthreads();
    #pragma unroll
    for (int it = 0; it < EPB / 256; ++it) {
        int e = b * EPB + it * 256 + t;
        if (e < NE) {
            int r = et[e], src = ei[e], dst = ei[NE + e];
            if ((unsigned)r < NR && (unsigned)src < NN && (unsigned)dst < NN) {
                unsigned local = atomicAdd(&lcur[r], 1u);
                rsorted[lbase[r] + local] = (unsigned)src | ((unsigned)dst << 16);
            }
        }
    }
}

// Per-relation dst counts + per-edge rank, all in LDS (two packed u16 counters
// per word; dst range split in two halves to fit 64 KB). One block = one
// relation. Writes the FULL cnt plane (so no pre-zeroing anywhere).
__global__ __launch_bounds__(1024) void relcnt_k(const unsigned* __restrict__ rsorted,
                                                 const unsigned* __restrict__ rngs,
                                                 unsigned* __restrict__ cnt,
                                                 unsigned short* __restrict__ rank16) {
    __shared__ unsigned lds[HALFW];     // 64000 B
    int r = blockIdx.x, t = threadIdx.x;
    unsigned base = rngs[2 * r], end = rngs[2 * r + 1];
    for (int half = 0; half < 2; ++half) {
        unsigned dlo = half * HALFD;
        unsigned dhi = (dlo + HALFD < NN) ? (dlo + HALFD) : NN;
        for (int w = t; w < HALFW; w += 1024) lds[w] = 0;
        __syncthreads();
        for (unsigned s = base + t; s < end; s += 1024) {
            unsigned d = rsorted[s] >> 16;
            if (d >= dlo && d < dhi) {
                unsigned off = d - dlo;
                atomicAdd(&lds[off >> 1], (off & 1) ? 0x10000u : 1u);
            }
        }
        __syncthreads();
        for (int w = t; w < HALFW; w += 1024) {
            unsigned u = lds[w];
            unsigned d0 = dlo + 2 * w;
            if (d0 < dhi) cnt[(size_t)r * NN + d0] = u & 0xFFFFu;
            unsigned d1 = d0 + 1;
            if (d1 < dhi) cnt[(size_t)r * NN + d1] = u >> 16;
        }
        __syncthreads();
        for (int w = t; w < HALFW; w += 1024) lds[w] = 0;
        __syncthreads();
        for (unsigned s = base + t; s < end; s += 1024) {
            unsigned d = rsorted[s] >> 16;
            if (d >= dlo && d < dhi) {
                unsigned off = d - dlo;
                unsigned old = atomicAdd(&lds[off >> 1], (off & 1) ? 0x10000u : 1u);
                rank16[s] = (unsigned short)((off & 1) ? (old >> 16) : (old & 0xFFFFu));
            }
        }
        __syncthreads();
    }
}

// Per-dst: relation-prefix offsets + f16 inverse counts, packed one word per
// (r,dst): {reloff:16 | f16(1/cnt):16}. Also derives dhist[dst] = degree.
__global__ __launch_bounds__(256) void drel_k(const unsigned* __restrict__ cnt,
                                              unsigned* __restrict__ packed,
                                              unsigned* __restrict__ dhist) {
    int dst = blockIdx.x * 256 + threadIdx.x;
    if (dst >= NN) return;
    unsigned run = 0;
    #pragma unroll 5
    for (int r = 0; r < NR; ++r) {
        unsigned c = cnt[(size_t)r * NN + dst];
        F16Bits fb; fb.f = (_Float16)(c ? 1.0f / (float)c : 0.0f);
        packed[(size_t)r * NN + dst] = (run & 0xFFFFu) | ((unsigned)fb.u << 16);
        run += c;
    }
    dhist[dst] = run;
}

// Exclusive prefix over NN dst bins -> rowptr[NN+1]
__global__ __launch_bounds__(256) void dprefix_k(const unsigned* __restrict__ dhist,
                                                 unsigned* __restrict__ rowptr) {
    __shared__ unsigned ps[257];
    int t = threadIdx.x;
    const int CH = (NN + 255) / 256;
    int lo = t * CH, hi = lo + CH; if (hi > NN) hi = NN; if (lo > NN) lo = NN;
    unsigned s = 0;
    for (int i = lo; i < hi; ++i) s += dhist[i];
    ps[t + 1] = s;
    if (t == 0) ps[0] = 0;
    __syncthreads();
    if (t == 0) for (int i = 1; i <= 256; ++i) ps[i] += ps[i - 1];
    __syncthreads();
    unsigned run = ps[t];
    for (int i = lo; i < hi; ++i) {
        rowptr[i] = run;
        run += dhist[i];
    }
    if (t == 255) rowptr[NN] = run;
}

// Build final edge records (identical format to before, so msg kernels are
// unchanged): word0 = src | scale_f16<<16 ; word1 = dpos | rel<<25.
// Pad slots (dst sentinel) -> {0, 0x80000000}.
__global__ __launch_bounds__(256) void finalize_k(const unsigned* __restrict__ rsorted,
                                                  const unsigned short* __restrict__ rank16,
                                                  const unsigned* __restrict__ packed,
                                                  const unsigned* __restrict__ rowptr,
                                                  const int* __restrict__ chunkrel,
                                                  uint2* __restrict__ pedges) {
    int s = blockIdx.x * 256 + threadIdx.x;
    if (s >= MAXE) return;
    unsigned v = rsorted[s];
    unsigned dst = v >> 16;
    if (dst >= NN) { pedges[s] = make_uint2(0u, 0x80000000u); return; }
    int r = chunkrel[s >> 6];
    unsigned pk = packed[(size_t)r * NN + dst];
    unsigned dpos = rowptr[dst] + (pk & 0xFFFFu) + (unsigned)rank16[s];
    pedges[s] = make_uint2((v & 0xFFFFu) | (pk & 0xFFFF0000u),
                           dpos | ((unsigned)r << 25));
}

// ---------------------------------------------------------------------------
// Layer-1 messages. One lane per edge; one wave = 64 edges of ONE relation
// (bucket padding) -> W wave-uniform -> scalar loads. x in f16 (128-B row),
// inner loop = 1024 v_dot2_f32_f16. Row written in f16 at its DST-SORTED slot
// (64 B) so gathers read sequentially.
__global__ __launch_bounds__(256) void msg1_k(const __half* __restrict__ xh,
                                              const __half* __restrict__ W1th,
                                              const uint2* __restrict__ pedges,
                                              __half* __restrict__ msg) {
    int wave = (blockIdx.x * 256 + threadIdx.x) >> 6;
    int lane = threadIdx.x & 63;
    if (wave >= NCHUNK) return;
    int e = (wave << 6) + lane;
    uint2 er = pedges[e];
    int w1 = (int)er.y;
    int rel = __builtin_amdgcn_readfirstlane((w1 >> 25) & 63);  // wave-uniform
    const _Float16* __restrict__ wr =
        (const _Float16*)W1th + (size_t)rel * (HIDC * INC);
    F16Bits fb; fb.u = (unsigned short)(er.x >> 16);
    float sc = (float)fb.f;
    int src = er.x & 0xFFFF;
    int drow = (w1 < 0) ? NE : (w1 & 0x1FFFFFF);                // pads -> dump
    half2v xv[INC / 2];
    const uint4* __restrict__ xp = (const uint4*)(xh + (size_t)src * INC);
    #pragma unroll
    for (int i = 0; i < INC / 8; ++i) ((uint4*)xv)[i] = xp[i];
    unsigned um[HIDC / 2];
    #pragma unroll
    for (int c2 = 0; c2 < HIDC / 2; ++c2) {
        const half2v* __restrict__ w0 = (const half2v*)(wr + (2 * c2) * INC);
        const half2v* __restrict__ w1p = (const half2v*)(wr + (2 * c2 + 1) * INC);
        float a0 = 0.f, a1 = 0.f;
        #pragma unroll
        for (int i = 0; i < INC / 2; ++i) {
            a0 = dot2acc(xv[i], w0[i], a0);
            a1 = dot2acc(xv[i], w1p[i], a1);
        }
        union { __half2 h; unsigned u; } cv;
        cv.h = __floats2half2_rn(a0 * sc, a1 * sc);
        um[c2] = cv.u;
    }
    uint4* __restrict__ mrow = (uint4*)(msg + (size_t)drow * HIDC);
    #pragma unroll
    for (int q = 0; q < 4; ++q)
        mrow[q] = make_uint4(um[4*q], um[4*q+1], um[4*q+2], um[4*q+3]);
}

// Layer-2 messages (32 -> 16). h f16 (3.2 MB: L2-resident), 256 dot2/edge,
// f16 rows (32 B) at dst-sorted slots.
__global__ __launch_bounds__(256) void msg2_k(const __half* __restrict__ hh,
                                              const __half* __restrict__ W2th,
                                              const uint2* __restrict__ pedges,
                                              __half* __restrict__ msg) {
    int wave = (blockIdx.x * 256 + threadIdx.x) >> 6;
    int lane = threadIdx.x & 63;
    if (wave >= NCHUNK) return;
    int e = (wave << 6) + lane;
    uint2 er = pedges[e];
    int w1 = (int)er.y;
    int rel = __builtin_amdgcn_readfirstlane((w1 >> 25) & 63);
    const _Float16* __restrict__ wr =
        (const _Float16*)W2th + (size_t)rel * (OUTC * HIDC);
    F16Bits fb; fb.u = (unsigned short)(er.x >> 16);
    float sc = (float)fb.f;
    int src = er.x & 0xFFFF;
    int drow = (w1 < 0) ? NE : (w1 & 0x1FFFFFF);
    half2v hv[HIDC / 2];
    const uint4* __restrict__ hp = (const uint4*)(hh + (size_t)src * HIDC);
    #pragma unroll
    for (int i = 0; i < HIDC / 8; ++i) ((uint4*)hv)[i] = hp[i];
    unsigned um[OUTC / 2];
    #pragma unroll
    for (int c2 = 0; c2 < OUTC / 2; ++c2) {
        const half2v* __restrict__ w0 = (const half2v*)(wr + (2 * c2) * HIDC);
        const half2v* __restrict__ w1p = (const half2v*)(wr + (2 * c2 + 1) * HIDC);
        float a0 = 0.f, a1 = 0.f;
        #pragma unroll
        for (int i = 0; i < HIDC / 2; ++i) {
            a0 = dot2acc(hv[i], w0[i], a0);
            a1 = dot2acc(hv[i], w1p[i], a1);
        }
        union { __half2 h; unsigned u; } cv;
        cv.h = __floats2half2_rn(a0 * sc, a1 * sc);
        um[c2] = cv.u;
    }
    uint4* __restrict__ mrow = (uint4*)(msg + (size_t)drow * OUTC);
    mrow[0] = make_uint4(um[0], um[1], um[2], um[3]);
    mrow[1] = make_uint4(um[4], um[5], um[6], um[7]);
}

// ---------------------------------------------------------------------------
// Fused gather + node update 1: h = relu(sum(msg rows) + x @ root1 + b1), f16 out.
// One wave per node; msg rows contiguous (dst-sorted). lane = (sub,c2):
// sub in [0,4) streams k, c2 in [0,16) covers 32 ch as half2.
__global__ __launch_bounds__(256) void gather1_k(const float* __restrict__ x,
                                                 const float* __restrict__ root1,
                                                 const float* __restrict__ b1,
                                                 const __half* __restrict__ msg,
                                                 const unsigned* __restrict__ rowptr,
                                                 __half* __restrict__ hh) {
    __shared__ float sr[INC * HIDC];   // 8 KB, [in][c]
    for (int k = threadIdx.x; k < INC * HIDC; k += 256) sr[k] = root1[k];
    __syncthreads();
    int wid = (blockIdx.x * 256 + threadIdx.x) >> 6;   // node id; grid exact
    int lane = threadIdx.x & 63;
    int c2 = lane & 15, sub = lane >> 4;
    unsigned k0 = rowptr[wid], k1 = rowptr[wid + 1];
    float accx = 0.f, accy = 0.f;
    for (unsigned k = k0 + sub; k < k1; k += 4) {
        union { __half2 hh2; unsigned u; } cv;
        cv.u = ((const unsigned*)(msg + (size_t)k * HIDC))[c2];
        float2 f = __half22float2(cv.hh2);
        accx += f.x; accy += f.y;
    }
    // root contribution: sub handles input range [sub*16, sub*16+16)
    const float4* __restrict__ xp = (const float4*)(x + (size_t)wid * INC + sub * 16);
    #pragma unroll
    for (int q = 0; q < 4; ++q) {
        float4 xr = xp[q];
        const float* xs = (const float*)&xr;
        #pragma unroll
        for (int j = 0; j < 4; ++j) {
            int in = sub * 16 + q * 4 + j;
            float2 rt = *(const float2*)&sr[in * HIDC + 2 * c2];
            accx = fmaf(xs[j], rt.x, accx);
            accy = fmaf(xs[j], rt.y, accy);
        }
    }
    accx += __shfl_xor(accx, 16); accy += __shfl_xor(accy, 16);
    accx += __shfl_xor(accx, 32); accy += __shfl_xor(accy, 32);
    if (sub == 0) {
        float2 bb = *(const float2*)&b1[2 * c2];
        float vx = accx + bb.x, vy = accy + bb.y;
        union { __half2 h2; unsigned u; } cv;
        cv.h2 = __floats2half2_rn(vx > 0.f ? vx : 0.f, vy > 0.f ? vy : 0.f);
        ((unsigned*)hh)[(size_t)wid * (HIDC / 2) + c2] = cv.u;
    }
}

// Fused gather + node update 2: out = sum(msg rows) + h @ root2 + b2 (f32 out).
// One wave per node; c2 in [0,8) covers 16 ch as half2; sub in [0,8) streams k.
__global__ __launch_bounds__(256) void gather2_k(const __half* __restrict__ hh,
                                                 const float* __restrict__ root2,
                                                 const float* __restrict__ b2,
                                                 const __half* __restrict__ msg,
                                                 const unsigned* __restrict__ rowptr,
                                                 float* __restrict__ out) {
    __shared__ float sr[HIDC * OUTC];  // 2 KB, [in][c]
    for (int k = threadIdx.x; k < HIDC * OUTC; k += 256) sr[k] = root2[k];
    __syncthreads();
    int wid = (blockIdx.x * 256 + threadIdx.x) >> 6;
    int lane = threadIdx.x & 63;
    int c2 = lane & 7, sub = lane >> 3;   // 8 streams
    unsigned k0 = rowptr[wid], k1 = rowptr[wid + 1];
    float accx = 0.f, accy = 0.f;
    for (unsigned k = k0 + sub; k < k1; k += 8) {
        union { __half2 hh2; unsigned u; } cv;
        cv.u = ((const unsigned*)(msg + (size_t)k * OUTC))[c2];
        float2 f = __half22float2(cv.hh2);
        accx += f.x; accy += f.y;
    }
    // root contribution: sub handles input range [sub*4, sub*4+4)
    uint2 hw = *(const uint2*)(hh + (size_t)wid * HIDC + sub * 4);
    union { __half2 h2; unsigned u; } ca, cb;
    ca.u = hw.x; cb.u = hw.y;
    float2 ha = __half22float2(ca.h2), hb = __half22float2(cb.h2);
    float hs[4] = { ha.x, ha.y, hb.x, hb.y };
    #pragma unroll
    for (int j = 0; j < 4; ++j) {
        int in = sub * 4 + j;
        float2 rt = *(const float2*)&sr[in * OUTC + 2 * c2];
        accx = fmaf(hs[j], rt.x, accx);
        accy = fmaf(hs[j], rt.y, accy);
    }
    accx += __shfl_xor(accx, 8);  accy += __shfl_xor(accy, 8);
    accx += __shfl_xor(accx, 16); accy += __shfl_xor(accy, 16);
    accx += __shfl_xor(accx, 32); accy += __shfl_xor(accy, 32);
    if (sub == 0) {
        float2 bb = *(const float2*)&b2[2 * c2];
        *(float2*)&out[(size_t)wid * OUTC + 2 * c2] =
            make_float2(accx + bb.x, accy + bb.y);
    }
}

// ---------------------------------------------------------------------------
extern "C" void kernel_launch(void* const* d_in, const int* in_sizes, int n_in,
                              void* d_out, int out_size, void* d_ws, size_t ws_size,
                              hipStream_t stream) {
    const float* x     = (const float*)d_in[0];
    const int*   ei    = (const int*)d_in[1];   // [2, NE]
    const int*   et    = (const int*)d_in[2];   // [NE]
    const float* W1    = (const float*)d_in[3];
    const float* root1 = (const float*)d_in[4];
    const float* b1    = (const float*)d_in[5];
    const float* W2    = (const float*)d_in[6];
    const float* root2 = (const float*)d_in[7];
    const float* b2    = (const float*)d_in[8];
    float* out = (float*)d_out;

    char* ws = (char*)d_ws;
    size_t o = 0;
    auto alloc = [&](size_t bytes) -> char* {
        char* p = ws + o;
        o = (o + bytes + 255) & ~(size_t)255;
        return p;
    };
    // rsorted FIRST: single 0xFF memset marks all slots as pads (dst=0xFFFF);
    // rscatter_k overwrites exactly the NE real slots. NOTHING needs zeroing.
    unsigned* rsorted = (unsigned*)alloc((size_t)MAXE * 4);        // 4.8 MB
    size_t ff_bytes = o;
    unsigned* ghist   = (unsigned*)alloc((size_t)NR * NB * 4);     // 53 KB
    unsigned* rbase   = (unsigned*)alloc((size_t)NR * NB * 4);
    unsigned* rngs    = (unsigned*)alloc((size_t)NR * 2 * 4);
    int*      chunkrel= (int*)     alloc((size_t)NCHUNK * 4);      // 75 KB
    unsigned short* rank16 = (unsigned short*)alloc((size_t)MAXE * 2); // 2.4 MB
    unsigned* cnt     = (unsigned*)alloc((size_t)NR * NN * 4);     // 9.0 MB
    unsigned* packed  = (unsigned*)alloc((size_t)NR * NN * 4);     // 9.0 MB
    unsigned* dhist   = (unsigned*)alloc((size_t)NN * 4);
    unsigned* rowptr  = (unsigned*)alloc(((size_t)NN + 1) * 4);
    uint2*    pedges  = (uint2*)   alloc((size_t)MAXE * 8);        // 9.6 MB
    __half*   W1th    = (__half*)  alloc((size_t)NR * HIDC * INC * 2);
    __half*   W2th    = (__half*)  alloc((size_t)NR * OUTC * HIDC * 2);
    __half*   xh      = (__half*)  alloc((size_t)NN * INC * 2);    // 6.4 MB
    __half*   hh      = (__half*)  alloc((size_t)NN * HIDC * 2);   // 3.2 MB
    // msg buffers alias: msg1 (f16, 64-B rows) fully consumed by gather1
    // before msg2 (f16, 32-B rows) is produced.
    char*     msgraw  = alloc(((size_t)NE + 1) * 64);              // 76.9 MB
    __half*   msg1    = (__half*)msgraw;
    __half*   msg2    = (__half*)msgraw;

    hipMemsetAsync(d_ws, 0xFF, ff_bytes, stream);
    prep_w    <<<(NR * HIDC * INC + 255) / 256, 256, 0, stream>>>(W1, W2, W1th, W2th);
    cast_x    <<<NN * INC / 2 / 256, 256, 0, stream>>>(x, xh);
    rhist_k   <<<NB, 256, 0, stream>>>(ei, et, ghist);
    rscan_k   <<<1, 1024, 0, stream>>>(ghist, rbase, rngs, chunkrel);
    rscatter_k<<<NB, 256, 0, stream>>>(ei, et, rbase, rsorted);
    relcnt_k  <<<NR, 1024, 0, stream>>>(rsorted, rngs, cnt, rank16);
    drel_k    <<<(NN + 255) / 256, 256, 0, stream>>>(cnt, packed, dhist);
    dprefix_k <<<1, 256, 0, stream>>>(dhist, rowptr);
    finalize_k<<<(MAXE + 255) / 256, 256, 0, stream>>>(rsorted, rank16, packed,
                                                       rowptr, chunkrel, pedges);
    msg1_k    <<<(MAXE + 255) / 256, 256, 0, stream>>>(xh, W1th, pedges, msg1);
    gather1_k <<<NN * 64 / 256, 256, 0, stream>>>(x, root1, b1, msg1, rowptr, hh);
    msg2_k    <<<(MAXE + 255) / 256, 256, 0, stream>>>(hh, W2th, pedges, msg2);
    gather2_k <<<NN * 64 / 256, 256, 0, stream>>>(hh, root2, b2, msg2, rowptr, out);
}

// Round 7
// 386.712 us; speedup vs baseline: 10.4162x; 1.1610x over previous
//
#include <hip/hip_runtime.h>
#include <hip/hip_fp16.h>
#include <cstdint>
#include <cstddef>

// Problem constants (match reference setup_inputs)
#define NN   50000      // nodes  (< 65536: src/dst fit 16 bits)
#define NE   1200000    // edges
#define NR   45         // relations (< 64: rel fits 6 bits)
#define INC  64
#define HIDC 32
#define OUTC 16
// Padded edge capacity: each relation bucket padded to multiple of 64 so every
// wave's 64 edges share one relation. NE + NR*64, itself a multiple of 64.
#define MAXE 1202880
#define NCHUNK (MAXE/64)
// relation counting-sort blocking
#define EPB 4096
#define NB  ((NE + EPB - 1) / EPB)      // 293 blocks
// relcnt LDS: 16000 words x two 16-bit counters = 32000 dsts per half
#define HALFW 16000
#define HALFD (2 * HALFW)

// f16 pair type + dot2 accumulate (v_dot2_f32_f16 when available)
typedef _Float16 half2v __attribute__((ext_vector_type(2)));

#if defined(__has_builtin)
#  if __has_builtin(__builtin_amdgcn_fdot2)
#    define HAS_FDOT2 1
#  endif
#endif
#ifndef HAS_FDOT2
#  define HAS_FDOT2 0
#endif

__device__ __forceinline__ float dot2acc(half2v a, half2v b, float c) {
#if HAS_FDOT2
    return __builtin_amdgcn_fdot2(a, b, c, false);
#else
    return fmaf((float)a.x, (float)b.x, fmaf((float)a.y, (float)b.y, c));
#endif
}

union F16Bits { unsigned short u; _Float16 f; };

// ---------------------------------------------------------------------------
// W1 -> W1th[r][c][in] (f16), W2 -> W2th[r][c][in] (f16): channel-major so the
// msg kernels stream weight columns via wave-uniform scalar loads.
__global__ __launch_bounds__(256) void prep_w(const float* __restrict__ W1,
                                              const float* __restrict__ W2,
                                              __half* __restrict__ W1th,
                                              __half* __restrict__ W2th) {
    int t = blockIdx.x * 256 + threadIdx.x;
    if (t < NR * HIDC * INC) {
        int r = t / (HIDC * INC), rem = t % (HIDC * INC);
        int c = rem / INC, in = rem % INC;
        W1th[t] = __float2half(W1[(r * INC + in) * HIDC + c]);
    }
    if (t < NR * OUTC * HIDC) {
        int r = t / (OUTC * HIDC), rem = t % (OUTC * HIDC);
        int c = rem / HIDC, in = rem % HIDC;
        W2th[t] = __float2half(W2[(r * HIDC + in) * OUTC + c]);
    }
}

// Cast x (f32) -> xh (f16), pairwise.
__global__ __launch_bounds__(256) void cast_x(const float* __restrict__ x,
                                              __half* __restrict__ xh) {
    int t = blockIdx.x * 256 + threadIdx.x;   // NN*INC/2 exact multiple of 256
    float2 f = ((const float2*)x)[t];
    union { __half2 h; unsigned u; } cv;
    cv.h = __floats2half2_rn(f.x, f.y);
    ((unsigned*)xh)[t] = cv.u;
}

// ---------------------------------------------------------------------------
// ATOMIC-FREE relation counting sort, step 1: per-block 45-bin histograms
// (LDS atomics only). ghist[r*NB + b] = #edges of relation r in block b.
__global__ __launch_bounds__(256) void rhist_k(const int* __restrict__ ei,
                                               const int* __restrict__ et,
                                               unsigned* __restrict__ ghist) {
    __shared__ unsigned lh[NR];
    int t = threadIdx.x, b = blockIdx.x;
    if (t < NR) lh[t] = 0;
    __syncthreads();
    #pragma unroll
    for (int it = 0; it < EPB / 256; ++it) {
        int e = b * EPB + it * 256 + t;
        if (e < NE) {
            int r = et[e], src = ei[e], dst = ei[NE + e];
            if ((unsigned)r < NR && (unsigned)src < NN && (unsigned)dst < NN)
                atomicAdd(&lh[r], 1u);
        }
    }
    __syncthreads();
    if (t < NR) ghist[t * NB + b] = lh[t];
}

// Step 2 (single block): exclusive prefix within each relation row (in place),
// 64-padded relation bases, per-(r,block) scatter bases, relation ranges, and
// the chunk->relation map used by finalize_k.
__global__ __launch_bounds__(1024) void rscan_k(unsigned* __restrict__ ghist,
                                                unsigned* __restrict__ rbase,
                                                unsigned* __restrict__ rngs,
                                                int* __restrict__ chunkrel) {
    __shared__ unsigned relbase[NR + 1];
    __shared__ unsigned reltot[NR];
    int t = threadIdx.x;
    if (t < NR) {                       // row prefix (45 lanes, wave 0)
        unsigned run = 0;
        for (int b = 0; b < NB; ++b) {
            unsigned v = ghist[t * NB + b];
            ghist[t * NB + b] = run;
            run += v;
        }
        reltot[t] = run;
    }
    __syncthreads();
    if (t == 0) {                       // padded relation bases
        unsigned acc = 0;
        for (int r = 0; r < NR; ++r) {
            relbase[r] = acc;
            acc += ((reltot[r] + 63u) >> 6) << 6;
        }
        relbase[NR] = acc;
    }
    __syncthreads();
    for (int i = t; i < NR * NB; i += 1024)
        rbase[i] = ghist[i] + relbase[i / NB];
    if (t < NR) {
        rngs[2 * t]     = relbase[t];
        rngs[2 * t + 1] = relbase[t] + reltot[t];
    }
    for (int c = t; c < NCHUNK; c += 1024) chunkrel[c] = 0;
    __syncthreads();
    if (t < NR) {
        unsigned c0 = relbase[t] >> 6, c1 = relbase[t + 1] >> 6;
        for (unsigned c = c0; c < c1; ++c) chunkrel[c] = t;
    }
}

// Step 3: deterministic scatter into relation buckets (LDS atomics only).
// rsorted[pos] = {dst:16 | src:16}. Pad slots keep 0xFFFFFFFF (dst sentinel).
__global__ __launch_bounds__(256) void rscatter_k(const int* __restrict__ ei,
                                                  const int* __restrict__ et,
                                                  const unsigned* __restrict__ rbase,
                                                  unsigned* __restrict__ rsorted) {
    __shared__ unsigned lbase[NR], lcur[NR];
    int t = threadIdx.x, b = blockIdx.x;
    if (t < NR) { lbase[t] = rbase[t * NB + b]; lcur[t] = 0; }
    __syncthreads();
    #pragma unroll
    for (int it = 0; it < EPB / 256; ++it) {
        int e = b * EPB + it * 256 + t;
        if (e < NE) {
            int r = et[e], src = ei[e], dst = ei[NE + e];
            if ((unsigned)r < NR && (unsigned)src < NN && (unsigned)dst < NN) {
                unsigned local = atomicAdd(&lcur[r], 1u);
                rsorted[lbase[r] + local] = (unsigned)src | ((unsigned)dst << 16);
            }
        }
    }
}

// Per-relation dst counts + per-edge rank, all in LDS (two packed u16 counters
// per word). One block = one (relation, dst-half) pair -> grid 2*NR for full
// CU utilization. Writes the FULL cnt plane (so no pre-zeroing anywhere).
__global__ __launch_bounds__(1024) void relcnt_k(const unsigned* __restrict__ rsorted,
                                                 const unsigned* __restrict__ rngs,
                                                 unsigned* __restrict__ cnt,
                                                 unsigned short* __restrict__ rank16) {
    __shared__ unsigned lds[HALFW];     // 64000 B
    int r = blockIdx.x >> 1, half = blockIdx.x & 1, t = threadIdx.x;
    unsigned base = rngs[2 * r], end = rngs[2 * r + 1];
    unsigned dlo = half * HALFD;
    unsigned dhi = (dlo + HALFD < NN) ? (dlo + HALFD) : NN;
    for (int w = t; w < HALFW; w += 1024) lds[w] = 0;
    __syncthreads();
    for (unsigned s = base + t; s < end; s += 1024) {
        unsigned d = rsorted[s] >> 16;
        if (d >= dlo && d < dhi) {
            unsigned off = d - dlo;
            atomicAdd(&lds[off >> 1], (off & 1) ? 0x10000u : 1u);
        }
    }
    __syncthreads();
    for (int w = t; w < HALFW; w += 1024) {
        unsigned u = lds[w];
        unsigned d0 = dlo + 2 * w;
        if (d0 < dhi) cnt[(size_t)r * NN + d0] = u & 0xFFFFu;
        unsigned d1 = d0 + 1;
        if (d1 < dhi) cnt[(size_t)r * NN + d1] = u >> 16;
    }
    __syncthreads();
    for (int w = t; w < HALFW; w += 1024) lds[w] = 0;
    __syncthreads();
    for (unsigned s = base + t; s < end; s += 1024) {
        unsigned d = rsorted[s] >> 16;
        if (d >= dlo && d < dhi) {
            unsigned off = d - dlo;
            unsigned old = atomicAdd(&lds[off >> 1], (off & 1) ? 0x10000u : 1u);
            rank16[s] = (unsigned short)((off & 1) ? (old >> 16) : (old & 0xFFFFu));
        }
    }
}

// Per-dst: relation-prefix offsets + f16 inverse counts, packed one word per
// (r,dst): {reloff:16 | f16(1/cnt):16}. Also derives dhist[dst] = degree.
__global__ __launch_bounds__(256) void drel_k(const unsigned* __restrict__ cnt,
                                              unsigned* __restrict__ packed,
                                              unsigned* __restrict__ dhist) {
    int dst = blockIdx.x * 256 + threadIdx.x;
    if (dst >= NN) return;
    unsigned run = 0;
    #pragma unroll 5
    for (int r = 0; r < NR; ++r) {
        unsigned c = cnt[(size_t)r * NN + dst];
        F16Bits fb; fb.f = (_Float16)(c ? 1.0f / (float)c : 0.0f);
        packed[(size_t)r * NN + dst] = (run & 0xFFFFu) | ((unsigned)fb.u << 16);
        run += c;
    }
    dhist[dst] = run;
}

// Exclusive prefix over NN dst bins -> rowptr[NN+1].
// Tiled block scan: 1024-thread coalesced tiles, wave shfl_up scan + 16-wave
// LDS combine + running carry. Replaces the 88-us serial-chunk version.
__global__ __launch_bounds__(1024) void dprefix_k(const unsigned* __restrict__ dhist,
                                                  unsigned* __restrict__ rowptr) {
    __shared__ unsigned wsum[16];
    __shared__ unsigned carry_s;
    int t = threadIdx.x;
    int lane = t & 63, wv = t >> 6;
    if (t == 0) carry_s = 0;
    __syncthreads();
    for (int base = 0; base < NN; base += 1024) {
        int i = base + t;
        unsigned v = (i < NN) ? dhist[i] : 0u;
        unsigned s = v;                        // inclusive wave scan
        #pragma unroll
        for (int off = 1; off < 64; off <<= 1) {
            unsigned n = __shfl_up(s, off);
            if (lane >= off) s += n;
        }
        if (lane == 63) wsum[wv] = s;
        __syncthreads();
        if (wv == 0) {                         // scan the 16 wave totals
            unsigned ws = (lane < 16) ? wsum[lane] : 0u;
            #pragma unroll
            for (int off = 1; off < 16; off <<= 1) {
                unsigned n = __shfl_up(ws, off);
                if (lane >= off) ws += n;
            }
            if (lane < 16) wsum[lane] = ws;    // inclusive over waves
        }
        __syncthreads();
        unsigned waveoff = (wv == 0) ? 0u : wsum[wv - 1];
        unsigned carry = carry_s;
        if (i < NN) rowptr[i] = carry + waveoff + s - v;
        __syncthreads();
        if (t == 1023) carry_s = carry + wsum[15];
        __syncthreads();
    }
    if (t == 0) rowptr[NN] = carry_s;
}

// Build final edge records (identical format to before, so msg kernels are
// unchanged): word0 = src | scale_f16<<16 ; word1 = dpos | rel<<25.
// Pad slots (dst sentinel) -> {0, 0x80000000}.
__global__ __launch_bounds__(256) void finalize_k(const unsigned* __restrict__ rsorted,
                                                  const unsigned short* __restrict__ rank16,
                                                  const unsigned* __restrict__ packed,
                                                  const unsigned* __restrict__ rowptr,
                                                  const int* __restrict__ chunkrel,
                                                  uint2* __restrict__ pedges) {
    int s = blockIdx.x * 256 + threadIdx.x;
    if (s >= MAXE) return;
    unsigned v = rsorted[s];
    unsigned dst = v >> 16;
    if (dst >= NN) { pedges[s] = make_uint2(0u, 0x80000000u); return; }
    int r = chunkrel[s >> 6];
    unsigned pk = packed[(size_t)r * NN + dst];
    unsigned dpos = rowptr[dst] + (pk & 0xFFFFu) + (unsigned)rank16[s];
    pedges[s] = make_uint2((v & 0xFFFFu) | (pk & 0xFFFF0000u),
                           dpos | ((unsigned)r << 25));
}

// ---------------------------------------------------------------------------
// Layer-1 messages. One lane per edge; one wave = 64 edges of ONE relation
// (bucket padding) -> W wave-uniform -> scalar loads. x in f16 (128-B row),
// inner loop = 1024 v_dot2_f32_f16. Row written in f16 at its DST-SORTED slot
// (64 B) so gathers read sequentially.
__global__ __launch_bounds__(256) void msg1_k(const __half* __restrict__ xh,
                                              const __half* __restrict__ W1th,
                                              const uint2* __restrict__ pedges,
                                              __half* __restrict__ msg) {
    int wave = (blockIdx.x * 256 + threadIdx.x) >> 6;
    int lane = threadIdx.x & 63;
    if (wave >= NCHUNK) return;
    int e = (wave << 6) + lane;
    uint2 er = pedges[e];
    int w1 = (int)er.y;
    int rel = __builtin_amdgcn_readfirstlane((w1 >> 25) & 63);  // wave-uniform
    const _Float16* __restrict__ wr =
        (const _Float16*)W1th + (size_t)rel * (HIDC * INC);
    F16Bits fb; fb.u = (unsigned short)(er.x >> 16);
    float sc = (float)fb.f;
    int src = er.x & 0xFFFF;
    int drow = (w1 < 0) ? NE : (w1 & 0x1FFFFFF);                // pads -> dump
    half2v xv[INC / 2];
    const uint4* __restrict__ xp = (const uint4*)(xh + (size_t)src * INC);
    #pragma unroll
    for (int i = 0; i < INC / 8; ++i) ((uint4*)xv)[i] = xp[i];
    unsigned um[HIDC / 2];
    #pragma unroll
    for (int c2 = 0; c2 < HIDC / 2; ++c2) {
        const half2v* __restrict__ w0 = (const half2v*)(wr + (2 * c2) * INC);
        const half2v* __restrict__ w1p = (const half2v*)(wr + (2 * c2 + 1) * INC);
        float a0 = 0.f, a1 = 0.f;
        #pragma unroll
        for (int i = 0; i < INC / 2; ++i) {
            a0 = dot2acc(xv[i], w0[i], a0);
            a1 = dot2acc(xv[i], w1p[i], a1);
        }
        union { __half2 h; unsigned u; } cv;
        cv.h = __floats2half2_rn(a0 * sc, a1 * sc);
        um[c2] = cv.u;
    }
    uint4* __restrict__ mrow = (uint4*)(msg + (size_t)drow * HIDC);
    #pragma unroll
    for (int q = 0; q < 4; ++q)
        mrow[q] = make_uint4(um[4*q], um[4*q+1], um[4*q+2], um[4*q+3]);
}

// Layer-2 messages (32 -> 16). h f16 (3.2 MB: L2-resident), 256 dot2/edge,
// f16 rows (32 B) at dst-sorted slots.
__global__ __launch_bounds__(256) void msg2_k(const __half* __restrict__ hh,
                                              const __half* __restrict__ W2th,
                                              const uint2* __restrict__ pedges,
                                              __half* __restrict__ msg) {
    int wave = (blockIdx.x * 256 + threadIdx.x) >> 6;
    int lane = threadIdx.x & 63;
    if (wave >= NCHUNK) return;
    int e = (wave << 6) + lane;
    uint2 er = pedges[e];
    int w1 = (int)er.y;
    int rel = __builtin_amdgcn_readfirstlane((w1 >> 25) & 63);
    const _Float16* __restrict__ wr =
        (const _Float16*)W2th + (size_t)rel * (OUTC * HIDC);
    F16Bits fb; fb.u = (unsigned short)(er.x >> 16);
    float sc = (float)fb.f;
    int src = er.x & 0xFFFF;
    int drow = (w1 < 0) ? NE : (w1 & 0x1FFFFFF);
    half2v hv[HIDC / 2];
    const uint4* __restrict__ hp = (const uint4*)(hh + (size_t)src * HIDC);
    #pragma unroll
    for (int i = 0; i < HIDC / 8; ++i) ((uint4*)hv)[i] = hp[i];
    unsigned um[OUTC / 2];
    #pragma unroll
    for (int c2 = 0; c2 < OUTC / 2; ++c2) {
        const half2v* __restrict__ w0 = (const half2v*)(wr + (2 * c2) * HIDC);
        const half2v* __restrict__ w1p = (const half2v*)(wr + (2 * c2 + 1) * HIDC);
        float a0 = 0.f, a1 = 0.f;
        #pragma unroll
        for (int i = 0; i < HIDC / 2; ++i) {
            a0 = dot2acc(hv[i], w0[i], a0);
            a1 = dot2acc(hv[i], w1p[i], a1);
        }
        union { __half2 h; unsigned u; } cv;
        cv.h = __floats2half2_rn(a0 * sc, a1 * sc);
        um[c2] = cv.u;
    }
    uint4* __restrict__ mrow = (uint4*)(msg + (size_t)drow * OUTC);
    mrow[0] = make_uint4(um[0], um[1], um[2], um[3]);
    mrow[1] = make_uint4(um[4], um[5], um[6], um[7]);
}

// ---------------------------------------------------------------------------
// Fused gather + node update 1: h = relu(sum(msg rows) + x @ root1 + b1), f16 out.
// One wave per node; msg rows contiguous (dst-sorted). lane = (sub,c2):
// sub in [0,4) streams k, c2 in [0,16) covers 32 ch as half2.
__global__ __launch_bounds__(256) void gather1_k(const float* __restrict__ x,
                                                 const float* __restrict__ root1,
                                                 const float* __restrict__ b1,
                                                 const __half* __restrict__ msg,
                                                 const unsigned* __restrict__ rowptr,
                                                 __half* __restrict__ hh) {
    __shared__ float sr[INC * HIDC];   // 8 KB, [in][c]
    for (int k = threadIdx.x; k < INC * HIDC; k += 256) sr[k] = root1[k];
    __syncthreads();
    int wid = (blockIdx.x * 256 + threadIdx.x) >> 6;   // node id; grid exact
    int lane = threadIdx.x & 63;
    int c2 = lane & 15, sub = lane >> 4;
    unsigned k0 = rowptr[wid], k1 = rowptr[wid + 1];
    float accx = 0.f, accy = 0.f;
    for (unsigned k = k0 + sub; k < k1; k += 4) {
        union { __half2 hh2; unsigned u; } cv;
        cv.u = ((const unsigned*)(msg + (size_t)k * HIDC))[c2];
        float2 f = __half22float2(cv.hh2);
        accx += f.x; accy += f.y;
    }
    // root contribution: sub handles input range [sub*16, sub*16+16)
    const float4* __restrict__ xp = (const float4*)(x + (size_t)wid * INC + sub * 16);
    #pragma unroll
    for (int q = 0; q < 4; ++q) {
        float4 xr = xp[q];
        const float* xs = (const float*)&xr;
        #pragma unroll
        for (int j = 0; j < 4; ++j) {
            int in = sub * 16 + q * 4 + j;
            float2 rt = *(const float2*)&sr[in * HIDC + 2 * c2];
            accx = fmaf(xs[j], rt.x, accx);
            accy = fmaf(xs[j], rt.y, accy);
        }
    }
    accx += __shfl_xor(accx, 16); accy += __shfl_xor(accy, 16);
    accx += __shfl_xor(accx, 32); accy += __shfl_xor(accy, 32);
    if (sub == 0) {
        float2 bb = *(const float2*)&b1[2 * c2];
        float vx = accx + bb.x, vy = accy + bb.y;
        union { __half2 h2; unsigned u; } cv;
        cv.h2 = __floats2half2_rn(vx > 0.f ? vx : 0.f, vy > 0.f ? vy : 0.f);
        ((unsigned*)hh)[(size_t)wid * (HIDC / 2) + c2] = cv.u;
    }
}

// Fused gather + node update 2: out = sum(msg rows) + h @ root2 + b2 (f32 out).
// One wave per node; c2 in [0,8) covers 16 ch as half2; sub in [0,8) streams k.
__global__ __launch_bounds__(256) void gather2_k(const __half* __restrict__ hh,
                                                 const float* __restrict__ root2,
                                                 const float* __restrict__ b2,
                                                 const __half* __restrict__ msg,
                                                 const unsigned* __restrict__ rowptr,
                                                 float* __restrict__ out) {
    __shared__ float sr[HIDC * OUTC];  // 2 KB, [in][c]
    for (int k = threadIdx.x; k < HIDC * OUTC; k += 256) sr[k] = root2[k];
    __syncthreads();
    int wid = (blockIdx.x * 256 + threadIdx.x) >> 6;
    int lane = threadIdx.x & 63;
    int c2 = lane & 7, sub = lane >> 3;   // 8 streams
    unsigned k0 = rowptr[wid], k1 = rowptr[wid + 1];
    float accx = 0.f, accy = 0.f;
    for (unsigned k = k0 + sub; k < k1; k += 8) {
        union { __half2 hh2; unsigned u; } cv;
        cv.u = ((const unsigned*)(msg + (size_t)k * OUTC))[c2];
        float2 f = __half22float2(cv.hh2);
        accx += f.x; accy += f.y;
    }
    // root contribution: sub handles input range [sub*4, sub*4+4)
    uint2 hw = *(const uint2*)(hh + (size_t)wid * HIDC + sub * 4);
    union { __half2 h2; unsigned u; } ca, cb;
    ca.u = hw.x; cb.u = hw.y;
    float2 ha = __half22float2(ca.h2), hb = __half22float2(cb.h2);
    float hs[4] = { ha.x, ha.y, hb.x, hb.y };
    #pragma unroll
    for (int j = 0; j < 4; ++j) {
        int in = sub * 4 + j;
        float2 rt = *(const float2*)&sr[in * OUTC + 2 * c2];
        accx = fmaf(hs[j], rt.x, accx);
        accy = fmaf(hs[j], rt.y, accy);
    }
    accx += __shfl_xor(accx, 8);  accy += __shfl_xor(accy, 8);
    accx += __shfl_xor(accx, 16); accy += __shfl_xor(accy, 16);
    accx += __shfl_xor(accx, 32); accy += __shfl_xor(accy, 32);
    if (sub == 0) {
        float2 bb = *(const float2*)&b2[2 * c2];
        *(float2*)&out[(size_t)wid * OUTC + 2 * c2] =
            make_float2(accx + bb.x, accy + bb.y);
    }
}

// ---------------------------------------------------------------------------
extern "C" void kernel_launch(void* const* d_in, const int* in_sizes, int n_in,
                              void* d_out, int out_size, void* d_ws, size_t ws_size,
                              hipStream_t stream) {
    const float* x     = (const float*)d_in[0];
    const int*   ei    = (const int*)d_in[1];   // [2, NE]
    const int*   et    = (const int*)d_in[2];   // [NE]
    const float* W1    = (const float*)d_in[3];
    const float* root1 = (const float*)d_in[4];
    const float* b1    = (const float*)d_in[5];
    const float* W2    = (const float*)d_in[6];
    const float* root2 = (const float*)d_in[7];
    const float* b2    = (const float*)d_in[8];
    float* out = (float*)d_out;

    char* ws = (char*)d_ws;
    size_t o = 0;
    auto alloc = [&](size_t bytes) -> char* {
        char* p = ws + o;
        o = (o + bytes + 255) & ~(size_t)255;
        return p;
    };
    // rsorted FIRST: single 0xFF memset marks all slots as pads (dst=0xFFFF);
    // rscatter_k overwrites exactly the NE real slots. NOTHING needs zeroing.
    unsigned* rsorted = (unsigned*)alloc((size_t)MAXE * 4);        // 4.8 MB
    size_t ff_bytes = o;
    unsigned* ghist   = (unsigned*)alloc((size_t)NR * NB * 4);     // 53 KB
    unsigned* rbase   = (unsigned*)alloc((size_t)NR * NB * 4);
    unsigned* rngs    = (unsigned*)alloc((size_t)NR * 2 * 4);
    int*      chunkrel= (int*)     alloc((size_t)NCHUNK * 4);      // 75 KB
    unsigned short* rank16 = (unsigned short*)alloc((size_t)MAXE * 2); // 2.4 MB
    unsigned* cnt     = (unsigned*)alloc((size_t)NR * NN * 4);     // 9.0 MB
    unsigned* packed  = (unsigned*)alloc((size_t)NR * NN * 4);     // 9.0 MB
    unsigned* dhist   = (unsigned*)alloc((size_t)NN * 4);
    unsigned* rowptr  = (unsigned*)alloc(((size_t)NN + 1) * 4);
    uint2*    pedges  = (uint2*)   alloc((size_t)MAXE * 8);        // 9.6 MB
    __half*   W1th    = (__half*)  alloc((size_t)NR * HIDC * INC * 2);
    __half*   W2th    = (__half*)  alloc((size_t)NR * OUTC * HIDC * 2);
    __half*   xh      = (__half*)  alloc((size_t)NN * INC * 2);    // 6.4 MB
    __half*   hh      = (__half*)  alloc((size_t)NN * HIDC * 2);   // 3.2 MB
    // msg buffers alias: msg1 (f16, 64-B rows) fully consumed by gather1
    // before msg2 (f16, 32-B rows) is produced.
    char*     msgraw  = alloc(((size_t)NE + 1) * 64);              // 76.9 MB
    __half*   msg1    = (__half*)msgraw;
    __half*   msg2    = (__half*)msgraw;

    hipMemsetAsync(d_ws, 0xFF, ff_bytes, stream);
    prep_w    <<<(NR * HIDC * INC + 255) / 256, 256, 0, stream>>>(W1, W2, W1th, W2th);
    cast_x    <<<NN * INC / 2 / 256, 256, 0, stream>>>(x, xh);
    rhist_k   <<<NB, 256, 0, stream>>>(ei, et, ghist);
    rscan_k   <<<1, 1024, 0, stream>>>(ghist, rbase, rngs, chunkrel);
    rscatter_k<<<NB, 256, 0, stream>>>(ei, et, rbase, rsorted);
    relcnt_k  <<<2 * NR, 1024, 0, stream>>>(rsorted, rngs, cnt, rank16);
    drel_k    <<<(NN + 255) / 256, 256, 0, stream>>>(cnt, packed, dhist);
    dprefix_k <<<1, 1024, 0, stream>>>(dhist, rowptr);
    finalize_k<<<(MAXE + 255) / 256, 256, 0, stream>>>(rsorted, rank16, packed,
                                                       rowptr, chunkrel, pedges);
    msg1_k    <<<(MAXE + 255) / 256, 256, 0, stream>>>(xh, W1th, pedges, msg1);
    gather1_k <<<NN * 64 / 256, 256, 0, stream>>>(x, root1, b1, msg1, rowptr, hh);
    msg2_k    <<<(MAXE + 255) / 256, 256, 0, stream>>>(hh, W2th, pedges, msg2);
    gather2_k <<<NN * 64 / 256, 256, 0, stream>>>(hh, root2, b2, msg2, rowptr, out);
}

// Round 8
// 371.838 us; speedup vs baseline: 10.8328x; 1.0400x over previous
//
#include <hip/hip_runtime.h>
#include <hip/hip_fp16.h>
#include <cstdint>
#include <cstddef>

// Problem constants (match reference setup_inputs)
#define NN   50000      // nodes  (< 65536: src/dst fit 16 bits)
#define NE   1200000    // edges
#define NR   45         // relations (< 64: rel fits 6 bits)
#define INC  64
#define HIDC 32
#define OUTC 16
// Padded edge capacity: each relation bucket padded to multiple of 64 so every
// wave's 64 edges share one relation. NE + NR*64, itself a multiple of 64.
#define MAXE 1202880
#define NCHUNK (MAXE/64)
// relation counting-sort blocking
#define EPB 4096
#define NB  ((NE + EPB - 1) / EPB)      // 293 blocks
// relcnt LDS: 16000 words x two 16-bit counters = 32000 dsts per half
#define HALFW 16000
#define HALFD (2 * HALFW)
// LDS row strides (f32 words) for the MFMA epilogue transpose: chosen so both
// the C-scatter writes and the per-edge row reads are <=2-way bank conflicts.
#define MS1 34
#define MS2 18

typedef _Float16 f16x8 __attribute__((ext_vector_type(8)));
typedef float    f32x4 __attribute__((ext_vector_type(4)));

union F16Bits { unsigned short u; _Float16 f; };
union ABFrag   { uint4 u; f16x8 f; };

// ---------------------------------------------------------------------------
// Precompute MFMA B-operand fragments per relation, in exact lane order:
//   B[k][n] fragment for 16x16x32: lane holds k=(lane>>4)*8+j, n=lane&15.
// W1 (64x32): 2 k-tiles x 2 n-tiles -> W1f[r][kb][nb][lane][j]  (NR*2048 f16)
// W2 (32x16): 1 k-tile  x 1 n-tile -> W2f[r][lane][j]           (NR*512  f16)
__global__ __launch_bounds__(256) void prep_w(const float* __restrict__ W1,
                                              const float* __restrict__ W2,
                                              __half* __restrict__ W1f,
                                              __half* __restrict__ W2f) {
    int t = blockIdx.x * 256 + threadIdx.x;
    if (t < NR * 2048) {
        int r = t >> 11, rem = t & 2047;
        int kb = rem >> 10, nb = (rem >> 9) & 1;
        int lane = (rem >> 3) & 63, j = rem & 7;
        int k = kb * 32 + (lane >> 4) * 8 + j;
        int n = nb * 16 + (lane & 15);
        W1f[t] = __float2half(W1[(r * INC + k) * HIDC + n]);
    }
    if (t < NR * 512) {
        int r = t >> 9, rem = t & 511;
        int lane = (rem >> 3) & 63, j = rem & 7;
        int k = (lane >> 4) * 8 + j;
        int n = lane & 15;
        W2f[t] = __float2half(W2[(r * HIDC + k) * OUTC + n]);
    }
}

// Cast x (f32) -> xh (f16), pairwise.
__global__ __launch_bounds__(256) void cast_x(const float* __restrict__ x,
                                              __half* __restrict__ xh) {
    int t = blockIdx.x * 256 + threadIdx.x;   // NN*INC/2 exact multiple of 256
    float2 f = ((const float2*)x)[t];
    union { __half2 h; unsigned u; } cv;
    cv.h = __floats2half2_rn(f.x, f.y);
    ((unsigned*)xh)[t] = cv.u;
}

// ---------------------------------------------------------------------------
// ATOMIC-FREE relation counting sort, step 1: per-block 45-bin histograms
// (LDS atomics only). ghist[b*NR + r] = #edges of relation r in block b
// ([b][r] layout so rscan's row-prefix loop reads coalesced).
__global__ __launch_bounds__(256) void rhist_k(const int* __restrict__ ei,
                                               const int* __restrict__ et,
                                               unsigned* __restrict__ ghist) {
    __shared__ unsigned lh[NR];
    int t = threadIdx.x, b = blockIdx.x;
    if (t < NR) lh[t] = 0;
    __syncthreads();
    #pragma unroll
    for (int it = 0; it < EPB / 256; ++it) {
        int e = b * EPB + it * 256 + t;
        if (e < NE) {
            int r = et[e], src = ei[e], dst = ei[NE + e];
            if ((unsigned)r < NR && (unsigned)src < NN && (unsigned)dst < NN)
                atomicAdd(&lh[r], 1u);
        }
    }
    __syncthreads();
    if (t < NR) ghist[b * NR + t] = lh[t];
}

// Step 2 (single block): exclusive prefix within each relation (in place,
// coalesced [b][r] reads), 64-padded relation bases, per-(r,block) scatter
// bases, relation ranges, and chunk->relation via parallel binary search.
__global__ __launch_bounds__(1024) void rscan_k(unsigned* __restrict__ ghist,
                                                unsigned* __restrict__ rbase,
                                                unsigned* __restrict__ rngs,
                                                int* __restrict__ chunkrel) {
    __shared__ unsigned relbase[NR + 1];
    __shared__ unsigned reltot[NR];
    int t = threadIdx.x;
    if (t < NR) {                       // row prefix; lane t reads ghist[b][t]
        unsigned run = 0;
        for (int b = 0; b < NB; ++b) {
            unsigned v = ghist[b * NR + t];
            ghist[b * NR + t] = run;
            run += v;
        }
        reltot[t] = run;
    }
    __syncthreads();
    if (t == 0) {                       // padded relation bases
        unsigned acc = 0;
        for (int r = 0; r < NR; ++r) {
            relbase[r] = acc;
            acc += ((reltot[r] + 63u) >> 6) << 6;
        }
        relbase[NR] = acc;
    }
    __syncthreads();
    for (int i = t; i < NR * NB; i += 1024) {
        int r = i / NB, b = i % NB;     // rbase stays [r][b] for rscatter
        rbase[i] = ghist[b * NR + r] + relbase[r];
    }
    if (t < NR) {
        rngs[2 * t]     = relbase[t];
        rngs[2 * t + 1] = relbase[t] + reltot[t];
    }
    // chunk -> relation: binary search over relbase (ascending)
    for (int c = t; c < NCHUNK; c += 1024) {
        unsigned pos = (unsigned)c << 6;
        int lo = 0, hi = NR - 1;
        while (lo < hi) {
            int mid = (lo + hi + 1) >> 1;
            if (relbase[mid] <= pos) lo = mid; else hi = mid - 1;
        }
        chunkrel[c] = lo;
    }
}

// Step 3: deterministic scatter into relation buckets (LDS atomics only).
// rsorted[pos] = {dst:16 | src:16}. Pad slots keep 0xFFFFFFFF (dst sentinel).
__global__ __launch_bounds__(256) void rscatter_k(const int* __restrict__ ei,
                                                  const int* __restrict__ et,
                                                  const unsigned* __restrict__ rbase,
                                                  unsigned* __restrict__ rsorted) {
    __shared__ unsigned lbase[NR], lcur[NR];
    int t = threadIdx.x, b = blockIdx.x;
    if (t < NR) { lbase[t] = rbase[t * NB + b]; lcur[t] = 0; }
    __syncthreads();
    #pragma unroll
    for (int it = 0; it < EPB / 256; ++it) {
        int e = b * EPB + it * 256 + t;
        if (e < NE) {
            int r = et[e], src = ei[e], dst = ei[NE + e];
            if ((unsigned)r < NR && (unsigned)src < NN && (unsigned)dst < NN) {
                unsigned local = atomicAdd(&lcur[r], 1u);
                rsorted[lbase[r] + local] = (unsigned)src | ((unsigned)dst << 16);
            }
        }
    }
}

// Per-relation dst counts + per-edge rank, all in LDS (two packed u16 counters
// per word). One block = one (relation, dst-half) pair -> grid 2*NR.
__global__ __launch_bounds__(1024) void relcnt_k(const unsigned* __restrict__ rsorted,
                                                 const unsigned* __restrict__ rngs,
                                                 unsigned* __restrict__ cnt,
                                                 unsigned short* __restrict__ rank16) {
    __shared__ unsigned lds[HALFW];     // 64000 B
    int r = blockIdx.x >> 1, half = blockIdx.x & 1, t = threadIdx.x;
    unsigned base = rngs[2 * r], end = rngs[2 * r + 1];
    unsigned dlo = half * HALFD;
    unsigned dhi = (dlo + HALFD < NN) ? (dlo + HALFD) : NN;
    for (int w = t; w < HALFW; w += 1024) lds[w] = 0;
    __syncthreads();
    for (unsigned s = base + t; s < end; s += 1024) {
        unsigned d = rsorted[s] >> 16;
        if (d >= dlo && d < dhi) {
            unsigned off = d - dlo;
            atomicAdd(&lds[off >> 1], (off & 1) ? 0x10000u : 1u);
        }
    }
    __syncthreads();
    for (int w = t; w < HALFW; w += 1024) {
        unsigned u = lds[w];
        unsigned d0 = dlo + 2 * w;
        if (d0 < dhi) cnt[(size_t)r * NN + d0] = u & 0xFFFFu;
        unsigned d1 = d0 + 1;
        if (d1 < dhi) cnt[(size_t)r * NN + d1] = u >> 16;
    }
    __syncthreads();
    for (int w = t; w < HALFW; w += 1024) lds[w] = 0;
    __syncthreads();
    for (unsigned s = base + t; s < end; s += 1024) {
        unsigned d = rsorted[s] >> 16;
        if (d >= dlo && d < dhi) {
            unsigned off = d - dlo;
            unsigned old = atomicAdd(&lds[off >> 1], (off & 1) ? 0x10000u : 1u);
            rank16[s] = (unsigned short)((off & 1) ? (old >> 16) : (old & 0xFFFFu));
        }
    }
}

// Per-dst: relation-prefix offsets + f16 inverse counts, packed one word per
// (r,dst): {reloff:16 | f16(1/cnt):16}. Also derives dhist[dst] = degree.
__global__ __launch_bounds__(256) void drel_k(const unsigned* __restrict__ cnt,
                                              unsigned* __restrict__ packed,
                                              unsigned* __restrict__ dhist) {
    int dst = blockIdx.x * 256 + threadIdx.x;
    if (dst >= NN) return;
    unsigned run = 0;
    #pragma unroll 5
    for (int r = 0; r < NR; ++r) {
        unsigned c = cnt[(size_t)r * NN + dst];
        F16Bits fb; fb.f = (_Float16)(c ? 1.0f / (float)c : 0.0f);
        packed[(size_t)r * NN + dst] = (run & 0xFFFFu) | ((unsigned)fb.u << 16);
        run += c;
    }
    dhist[dst] = run;
}

// Exclusive prefix over NN dst bins -> rowptr[NN+1].
// Tiled block scan: 1024-thread coalesced tiles, wave shfl_up scan + 16-wave
// LDS combine + running carry.
__global__ __launch_bounds__(1024) void dprefix_k(const unsigned* __restrict__ dhist,
                                                  unsigned* __restrict__ rowptr) {
    __shared__ unsigned wsum[16];
    __shared__ unsigned carry_s;
    int t = threadIdx.x;
    int lane = t & 63, wv = t >> 6;
    if (t == 0) carry_s = 0;
    __syncthreads();
    for (int base = 0; base < NN; base += 1024) {
        int i = base + t;
        unsigned v = (i < NN) ? dhist[i] : 0u;
        unsigned s = v;                        // inclusive wave scan
        #pragma unroll
        for (int off = 1; off < 64; off <<= 1) {
            unsigned n = __shfl_up(s, off);
            if (lane >= off) s += n;
        }
        if (lane == 63) wsum[wv] = s;
        __syncthreads();
        if (wv == 0) {                         // scan the 16 wave totals
            unsigned ws = (lane < 16) ? wsum[lane] : 0u;
            #pragma unroll
            for (int off = 1; off < 16; off <<= 1) {
                unsigned n = __shfl_up(ws, off);
                if (lane >= off) ws += n;
            }
            if (lane < 16) wsum[lane] = ws;    // inclusive over waves
        }
        __syncthreads();
        unsigned waveoff = (wv == 0) ? 0u : wsum[wv - 1];
        unsigned carry = carry_s;
        if (i < NN) rowptr[i] = carry + waveoff + s - v;
        __syncthreads();
        if (t == 1023) carry_s = carry + wsum[15];
        __syncthreads();
    }
    if (t == 0) rowptr[NN] = carry_s;
}

// Build final edge records: word0 = src | scale_f16<<16 ; word1 = dpos | rel<<25.
// Pad slots (dst sentinel) -> {0, 0x80000000}.
__global__ __launch_bounds__(256) void finalize_k(const unsigned* __restrict__ rsorted,
                                                  const unsigned short* __restrict__ rank16,
                                                  const unsigned* __restrict__ packed,
                                                  const unsigned* __restrict__ rowptr,
                                                  const int* __restrict__ chunkrel,
                                                  uint2* __restrict__ pedges) {
    int s = blockIdx.x * 256 + threadIdx.x;
    if (s >= MAXE) return;
    unsigned v = rsorted[s];
    unsigned dst = v >> 16;
    if (dst >= NN) { pedges[s] = make_uint2(0u, 0x80000000u); return; }
    int r = chunkrel[s >> 6];
    unsigned pk = packed[(size_t)r * NN + dst];
    unsigned dpos = rowptr[dst] + (pk & 0xFFFFu) + (unsigned)rank16[s];
    pedges[s] = make_uint2((v & 0xFFFFu) | (pk & 0xFFFF0000u),
                           dpos | ((unsigned)r << 25));
}

// ---------------------------------------------------------------------------
// Layer-1 messages via MFMA. One wave = 64 edges of ONE relation = 4 tiles of
// 16 edges. Per tile: A-frags from xh (A[m=lane&15][k=quad*8+j], src via
// shfl), 4x mfma_f32_16x16x32_f16 against the wave-uniform precomputed B
// fragments, C transposed through padded LDS (stride 34: <=2-way conflicts),
// scaled per edge, written as 64-B f16 rows at DST-SORTED slots.
__global__ __launch_bounds__(256) void msg1_k(const __half* __restrict__ xh,
                                              const __half* __restrict__ W1f,
                                              const uint2* __restrict__ pedges,
                                              __half* __restrict__ msg) {
    __shared__ float lmsg[4 * 64 * MS1];    // 34816 B
    int tid = threadIdx.x;
    int wv = tid >> 6, lane = tid & 63;
    int wave = (blockIdx.x * 256 + tid) >> 6;
    if (wave >= NCHUNK) return;
    int e = (wave << 6) + lane;
    uint2 er = pedges[e];
    int w1 = (int)er.y;
    int rel = __builtin_amdgcn_readfirstlane((w1 >> 25) & 63);  // wave-uniform
    F16Bits fb; fb.u = (unsigned short)(er.x >> 16);
    float sc = (float)fb.f;
    int src = er.x & 0xFFFF;
    int drow = (w1 < 0) ? NE : (w1 & 0x1FFFFFF);                // pads -> dump
    // B fragments: [kb][nb] -> 4 coalesced 16-B loads, wave-uniform base
    const uint4* __restrict__ wf = (const uint4*)W1f + (size_t)rel * 256;
    ABFrag b00, b01, b10, b11;
    b00.u = wf[0 * 64 + lane];
    b01.u = wf[1 * 64 + lane];
    b10.u = wf[2 * 64 + lane];
    b11.u = wf[3 * 64 + lane];
    int quad = lane >> 4, col = lane & 15;
    float* __restrict__ lrow = lmsg + wv * (64 * MS1);
    #pragma unroll
    for (int tl = 0; tl < 4; ++tl) {
        int s = __shfl(src, tl * 16 + col);
        const uint4* __restrict__ xp = (const uint4*)(xh + (size_t)s * INC) + quad;
        ABFrag a0, a1;
        a0.u = xp[0];          // k = quad*8 .. +8
        a1.u = xp[4];          // k = 32 + quad*8 .. +8
        f32x4 acc0 = {0.f, 0.f, 0.f, 0.f}, acc1 = {0.f, 0.f, 0.f, 0.f};
        acc0 = __builtin_amdgcn_mfma_f32_16x16x32_f16(a0.f, b00.f, acc0, 0, 0, 0);
        acc0 = __builtin_amdgcn_mfma_f32_16x16x32_f16(a1.f, b10.f, acc0, 0, 0, 0);
        acc1 = __builtin_amdgcn_mfma_f32_16x16x32_f16(a0.f, b01.f, acc1, 0, 0, 0);
        acc1 = __builtin_amdgcn_mfma_f32_16x16x32_f16(a1.f, b11.f, acc1, 0, 0, 0);
        // C: row = quad*4 + i, col = lane&15 (+16 for the second n-tile)
        float* __restrict__ lt = lrow + (tl * 16 + quad * 4) * MS1;
        #pragma unroll
        for (int i = 0; i < 4; ++i) {
            lt[i * MS1 + col]      = acc0[i];
            lt[i * MS1 + col + 16] = acc1[i];
        }
    }
    // epilogue: each lane reads its OWN edge's 32 f32, scales, packs f16.
    // Wave-synchronous LDS (no cross-wave sharing) -> no barrier needed.
    const float* __restrict__ myrow = lrow + lane * MS1;
    unsigned um[16];
    #pragma unroll
    for (int k = 0; k < 16; ++k) {
        float2 v = *(const float2*)(myrow + 2 * k);
        union { __half2 h; unsigned u; } cv;
        cv.h = __floats2half2_rn(v.x * sc, v.y * sc);
        um[k] = cv.u;
    }
    uint4* __restrict__ mrow = (uint4*)(msg + (size_t)drow * HIDC);
    #pragma unroll
    for (int q = 0; q < 4; ++q)
        mrow[q] = make_uint4(um[4*q], um[4*q+1], um[4*q+2], um[4*q+3]);
}

// Layer-2 messages via MFMA (32 -> 16): one k-tile, one n-tile -> 1 MFMA per
// 16-edge tile. h f16 (3.2 MB, L2-resident). 32-B f16 rows at dst slots.
__global__ __launch_bounds__(256) void msg2_k(const __half* __restrict__ hh,
                                              const __half* __restrict__ W2f,
                                              const uint2* __restrict__ pedges,
                                              __half* __restrict__ msg) {
    __shared__ float lmsg[4 * 64 * MS2];    // 18432 B
    int tid = threadIdx.x;
    int wv = tid >> 6, lane = tid & 63;
    int wave = (blockIdx.x * 256 + tid) >> 6;
    if (wave >= NCHUNK) return;
    int e = (wave << 6) + lane;
    uint2 er = pedges[e];
    int w1 = (int)er.y;
    int rel = __builtin_amdgcn_readfirstlane((w1 >> 25) & 63);
    F16Bits fb; fb.u = (unsigned short)(er.x >> 16);
    float sc = (float)fb.f;
    int src = er.x & 0xFFFF;
    int drow = (w1 < 0) ? NE : (w1 & 0x1FFFFFF);
    ABFrag bf;
    bf.u = ((const uint4*)W2f + (size_t)rel * 64)[lane];
    int quad = lane >> 4, col = lane & 15;
    float* __restrict__ lrow = lmsg + wv * (64 * MS2);
    #pragma unroll
    for (int tl = 0; tl < 4; ++tl) {
        int s = __shfl(src, tl * 16 + col);
        ABFrag a;
        a.u = *((const uint4*)(hh + (size_t)s * HIDC) + quad);  // k = quad*8
        f32x4 acc = {0.f, 0.f, 0.f, 0.f};
        acc = __builtin_amdgcn_mfma_f32_16x16x32_f16(a.f, bf.f, acc, 0, 0, 0);
        float* __restrict__ lt = lrow + (tl * 16 + quad * 4) * MS2;
        #pragma unroll
        for (int i = 0; i < 4; ++i) lt[i * MS2 + col] = acc[i];
    }
    const float* __restrict__ myrow = lrow + lane * MS2;
    unsigned um[8];
    #pragma unroll
    for (int k = 0; k < 8; ++k) {
        float2 v = *(const float2*)(myrow + 2 * k);
        union { __half2 h; unsigned u; } cv;
        cv.h = __floats2half2_rn(v.x * sc, v.y * sc);
        um[k] = cv.u;
    }
    uint4* __restrict__ mrow = (uint4*)(msg + (size_t)drow * OUTC);
    mrow[0] = make_uint4(um[0], um[1], um[2], um[3]);
    mrow[1] = make_uint4(um[4], um[5], um[6], um[7]);
}

// ---------------------------------------------------------------------------
// Fused gather + node update 1: h = relu(sum(msg rows) + x @ root1 + b1), f16 out.
// One wave per node; msg rows contiguous (dst-sorted). lane = (sub,c2):
// sub in [0,4) streams k, c2 in [0,16) covers 32 ch as half2.
__global__ __launch_bounds__(256) void gather1_k(const float* __restrict__ x,
                                                 const float* __restrict__ root1,
                                                 const float* __restrict__ b1,
                                                 const __half* __restrict__ msg,
                                                 const unsigned* __restrict__ rowptr,
                                                 __half* __restrict__ hh) {
    __shared__ float sr[INC * HIDC];   // 8 KB, [in][c]
    for (int k = threadIdx.x; k < INC * HIDC; k += 256) sr[k] = root1[k];
    __syncthreads();
    int wid = (blockIdx.x * 256 + threadIdx.x) >> 6;   // node id; grid exact
    int lane = threadIdx.x & 63;
    int c2 = lane & 15, sub = lane >> 4;
    unsigned k0 = rowptr[wid], k1 = rowptr[wid + 1];
    float accx = 0.f, accy = 0.f;
    for (unsigned k = k0 + sub; k < k1; k += 4) {
        union { __half2 hh2; unsigned u; } cv;
        cv.u = ((const unsigned*)(msg + (size_t)k * HIDC))[c2];
        float2 f = __half22float2(cv.hh2);
        accx += f.x; accy += f.y;
    }
    // root contribution: sub handles input range [sub*16, sub*16+16)
    const float4* __restrict__ xp = (const float4*)(x + (size_t)wid * INC + sub * 16);
    #pragma unroll
    for (int q = 0; q < 4; ++q) {
        float4 xr = xp[q];
        const float* xs = (const float*)&xr;
        #pragma unroll
        for (int j = 0; j < 4; ++j) {
            int in = sub * 16 + q * 4 + j;
            float2 rt = *(const float2*)&sr[in * HIDC + 2 * c2];
            accx = fmaf(xs[j], rt.x, accx);
            accy = fmaf(xs[j], rt.y, accy);
        }
    }
    accx += __shfl_xor(accx, 16); accy += __shfl_xor(accy, 16);
    accx += __shfl_xor(accx, 32); accy += __shfl_xor(accy, 32);
    if (sub == 0) {
        float2 bb = *(const float2*)&b1[2 * c2];
        float vx = accx + bb.x, vy = accy + bb.y;
        union { __half2 h2; unsigned u; } cv;
        cv.h2 = __floats2half2_rn(vx > 0.f ? vx : 0.f, vy > 0.f ? vy : 0.f);
        ((unsigned*)hh)[(size_t)wid * (HIDC / 2) + c2] = cv.u;
    }
}

// Fused gather + node update 2: out = sum(msg rows) + h @ root2 + b2 (f32 out).
// One wave per node; c2 in [0,8) covers 16 ch as half2; sub in [0,8) streams k.
__global__ __launch_bounds__(256) void gather2_k(const __half* __restrict__ hh,
                                                 const float* __restrict__ root2,
                                                 const float* __restrict__ b2,
                                                 const __half* __restrict__ msg,
                                                 const unsigned* __restrict__ rowptr,
                                                 float* __restrict__ out) {
    __shared__ float sr[HIDC * OUTC];  // 2 KB, [in][c]
    for (int k = threadIdx.x; k < HIDC * OUTC; k += 256) sr[k] = root2[k];
    __syncthreads();
    int wid = (blockIdx.x * 256 + threadIdx.x) >> 6;
    int lane = threadIdx.x & 63;
    int c2 = lane & 7, sub = lane >> 3;   // 8 streams
    unsigned k0 = rowptr[wid], k1 = rowptr[wid + 1];
    float accx = 0.f, accy = 0.f;
    for (unsigned k = k0 + sub; k < k1; k += 8) {
        union { __half2 hh2; unsigned u; } cv;
        cv.u = ((const unsigned*)(msg + (size_t)k * OUTC))[c2];
        float2 f = __half22float2(cv.hh2);
        accx += f.x; accy += f.y;
    }
    // root contribution: sub handles input range [sub*4, sub*4+4)
    uint2 hw = *(const uint2*)(hh + (size_t)wid * HIDC + sub * 4);
    union { __half2 h2; unsigned u; } ca, cb;
    ca.u = hw.x; cb.u = hw.y;
    float2 ha = __half22float2(ca.h2), hb = __half22float2(cb.h2);
    float hs[4] = { ha.x, ha.y, hb.x, hb.y };
    #pragma unroll
    for (int j = 0; j < 4; ++j) {
        int in = sub * 4 + j;
        float2 rt = *(const float2*)&sr[in * OUTC + 2 * c2];
        accx = fmaf(hs[j], rt.x, accx);
        accy = fmaf(hs[j], rt.y, accy);
    }
    accx += __shfl_xor(accx, 8);  accy += __shfl_xor(accy, 8);
    accx += __shfl_xor(accx, 16); accy += __shfl_xor(accy, 16);
    accx += __shfl_xor(accx, 32); accy += __shfl_xor(accy, 32);
    if (sub == 0) {
        float2 bb = *(const float2*)&b2[2 * c2];
        *(float2*)&out[(size_t)wid * OUTC + 2 * c2] =
            make_float2(accx + bb.x, accy + bb.y);
    }
}

// ---------------------------------------------------------------------------
extern "C" void kernel_launch(void* const* d_in, const int* in_sizes, int n_in,
                              void* d_out, int out_size, void* d_ws, size_t ws_size,
                              hipStream_t stream) {
    const float* x     = (const float*)d_in[0];
    const int*   ei    = (const int*)d_in[1];   // [2, NE]
    const int*   et    = (const int*)d_in[2];   // [NE]
    const float* W1    = (const float*)d_in[3];
    const float* root1 = (const float*)d_in[4];
    const float* b1    = (const float*)d_in[5];
    const float* W2    = (const float*)d_in[6];
    const float* root2 = (const float*)d_in[7];
    const float* b2    = (const float*)d_in[8];
    float* out = (float*)d_out;

    char* ws = (char*)d_ws;
    size_t o = 0;
    auto alloc = [&](size_t bytes) -> char* {
        char* p = ws + o;
        o = (o + bytes + 255) & ~(size_t)255;
        return p;
    };
    // rsorted FIRST: single 0xFF memset marks all slots as pads (dst=0xFFFF);
    // rscatter_k overwrites exactly the NE real slots. NOTHING needs zeroing.
    unsigned* rsorted = (unsigned*)alloc((size_t)MAXE * 4);        // 4.8 MB
    size_t ff_bytes = o;
    unsigned* ghist   = (unsigned*)alloc((size_t)NR * NB * 4);     // 53 KB
    unsigned* rbase   = (unsigned*)alloc((size_t)NR * NB * 4);
    unsigned* rngs    = (unsigned*)alloc((size_t)NR * 2 * 4);
    int*      chunkrel= (int*)     alloc((size_t)NCHUNK * 4);      // 75 KB
    unsigned short* rank16 = (unsigned short*)alloc((size_t)MAXE * 2); // 2.4 MB
    unsigned* cnt     = (unsigned*)alloc((size_t)NR * NN * 4);     // 9.0 MB
    unsigned* packed  = (unsigned*)alloc((size_t)NR * NN * 4);     // 9.0 MB
    unsigned* dhist   = (unsigned*)alloc((size_t)NN * 4);
    unsigned* rowptr  = (unsigned*)alloc(((size_t)NN + 1) * 4);
    uint2*    pedges  = (uint2*)   alloc((size_t)MAXE * 8);        // 9.6 MB
    __half*   W1f     = (__half*)  alloc((size_t)NR * 2048 * 2);   // 184 KB
    __half*   W2f     = (__half*)  alloc((size_t)NR * 512 * 2);    //  46 KB
    __half*   xh      = (__half*)  alloc((size_t)NN * INC * 2);    // 6.4 MB
    __half*   hh      = (__half*)  alloc((size_t)NN * HIDC * 2);   // 3.2 MB
    // msg buffers alias: msg1 (f16, 64-B rows) fully consumed by gather1
    // before msg2 (f16, 32-B rows) is produced.
    char*     msgraw  = alloc(((size_t)NE + 1) * 64);              // 76.9 MB
    __half*   msg1    = (__half*)msgraw;
    __half*   msg2    = (__half*)msgraw;

    hipMemsetAsync(d_ws, 0xFF, ff_bytes, stream);
    prep_w    <<<(NR * 2048 + 255) / 256, 256, 0, stream>>>(W1, W2, W1f, W2f);
    cast_x    <<<NN * INC / 2 / 256, 256, 0, stream>>>(x, xh);
    rhist_k   <<<NB, 256, 0, stream>>>(ei, et, ghist);
    rscan_k   <<<1, 1024, 0, stream>>>(ghist, rbase, rngs, chunkrel);
    rscatter_k<<<NB, 256, 0, stream>>>(ei, et, rbase, rsorted);
    relcnt_k  <<<2 * NR, 1024, 0, stream>>>(rsorted, rngs, cnt, rank16);
    drel_k    <<<(NN + 255) / 256, 256, 0, stream>>>(cnt, packed, dhist);
    dprefix_k <<<1, 1024, 0, stream>>>(dhist, rowptr);
    finalize_k<<<(MAXE + 255) / 256, 256, 0, stream>>>(rsorted, rank16, packed,
                                                       rowptr, chunkrel, pedges);
    msg1_k    <<<(MAXE + 255) / 256, 256, 0, stream>>>(xh, W1f, pedges, msg1);
    gather1_k <<<NN * 64 / 256, 256, 0, stream>>>(x, root1, b1, msg1, rowptr, hh);
    msg2_k    <<<(MAXE + 255) / 256, 256, 0, stream>>>(hh, W2f, pedges, msg2);
    gather2_k <<<NN * 64 / 256, 256, 0, stream>>>(hh, root2, b2, msg2, rowptr, out);
}

// Round 9
// 367.064 us; speedup vs baseline: 10.9737x; 1.0130x over previous
//
#include <hip/hip_runtime.h>
#include <hip/hip_fp16.h>
#include <cstdint>
#include <cstddef>

// Problem constants (match reference setup_inputs)
#define NN   50000      // nodes  (< 65536: src/dst fit 16 bits)
#define NE   1200000    // edges
#define NR   45         // relations (< 64: rel fits 6 bits)
#define INC  64
#define HIDC 32
#define OUTC 16
// Padded edge capacity: each relation bucket padded to multiple of 64 so every
// wave's 64 edges share one relation. NE + NR*64, itself a multiple of 64.
#define MAXE 1202880
#define NCHUNK (MAXE/64)
// relation counting-sort blocking
#define EPB 4096
#define NB  ((NE + EPB - 1) / EPB)      // 293 blocks
#define SEG 16                          // scan segments per relation
#define BPS ((NB + SEG - 1) / SEG)      // 19 blocks per segment
// relcnt LDS: 16000 words x two 16-bit counters = 32000 dsts per half
#define HALFW 16000
#define HALFD (2 * HALFW)
// LDS row strides (f32 words) for the MFMA epilogue transpose (per-tile
// 16-row buffer, reused across the 4 tiles -> 4x less LDS than full-wave).
#define MS1 34
#define MS2 18

typedef _Float16 f16x8 __attribute__((ext_vector_type(8)));
typedef float    f32x4 __attribute__((ext_vector_type(4)));

union F16Bits { unsigned short u; _Float16 f; };
union ABFrag   { uint4 u; f16x8 f; };

// ---------------------------------------------------------------------------
// Fused: MFMA B-fragments per relation + x f32->f16 cast.
//   B[k][n] fragment for 16x16x32: lane holds k=(lane>>4)*8+j, n=lane&15.
// W1 (64x32): 2 k-tiles x 2 n-tiles -> W1f[r][kb][nb][lane][j]  (NR*2048 f16)
// W2 (32x16): 1 k-tile  x 1 n-tile -> W2f[r][lane][j]           (NR*512  f16)
__global__ __launch_bounds__(256) void prep_k(const float* __restrict__ W1,
                                              const float* __restrict__ W2,
                                              const float* __restrict__ x,
                                              __half* __restrict__ W1f,
                                              __half* __restrict__ W2f,
                                              __half* __restrict__ xh) {
    int t = blockIdx.x * 256 + threadIdx.x;
    if (t < NR * 2048) {
        int r = t >> 11, rem = t & 2047;
        int kb = rem >> 10, nb = (rem >> 9) & 1;
        int lane = (rem >> 3) & 63, j = rem & 7;
        int k = kb * 32 + (lane >> 4) * 8 + j;
        int n = nb * 16 + (lane & 15);
        W1f[t] = __float2half(W1[(r * INC + k) * HIDC + n]);
    }
    if (t < NR * 512) {
        int r = t >> 9, rem = t & 511;
        int lane = (rem >> 3) & 63, j = rem & 7;
        int k = (lane >> 4) * 8 + j;
        int n = lane & 15;
        W2f[t] = __float2half(W2[(r * HIDC + k) * OUTC + n]);
    }
    if (t < NN * INC / 2) {
        float2 f = ((const float2*)x)[t];
        union { __half2 h; unsigned u; } cv;
        cv.h = __floats2half2_rn(f.x, f.y);
        ((unsigned*)xh)[t] = cv.u;
    }
}

// ---------------------------------------------------------------------------
// ATOMIC-FREE relation counting sort, step 1: per-block 45-bin histograms
// (LDS atomics only). ghist[b*NR + r] ([b][r] layout: coalesced rscan reads).
__global__ __launch_bounds__(256) void rhist_k(const int* __restrict__ ei,
                                               const int* __restrict__ et,
                                               unsigned* __restrict__ ghist) {
    __shared__ unsigned lh[NR];
    int t = threadIdx.x, b = blockIdx.x;
    if (t < NR) lh[t] = 0;
    __syncthreads();
    #pragma unroll
    for (int it = 0; it < EPB / 256; ++it) {
        int e = b * EPB + it * 256 + t;
        if (e < NE) {
            int r = et[e], src = ei[e], dst = ei[NE + e];
            if ((unsigned)r < NR && (unsigned)src < NN && (unsigned)dst < NN)
                atomicAdd(&lh[r], 1u);
        }
    }
    __syncthreads();
    if (t < NR) ghist[b * NR + t] = lh[t];
}

// Step 2 (single block): exclusive prefix within each relation via a
// two-pass segmented scan (16 segments x 19 blocks, no long serial chains),
// 64-padded relation bases, per-(r,block) scatter bases, relation ranges,
// chunk->relation via parallel binary search.
__global__ __launch_bounds__(1024) void rscan_k(unsigned* __restrict__ ghist,
                                                unsigned* __restrict__ rbase,
                                                unsigned* __restrict__ rngs,
                                                int* __restrict__ chunkrel) {
    __shared__ unsigned part[NR * SEG];     // 2880 B
    __shared__ unsigned relbase[NR + 1];
    __shared__ unsigned reltot[NR];
    int t = threadIdx.x;
    int r = t / SEG, sg = t % SEG;
    if (t < NR * SEG) {                     // pass 1: segment partial sums
        unsigned s = 0;
        int b0 = sg * BPS, b1 = b0 + BPS; if (b1 > NB) b1 = NB;
        for (int b = b0; b < b1; ++b) s += ghist[b * NR + r];
        part[t] = s;
    }
    __syncthreads();
    if (t < NR) {                           // scan the 16 partials per relation
        unsigned run = 0;
        #pragma unroll
        for (int s = 0; s < SEG; ++s) {
            unsigned v = part[t * SEG + s];
            part[t * SEG + s] = run;
            run += v;
        }
        reltot[t] = run;
    }
    __syncthreads();
    if (t == 0) {                           // padded relation bases
        unsigned acc = 0;
        for (int rr = 0; rr < NR; ++rr) {
            relbase[rr] = acc;
            acc += ((reltot[rr] + 63u) >> 6) << 6;
        }
        relbase[NR] = acc;
    }
    __syncthreads();
    if (t < NR * SEG) {                     // pass 2: write back prefixes
        unsigned run = part[t];
        int b0 = sg * BPS, b1 = b0 + BPS; if (b1 > NB) b1 = NB;
        for (int b = b0; b < b1; ++b) {
            unsigned v = ghist[b * NR + r];
            ghist[b * NR + r] = run;
            run += v;
        }
    }
    __syncthreads();
    for (int i = t; i < NR * NB; i += 1024) {
        int rr = i / NB, b = i % NB;        // rbase stays [r][b] for rscatter
        rbase[i] = ghist[b * NR + rr] + relbase[rr];
    }
    if (t < NR) {
        rngs[2 * t]     = relbase[t];
        rngs[2 * t + 1] = relbase[t] + reltot[t];
    }
    // chunk -> relation: binary search over relbase (ascending)
    for (int c = t; c < NCHUNK; c += 1024) {
        unsigned pos = (unsigned)c << 6;
        int lo = 0, hi = NR - 1;
        while (lo < hi) {
            int mid = (lo + hi + 1) >> 1;
            if (relbase[mid] <= pos) lo = mid; else hi = mid - 1;
        }
        chunkrel[c] = lo;
    }
}

// Step 3: deterministic scatter into relation buckets (LDS atomics only).
// rsorted[pos] = {dst:16 | src:16}. Pad slots keep 0xFFFFFFFF (dst sentinel).
__global__ __launch_bounds__(256) void rscatter_k(const int* __restrict__ ei,
                                                  const int* __restrict__ et,
                                                  const unsigned* __restrict__ rbase,
                                                  unsigned* __restrict__ rsorted) {
    __shared__ unsigned lbase[NR], lcur[NR];
    int t = threadIdx.x, b = blockIdx.x;
    if (t < NR) { lbase[t] = rbase[t * NB + b]; lcur[t] = 0; }
    __syncthreads();
    #pragma unroll
    for (int it = 0; it < EPB / 256; ++it) {
        int e = b * EPB + it * 256 + t;
        if (e < NE) {
            int r = et[e], src = ei[e], dst = ei[NE + e];
            if ((unsigned)r < NR && (unsigned)src < NN && (unsigned)dst < NN) {
                unsigned local = atomicAdd(&lcur[r], 1u);
                rsorted[lbase[r] + local] = (unsigned)src | ((unsigned)dst << 16);
            }
        }
    }
}

// Per-relation dst counts + per-edge rank, all in LDS (two packed u16 counters
// per word). One block = one (relation, dst-half) pair -> grid 2*NR.
__global__ __launch_bounds__(1024) void relcnt_k(const unsigned* __restrict__ rsorted,
                                                 const unsigned* __restrict__ rngs,
                                                 unsigned* __restrict__ cnt,
                                                 unsigned short* __restrict__ rank16) {
    __shared__ unsigned lds[HALFW];     // 64000 B
    int r = blockIdx.x >> 1, half = blockIdx.x & 1, t = threadIdx.x;
    unsigned base = rngs[2 * r], end = rngs[2 * r + 1];
    unsigned dlo = half * HALFD;
    unsigned dhi = (dlo + HALFD < NN) ? (dlo + HALFD) : NN;
    for (int w = t; w < HALFW; w += 1024) lds[w] = 0;
    __syncthreads();
    for (unsigned s = base + t; s < end; s += 1024) {
        unsigned d = rsorted[s] >> 16;
        if (d >= dlo && d < dhi) {
            unsigned off = d - dlo;
            atomicAdd(&lds[off >> 1], (off & 1) ? 0x10000u : 1u);
        }
    }
    __syncthreads();
    for (int w = t; w < HALFW; w += 1024) {
        unsigned u = lds[w];
        unsigned d0 = dlo + 2 * w;
        if (d0 < dhi) cnt[(size_t)r * NN + d0] = u & 0xFFFFu;
        unsigned d1 = d0 + 1;
        if (d1 < dhi) cnt[(size_t)r * NN + d1] = u >> 16;
    }
    __syncthreads();
    for (int w = t; w < HALFW; w += 1024) lds[w] = 0;
    __syncthreads();
    for (unsigned s = base + t; s < end; s += 1024) {
        unsigned d = rsorted[s] >> 16;
        if (d >= dlo && d < dhi) {
            unsigned off = d - dlo;
            unsigned old = atomicAdd(&lds[off >> 1], (off & 1) ? 0x10000u : 1u);
            rank16[s] = (unsigned short)((off & 1) ? (old >> 16) : (old & 0xFFFFu));
        }
    }
}

// Per-dst: relation-prefix offsets + f16 inverse counts, packed one word per
// (r,dst): {reloff:16 | f16(1/cnt):16}. Also derives dhist[dst] = degree.
__global__ __launch_bounds__(256) void drel_k(const unsigned* __restrict__ cnt,
                                              unsigned* __restrict__ packed,
                                              unsigned* __restrict__ dhist) {
    int dst = blockIdx.x * 256 + threadIdx.x;
    if (dst >= NN) return;
    unsigned run = 0;
    #pragma unroll 5
    for (int r = 0; r < NR; ++r) {
        unsigned c = cnt[(size_t)r * NN + dst];
        F16Bits fb; fb.f = (_Float16)(c ? 1.0f / (float)c : 0.0f);
        packed[(size_t)r * NN + dst] = (run & 0xFFFFu) | ((unsigned)fb.u << 16);
        run += c;
    }
    dhist[dst] = run;
}

// Exclusive prefix over NN dst bins -> rowptr[NN+1].
// Tiled block scan: 1024-thread coalesced tiles, wave shfl_up scan + 16-wave
// LDS combine + running carry.
__global__ __launch_bounds__(1024) void dprefix_k(const unsigned* __restrict__ dhist,
                                                  unsigned* __restrict__ rowptr) {
    __shared__ unsigned wsum[16];
    __shared__ unsigned carry_s;
    int t = threadIdx.x;
    int lane = t & 63, wv = t >> 6;
    if (t == 0) carry_s = 0;
    __syncthreads();
    for (int base = 0; base < NN; base += 1024) {
        int i = base + t;
        unsigned v = (i < NN) ? dhist[i] : 0u;
        unsigned s = v;                        // inclusive wave scan
        #pragma unroll
        for (int off = 1; off < 64; off <<= 1) {
            unsigned n = __shfl_up(s, off);
            if (lane >= off) s += n;
        }
        if (lane == 63) wsum[wv] = s;
        __syncthreads();
        if (wv == 0) {                         // scan the 16 wave totals
            unsigned ws = (lane < 16) ? wsum[lane] : 0u;
            #pragma unroll
            for (int off = 1; off < 16; off <<= 1) {
                unsigned n = __shfl_up(ws, off);
                if (lane >= off) ws += n;
            }
            if (lane < 16) wsum[lane] = ws;    // inclusive over waves
        }
        __syncthreads();
        unsigned waveoff = (wv == 0) ? 0u : wsum[wv - 1];
        unsigned carry = carry_s;
        if (i < NN) rowptr[i] = carry + waveoff + s - v;
        __syncthreads();
        if (t == 1023) carry_s = carry + wsum[15];
        __syncthreads();
    }
    if (t == 0) rowptr[NN] = carry_s;
}

// Build final edge records: word0 = src | scale_f16<<16 ; word1 = dpos | rel<<25.
// Pad slots (dst sentinel) -> {0, 0x80000000}.
__global__ __launch_bounds__(256) void finalize_k(const unsigned* __restrict__ rsorted,
                                                  const unsigned short* __restrict__ rank16,
                                                  const unsigned* __restrict__ packed,
                                                  const unsigned* __restrict__ rowptr,
                                                  const int* __restrict__ chunkrel,
                                                  uint2* __restrict__ pedges) {
    int s = blockIdx.x * 256 + threadIdx.x;
    if (s >= MAXE) return;
    unsigned v = rsorted[s];
    unsigned dst = v >> 16;
    if (dst >= NN) { pedges[s] = make_uint2(0u, 0x80000000u); return; }
    int r = chunkrel[s >> 6];
    unsigned pk = packed[(size_t)r * NN + dst];
    unsigned dpos = rowptr[dst] + (pk & 0xFFFFu) + (unsigned)rank16[s];
    pedges[s] = make_uint2((v & 0xFFFFu) | (pk & 0xFFFF0000u),
                           dpos | ((unsigned)r << 25));
}

// ---------------------------------------------------------------------------
// Layer-1 messages via MFMA. One wave = 64 edges of ONE relation = 4 tiles of
// 16 edges. Per tile: A-frags from xh (A[m=lane&15][k=quad*8+j], src via
// shfl), 4x mfma_f32_16x16x32_f16 vs wave-uniform precomputed B fragments, C
// transposed through a PER-TILE 16-row LDS buffer (reused across tiles -> 4x
// less LDS -> 8 blocks/CU), epilogue exec-masked to the tile's 16 lanes.
// Wave-synchronous LDS, program-order write->read: no barrier needed.
__global__ __launch_bounds__(256) void msg1_k(const __half* __restrict__ xh,
                                              const __half* __restrict__ W1f,
                                              const uint2* __restrict__ pedges,
                                              __half* __restrict__ msg) {
    __shared__ float lmsg[4 * 16 * MS1];    // 8704 B
    int tid = threadIdx.x;
    int wv = tid >> 6, lane = tid & 63;
    int wave = (blockIdx.x * 256 + tid) >> 6;
    if (wave >= NCHUNK) return;
    int e = (wave << 6) + lane;
    uint2 er = pedges[e];
    int w1 = (int)er.y;
    int rel = __builtin_amdgcn_readfirstlane((w1 >> 25) & 63);  // wave-uniform
    F16Bits fb; fb.u = (unsigned short)(er.x >> 16);
    float sc = (float)fb.f;
    int src = er.x & 0xFFFF;
    int drow = (w1 < 0) ? NE : (w1 & 0x1FFFFFF);                // pads -> dump
    // B fragments: [kb][nb] -> 4 coalesced 16-B loads, wave-uniform base
    const uint4* __restrict__ wf = (const uint4*)W1f + (size_t)rel * 256;
    ABFrag b00, b01, b10, b11;
    b00.u = wf[0 * 64 + lane];
    b01.u = wf[1 * 64 + lane];
    b10.u = wf[2 * 64 + lane];
    b11.u = wf[3 * 64 + lane];
    int quad = lane >> 4, col = lane & 15;
    float* __restrict__ lwave = lmsg + wv * (16 * MS1);
    #pragma unroll
    for (int tl = 0; tl < 4; ++tl) {
        int s = __shfl(src, tl * 16 + col);
        const uint4* __restrict__ xp = (const uint4*)(xh + (size_t)s * INC) + quad;
        ABFrag a0, a1;
        a0.u = xp[0];          // k = quad*8 .. +8
        a1.u = xp[4];          // k = 32 + quad*8 .. +8
        f32x4 acc0 = {0.f, 0.f, 0.f, 0.f}, acc1 = {0.f, 0.f, 0.f, 0.f};
        acc0 = __builtin_amdgcn_mfma_f32_16x16x32_f16(a0.f, b00.f, acc0, 0, 0, 0);
        acc0 = __builtin_amdgcn_mfma_f32_16x16x32_f16(a1.f, b10.f, acc0, 0, 0, 0);
        acc1 = __builtin_amdgcn_mfma_f32_16x16x32_f16(a0.f, b01.f, acc1, 0, 0, 0);
        acc1 = __builtin_amdgcn_mfma_f32_16x16x32_f16(a1.f, b11.f, acc1, 0, 0, 0);
        // C: row = quad*4 + i (edge-in-tile), col = lane&15 (+16 2nd n-tile)
        float* __restrict__ lt = lwave + (quad * 4) * MS1;
        #pragma unroll
        for (int i = 0; i < 4; ++i) {
            lt[i * MS1 + col]      = acc0[i];
            lt[i * MS1 + col + 16] = acc1[i];
        }
        // epilogue for this tile's 16 lanes: read own row, scale, pack, store
        if ((lane >> 4) == tl) {
            const float* __restrict__ myrow = lwave + (lane & 15) * MS1;
            unsigned um[16];
            #pragma unroll
            for (int k = 0; k < 16; ++k) {
                float2 v = *(const float2*)(myrow + 2 * k);
                union { __half2 h; unsigned u; } cv;
                cv.h = __floats2half2_rn(v.x * sc, v.y * sc);
                um[k] = cv.u;
            }
            uint4* __restrict__ mrow = (uint4*)(msg + (size_t)drow * HIDC);
            #pragma unroll
            for (int q = 0; q < 4; ++q)
                mrow[q] = make_uint4(um[4*q], um[4*q+1], um[4*q+2], um[4*q+3]);
        }
    }
}

// Layer-2 messages via MFMA (32 -> 16): 1 MFMA per 16-edge tile, per-tile LDS.
__global__ __launch_bounds__(256) void msg2_k(const __half* __restrict__ hh,
                                              const __half* __restrict__ W2f,
                                              const uint2* __restrict__ pedges,
                                              __half* __restrict__ msg) {
    __shared__ float lmsg[4 * 16 * MS2];    // 4608 B
    int tid = threadIdx.x;
    int wv = tid >> 6, lane = tid & 63;
    int wave = (blockIdx.x * 256 + tid) >> 6;
    if (wave >= NCHUNK) return;
    int e = (wave << 6) + lane;
    uint2 er = pedges[e];
    int w1 = (int)er.y;
    int rel = __builtin_amdgcn_readfirstlane((w1 >> 25) & 63);
    F16Bits fb; fb.u = (unsigned short)(er.x >> 16);
    float sc = (float)fb.f;
    int src = er.x & 0xFFFF;
    int drow = (w1 < 0) ? NE : (w1 & 0x1FFFFFF);
    ABFrag bf;
    bf.u = ((const uint4*)W2f + (size_t)rel * 64)[lane];
    int quad = lane >> 4, col = lane & 15;
    float* __restrict__ lwave = lmsg + wv * (16 * MS2);
    #pragma unroll
    for (int tl = 0; tl < 4; ++tl) {
        int s = __shfl(src, tl * 16 + col);
        ABFrag a;
        a.u = *((const uint4*)(hh + (size_t)s * HIDC) + quad);  // k = quad*8
        f32x4 acc = {0.f, 0.f, 0.f, 0.f};
        acc = __builtin_amdgcn_mfma_f32_16x16x32_f16(a.f, bf.f, acc, 0, 0, 0);
        float* __restrict__ lt = lwave + (quad * 4) * MS2;
        #pragma unroll
        for (int i = 0; i < 4; ++i) lt[i * MS2 + col] = acc[i];
        if ((lane >> 4) == tl) {
            const float* __restrict__ myrow = lwave + (lane & 15) * MS2;
            unsigned um[8];
            #pragma unroll
            for (int k = 0; k < 8; ++k) {
                float2 v = *(const float2*)(myrow + 2 * k);
                union { __half2 h; unsigned u; } cv;
                cv.h = __floats2half2_rn(v.x * sc, v.y * sc);
                um[k] = cv.u;
            }
            uint4* __restrict__ mrow = (uint4*)(msg + (size_t)drow * OUTC);
            mrow[0] = make_uint4(um[0], um[1], um[2], um[3]);
            mrow[1] = make_uint4(um[4], um[5], um[6], um[7]);
        }
    }
}

// ---------------------------------------------------------------------------
// Fused gather + node update 1: h = relu(sum(msg rows) + x @ root1 + b1), f16 out.
// One wave per node; msg rows contiguous (dst-sorted). lane = (sub,c2):
// sub in [0,4) streams k, c2 in [0,16) covers 32 ch as half2.
__global__ __launch_bounds__(256) void gather1_k(const float* __restrict__ x,
                                                 const float* __restrict__ root1,
                                                 const float* __restrict__ b1,
                                                 const __half* __restrict__ msg,
                                                 const unsigned* __restrict__ rowptr,
                                                 __half* __restrict__ hh) {
    __shared__ float sr[INC * HIDC];   // 8 KB, [in][c]
    for (int k = threadIdx.x; k < INC * HIDC; k += 256) sr[k] = root1[k];
    __syncthreads();
    int wid = (blockIdx.x * 256 + threadIdx.x) >> 6;   // node id; grid exact
    int lane = threadIdx.x & 63;
    int c2 = lane & 15, sub = lane >> 4;
    unsigned k0 = rowptr[wid], k1 = rowptr[wid + 1];
    float accx = 0.f, accy = 0.f;
    for (unsigned k = k0 + sub; k < k1; k += 4) {
        union { __half2 hh2; unsigned u; } cv;
        cv.u = ((const unsigned*)(msg + (size_t)k * HIDC))[c2];
        float2 f = __half22float2(cv.hh2);
        accx += f.x; accy += f.y;
    }
    // root contribution: sub handles input range [sub*16, sub*16+16)
    const float4* __restrict__ xp = (const float4*)(x + (size_t)wid * INC + sub * 16);
    #pragma unroll
    for (int q = 0; q < 4; ++q) {
        float4 xr = xp[q];
        const float* xs = (const float*)&xr;
        #pragma unroll
        for (int j = 0; j < 4; ++j) {
            int in = sub * 16 + q * 4 + j;
            float2 rt = *(const float2*)&sr[in * HIDC + 2 * c2];
            accx = fmaf(xs[j], rt.x, accx);
            accy = fmaf(xs[j], rt.y, accy);
        }
    }
    accx += __shfl_xor(accx, 16); accy += __shfl_xor(accy, 16);
    accx += __shfl_xor(accx, 32); accy += __shfl_xor(accy, 32);
    if (sub == 0) {
        float2 bb = *(const float2*)&b1[2 * c2];
        float vx = accx + bb.x, vy = accy + bb.y;
        union { __half2 h2; unsigned u; } cv;
        cv.h2 = __floats2half2_rn(vx > 0.f ? vx : 0.f, vy > 0.f ? vy : 0.f);
        ((unsigned*)hh)[(size_t)wid * (HIDC / 2) + c2] = cv.u;
    }
}

// Fused gather + node update 2: out = sum(msg rows) + h @ root2 + b2 (f32 out).
// One wave per node; c2 in [0,8) covers 16 ch as half2; sub in [0,8) streams k.
__global__ __launch_bounds__(256) void gather2_k(const __half* __restrict__ hh,
                                                 const float* __restrict__ root2,
                                                 const float* __restrict__ b2,
                                                 const __half* __restrict__ msg,
                                                 const unsigned* __restrict__ rowptr,
                                                 float* __restrict__ out) {
    __shared__ float sr[HIDC * OUTC];  // 2 KB, [in][c]
    for (int k = threadIdx.x; k < HIDC * OUTC; k += 256) sr[k] = root2[k];
    __syncthreads();
    int wid = (blockIdx.x * 256 + threadIdx.x) >> 6;
    int lane = threadIdx.x & 63;
    int c2 = lane & 7, sub = lane >> 3;   // 8 streams
    unsigned k0 = rowptr[wid], k1 = rowptr[wid + 1];
    float accx = 0.f, accy = 0.f;
    for (unsigned k = k0 + sub; k < k1; k += 8) {
        union { __half2 hh2; unsigned u; } cv;
        cv.u = ((const unsigned*)(msg + (size_t)k * OUTC))[c2];
        float2 f = __half22float2(cv.hh2);
        accx += f.x; accy += f.y;
    }
    // root contribution: sub handles input range [sub*4, sub*4+4)
    uint2 hw = *(const uint2*)(hh + (size_t)wid * HIDC + sub * 4);
    union { __half2 h2; unsigned u; } ca, cb;
    ca.u = hw.x; cb.u = hw.y;
    float2 ha = __half22float2(ca.h2), hb = __half22float2(cb.h2);
    float hs[4] = { ha.x, ha.y, hb.x, hb.y };
    #pragma unroll
    for (int j = 0; j < 4; ++j) {
        int in = sub * 4 + j;
        float2 rt = *(const float2*)&sr[in * OUTC + 2 * c2];
        accx = fmaf(hs[j], rt.x, accx);
        accy = fmaf(hs[j], rt.y, accy);
    }
    accx += __shfl_xor(accx, 8);  accy += __shfl_xor(accy, 8);
    accx += __shfl_xor(accx, 16); accy += __shfl_xor(accy, 16);
    accx += __shfl_xor(accx, 32); accy += __shfl_xor(accy, 32);
    if (sub == 0) {
        float2 bb = *(const float2*)&b2[2 * c2];
        *(float2*)&out[(size_t)wid * OUTC + 2 * c2] =
            make_float2(accx + bb.x, accy + bb.y);
    }
}

// ---------------------------------------------------------------------------
extern "C" void kernel_launch(void* const* d_in, const int* in_sizes, int n_in,
                              void* d_out, int out_size, void* d_ws, size_t ws_size,
                              hipStream_t stream) {
    const float* x     = (const float*)d_in[0];
    const int*   ei    = (const int*)d_in[1];   // [2, NE]
    const int*   et    = (const int*)d_in[2];   // [NE]
    const float* W1    = (const float*)d_in[3];
    const float* root1 = (const float*)d_in[4];
    const float* b1    = (const float*)d_in[5];
    const float* W2    = (const float*)d_in[6];
    const float* root2 = (const float*)d_in[7];
    const float* b2    = (const float*)d_in[8];
    float* out = (float*)d_out;

    char* ws = (char*)d_ws;
    size_t o = 0;
    auto alloc = [&](size_t bytes) -> char* {
        char* p = ws + o;
        o = (o + bytes + 255) & ~(size_t)255;
        return p;
    };
    // rsorted FIRST: single 0xFF memset marks all slots as pads (dst=0xFFFF);
    // rscatter_k overwrites exactly the NE real slots. NOTHING needs zeroing.
    unsigned* rsorted = (unsigned*)alloc((size_t)MAXE * 4);        // 4.8 MB
    size_t ff_bytes = o;
    unsigned* ghist   = (unsigned*)alloc((size_t)NR * NB * 4);     // 53 KB
    unsigned* rbase   = (unsigned*)alloc((size_t)NR * NB * 4);
    unsigned* rngs    = (unsigned*)alloc((size_t)NR * 2 * 4);
    int*      chunkrel= (int*)     alloc((size_t)NCHUNK * 4);      // 75 KB
    unsigned short* rank16 = (unsigned short*)alloc((size_t)MAXE * 2); // 2.4 MB
    unsigned* cnt     = (unsigned*)alloc((size_t)NR * NN * 4);     // 9.0 MB
    unsigned* packed  = (unsigned*)alloc((size_t)NR * NN * 4);     // 9.0 MB
    unsigned* dhist   = (unsigned*)alloc((size_t)NN * 4);
    unsigned* rowptr  = (unsigned*)alloc(((size_t)NN + 1) * 4);
    uint2*    pedges  = (uint2*)   alloc((size_t)MAXE * 8);        // 9.6 MB
    __half*   W1f     = (__half*)  alloc((size_t)NR * 2048 * 2);   // 184 KB
    __half*   W2f     = (__half*)  alloc((size_t)NR * 512 * 2);    //  46 KB
    __half*   xh      = (__half*)  alloc((size_t)NN * INC * 2);    // 6.4 MB
    __half*   hh      = (__half*)  alloc((size_t)NN * HIDC * 2);   // 3.2 MB
    // msg buffers alias: msg1 (f16, 64-B rows) fully consumed by gather1
    // before msg2 (f16, 32-B rows) is produced.
    char*     msgraw  = alloc(((size_t)NE + 1) * 64);              // 76.9 MB
    __half*   msg1    = (__half*)msgraw;
    __half*   msg2    = (__half*)msgraw;

    hipMemsetAsync(d_ws, 0xFF, ff_bytes, stream);
    prep_k    <<<(NN * INC / 2 + 255) / 256, 256, 0, stream>>>(W1, W2, x, W1f, W2f, xh);
    rhist_k   <<<NB, 256, 0, stream>>>(ei, et, ghist);
    rscan_k   <<<1, 1024, 0, stream>>>(ghist, rbase, rngs, chunkrel);
    rscatter_k<<<NB, 256, 0, stream>>>(ei, et, rbase, rsorted);
    relcnt_k  <<<2 * NR, 1024, 0, stream>>>(rsorted, rngs, cnt, rank16);
    drel_k    <<<(NN + 255) / 256, 256, 0, stream>>>(cnt, packed, dhist);
    dprefix_k <<<1, 1024, 0, stream>>>(dhist, rowptr);
    finalize_k<<<(MAXE + 255) / 256, 256, 0, stream>>>(rsorted, rank16, packed,
                                                       rowptr, chunkrel, pedges);
    msg1_k    <<<(MAXE + 255) / 256, 256, 0, stream>>>(xh, W1f, pedges, msg1);
    gather1_k <<<NN * 64 / 256, 256, 0, stream>>>(x, root1, b1, msg1, rowptr, hh);
    msg2_k    <<<(MAXE + 255) / 256, 256, 0, stream>>>(hh, W2f, pedges, msg2);
    gather2_k <<<NN * 64 / 256, 256, 0, stream>>>(hh, root2, b2, msg2, rowptr, out);
}